// Round 3
// baseline (1948.779 us; speedup 1.0000x reference)
//
#include <hip/hip_runtime.h>
#include <hip/hip_bf16.h>
#include <cstdint>
#include <cstddef>

typedef __hip_bfloat16 bf16;

#define MAXN 100
#define HH   4
#define FIN  128
#define KS1  25

static inline int ceil_div(int a, int b){ return (a + b - 1) / b; }

// ---------------- input dtype sniff ----------------
// Examine even-indexed u16 half-words of x (~N(0,1)). If input is bf16, nearly
// all decode to sane magnitudes; if f32, the low mantissa halves have random
// exponents and only ~11% look sane. flag=1 -> bf16 inputs, 0 -> f32 inputs.
__global__ __launch_bounds__(256) void sniff_dtype(const unsigned short* __restrict__ u,
                                                   float* __restrict__ flag){
  __shared__ int cnt;
  if (threadIdx.x == 0) cnt = 0;
  __syncthreads();
  unsigned short b = u[2 * threadIdx.x];
  unsigned int w = ((unsigned int)b) << 16;
  float v = __uint_as_float(w);
  float a = fabsf(v);
  if (a >= 6.1e-5f && a <= 16384.f) atomicAdd(&cnt, 1);
  __syncthreads();
  if (threadIdx.x == 0) *flag = (cnt >= 128) ? 1.0f : 0.0f;
}

// ---------------- casts (dtype-agnostic via flag) ----------------
__global__ __launch_bounds__(256) void cast_in(const void* __restrict__ s, float* __restrict__ d,
                                               int n, const float* __restrict__ flag){
  int i = blockIdx.x * 256 + threadIdx.x;
  if (i >= n) return;
  if (*flag != 0.0f) d[i] = __bfloat162float(((const bf16*)s)[i]);
  else               d[i] = ((const float*)s)[i];
}

struct CastBatch {
  const void* src[36];
  float*      dst[36];
  int         n[36];
};

__global__ __launch_bounds__(256) void cast_many(CastBatch cb, const float* __restrict__ flag){
  int t = blockIdx.y;
  int n = cb.n[t];
  bool isbf = (*flag != 0.0f);
  const void* s = cb.src[t];
  float* d = cb.dst[t];
  for (int i = blockIdx.x * 256 + threadIdx.x; i < n; i += gridDim.x * 256)
    d[i] = isbf ? __bfloat162float(((const bf16*)s)[i]) : ((const float*)s)[i];
}

// ---------------- degree / norm ----------------
__global__ __launch_bounds__(256) void deg_init(float* deg, int n){
  int i = blockIdx.x * 256 + threadIdx.x;
  if (i < n) deg[i] = 1.0f;                        // self-loop
}
__global__ __launch_bounds__(256) void deg_edges(const int* __restrict__ dst, float* deg, int e){
  int i = blockIdx.x * 256 + threadIdx.x;
  if (i < e) atomicAdd(&deg[dst[i]], 1.0f);
}
__global__ __launch_bounds__(256) void deg_fin(float* deg, int n){
  int i = blockIdx.x * 256 + threadIdx.x;
  if (i < n) deg[i] = 1.0f / sqrtf(deg[i]);        // deg >= 1 always
}

// ---------------- generic fp32 GEMM ----------------
// C = epilogue(A[M,K] @ B[K,N] + bias); mode 0: none, 1: relu, 2: resid + relu(.)
#define BM 64
#define BN 64
#define BK 16
__global__ __launch_bounds__(256) void gemm_f32(
    const float* __restrict__ A, int lda,
    const float* __restrict__ B, int ldb,
    const float* __restrict__ bias,
    const float* __restrict__ resid, int ldr,
    float* __restrict__ C, int ldc,
    int M, int Nn, int K, int mode)
{
  __shared__ __align__(16) float As[BK][BM + 4];   // stride 68 keeps float4 alignment
  __shared__ __align__(16) float Bs[BK][BN + 4];
  int bm = blockIdx.x * BM, bn = blockIdx.y * BN;
  int tid = threadIdx.x;
  int tx = tid & 15, ty = tid >> 4;
  float acc[4][4] = {};
  for (int k0 = 0; k0 < K; k0 += BK){
    for (int i = tid; i < BM * BK; i += 256){
      int r = i >> 4, kk = i & 15;
      int gr = bm + r;
      As[kk][r] = (gr < M) ? A[(size_t)gr * lda + k0 + kk] : 0.f;
    }
    for (int i = tid; i < BK * BN; i += 256){
      int r = i >> 6, c = i & 63;
      int gc = bn + c;
      Bs[r][c] = (gc < Nn) ? B[(size_t)(k0 + r) * ldb + gc] : 0.f;
    }
    __syncthreads();
#pragma unroll
    for (int kk = 0; kk < BK; kk++){
      float4 a4 = *reinterpret_cast<const float4*>(&As[kk][ty * 4]);
      float4 b4 = *reinterpret_cast<const float4*>(&Bs[kk][tx * 4]);
      float a[4] = {a4.x, a4.y, a4.z, a4.w};
      float b[4] = {b4.x, b4.y, b4.z, b4.w};
#pragma unroll
      for (int i = 0; i < 4; i++)
#pragma unroll
        for (int j = 0; j < 4; j++)
          acc[i][j] = fmaf(a[i], b[j], acc[i][j]);
    }
    __syncthreads();
  }
#pragma unroll
  for (int i = 0; i < 4; i++){
    int gr = bm + ty * 4 + i;
    if (gr >= M) continue;
#pragma unroll
    for (int j = 0; j < 4; j++){
      int gc = bn + tx * 4 + j;
      if (gc >= Nn) continue;
      float v = acc[i][j];
      if (bias) v += bias[gc];
      if (mode == 1) v = fmaxf(v, 0.f);
      else if (mode == 2) v = resid[(size_t)gr * ldr + gc] + fmaxf(v, 0.f);
      C[(size_t)gr * ldc + gc] = v;
    }
  }
}

// ---------------- GCN propagate ----------------
// y[r, c] = t[r, c] * dinv[r]^2 + bias[c]   (self-loop + bias init)
__global__ __launch_bounds__(256) void gcn_init(const float* __restrict__ t, int fshift,
    const float* __restrict__ dinv, const float* __restrict__ bias,
    float* __restrict__ y, int ldy, int total)
{
  int i = blockIdx.x * 256 + threadIdx.x;
  if (i >= total) return;
  int r = i >> fshift;
  int c = i & ((1 << fshift) - 1);
  float dv = dinv[r];
  y[(size_t)r * ldy + c] = t[i] * dv * dv + bias[c];
}

// y[dst, c] += t[src, c] * dinv[src]*dinv[dst]
__global__ __launch_bounds__(256) void gcn_edges(const int* __restrict__ src, const int* __restrict__ dst,
    const float* __restrict__ t, const float* __restrict__ dinv,
    float* __restrict__ y, int ldy, int fshift, int total)
{
  int i = blockIdx.x * 256 + threadIdx.x;
  if (i >= total) return;
  int e = i >> fshift;
  int c = i & ((1 << fshift) - 1);
  int s = src[e], d = dst[e];
  float nrm = dinv[s] * dinv[d];
  atomicAdd(&y[(size_t)d * ldy + c], t[((size_t)s << fshift) + c] * nrm);
}

__global__ __launch_bounds__(256) void relu_strided(float* y, int ldy, int fshift, int total){
  int i = blockIdx.x * 256 + threadIdx.x;
  if (i >= total) return;
  int r = i >> fshift, c = i & ((1 << fshift) - 1);
  float* p = &y[(size_t)r * ldy + c];
  *p = fmaxf(*p, 0.f);
}

// ---------------- pooling (sum of 100 rows per graph), f32 out ----------------
__global__ __launch_bounds__(256) void pool_sum(const float* __restrict__ x, int ldx,
    float* __restrict__ out, int total /* G*128 */)
{
  int i = blockIdx.x * 256 + threadIdx.x;
  if (i >= total) return;
  int g = i >> 7, c = i & 127;
  float s = 0.f;
  const float* p = x + (size_t)g * MAXN * ldx + c;
  for (int k = 0; k < MAXN; k++) s += p[(size_t)k * ldx];
  out[i] = s;
}

// ---------------- attention: scores S[g,h,q,k] = scale * <Q[q,h,:], K[k,h,:]> ----------------
__global__ __launch_bounds__(256) void attn_score(
    const float* __restrict__ Q, int qbroadcast, int ldq,
    const float* __restrict__ Km, int ldk,
    float* __restrict__ S, int nq, int nk, int dh, float scale)
{
  __shared__ float Ks[100 * 65];
  __shared__ float Qs[25 * 65];
  int g = blockIdx.x, h = blockIdx.y;
  int H = gridDim.y;
  int tid = threadIdx.x;
  int pd = dh + 1;
  for (int i = tid; i < nk * dh; i += 256){
    int k = i / dh, d = i - k * dh;
    Ks[k * pd + d] = Km[(size_t)(g * nk + k) * ldk + h * dh + d];
  }
  for (int i = tid; i < nq * dh; i += 256){
    int q = i / dh, d = i - q * dh;
    int qr = qbroadcast ? q : g * nq + q;
    Qs[q * pd + d] = Q[(size_t)qr * ldq + h * dh + d];
  }
  __syncthreads();
  int tot = nq * nk;
  for (int o = tid; o < tot; o += 256){
    int q = o / nk, k = o - q * nk;
    float acc = 0.f;
    const float* qp = &Qs[q * pd];
    const float* kp = &Ks[k * pd];
    for (int d = 0; d < dh; d++) acc = fmaf(qp[d], kp[d], acc);
    S[(((size_t)g * H + h) * nq + q) * nk + k] = acc * scale;
  }
}

// softmax over the q axis (axis=2 of [G,H,nq,nk]) — one thread per (g,h,k)
__global__ __launch_bounds__(256) void softmax_q(float* __restrict__ S, int nq, int nk, int total){
  int i = blockIdx.x * 256 + threadIdx.x;
  if (i >= total) return;
  int gh = i / nk, k = i - gh * nk;
  float* base = S + (size_t)gh * nq * nk + k;
  float m = -1e30f;
  for (int q = 0; q < nq; q++) m = fmaxf(m, base[q * nk]);
  float s = 0.f;
  for (int q = 0; q < nq; q++){ float e = __expf(base[q * nk] - m); base[q * nk] = e; s += e; }
  float inv = 1.0f / s;
  for (int q = 0; q < nq; q++) base[q * nk] *= inv;
}

// O[g,q,c] = Q[.,q,c] + sum_k A[g,h(c),q,k] * V[g,k,c]
__global__ __launch_bounds__(256) void attn_av(
    const float* __restrict__ S, const float* __restrict__ V, int ldv,
    const float* __restrict__ Q, int qbroadcast, int ldq,
    float* __restrict__ O, int ldo,
    int nq, int nk, int H, int dh, int total)
{
  int i = blockIdx.x * 256 + threadIdx.x;
  if (i >= total) return;
  int dv = H * dh;
  int g = i / (nq * dv);
  int rem = i - g * (nq * dv);
  int q = rem / dv;
  int c = rem - q * dv;
  int h = c / dh;
  const float* a = S + (((size_t)g * H + h) * nq + q) * nk;
  const float* v = V + (size_t)(g * nk) * ldv + c;
  int qr = qbroadcast ? q : g * nq + q;
  float acc = Q[(size_t)qr * ldq + c];
  for (int k = 0; k < nk; k++) acc = fmaf(a[k], v[(size_t)k * ldv], acc);
  O[(size_t)(g * nq + q) * ldo + c] = acc;
}

// GMPool_I with 1 seed: softmax over singleton q-axis == 1 -> O2[g,c] = Q2[c] + sum_k V2[g,k,c]
__global__ __launch_bounds__(256) void seed_sum(const float* __restrict__ V, const float* __restrict__ Qc,
    float* __restrict__ O, int total /* G*128 */)
{
  int i = blockIdx.x * 256 + threadIdx.x;
  if (i >= total) return;
  int g = i >> 7, c = i & 127;
  float acc = Qc[c];
  const float* p = V + (size_t)(g * KS1) * 128 + c;
  for (int k = 0; k < KS1; k++) acc += p[k * 128];
  O[i] = acc;
}

// ---------------- host ----------------
extern "C" void kernel_launch(void* const* d_in, const int* in_sizes, int n_in,
                              void* d_out, int out_size, void* d_ws, size_t ws_size,
                              hipStream_t stream)
{
  const int*  edge = (const int*)d_in[1];
  const int N = in_sizes[0] / FIN;      // 20000
  const int E = in_sizes[1] / 2;        // 320000
  const int G = N / MAXN;               // 200
  const int* srcp = edge;
  const int* dstp = edge + E;
  float* out = (float*)d_out;           // f32 output: [logits 200x10 | p1 200x128 | p2 200x128]

  float* w = (float*)d_ws;
  size_t off = 0;
  auto alloc = [&](size_t nfl){ float* p = w + off; off += nfl; return p; };

  float* dflag = alloc(1);
  float* dinv = alloc(N);

  // fp32 copies of all float inputs (skip 0:x, 1:edge, 2:batch, 27/28: unused Wk2/bk2)
  float* wf[41] = {nullptr};
  CastBatch cb;
  int nw = 0;
  for (int t = 3; t < 41; t++){
    if (t == 27 || t == 28) continue;
    float* p = alloc((size_t)in_sizes[t]);
    wf[t] = p;
    cb.src[nw] = d_in[t];
    cb.dst[nw] = p;
    cb.n[nw]   = in_sizes[t];
    nw++;
  }

  float* P0 = alloc((size_t)N * 256);   // xcat = [x1 | x2]
  float* P1 = alloc((size_t)N * 256);   // xf, tK, tV; later attn0 slabs
  float* P2 = alloc((size_t)N * 256);   // t1/t2, Kd; later V2
  float* P3 = alloc((size_t)N * 256);   // Vd; later SAB slabs
  float* Sbuf = alloc((size_t)G * HH * KS1 * MAXN);
  float* Q0   = alloc(25 * 256);
  float* Q2c  = alloc(128);
  float* O2   = alloc((size_t)G * 128);
  float* O2f  = alloc((size_t)G * 128);
  float* zb   = alloc((size_t)G * 128);
  float* z1   = alloc((size_t)G * 128);
  float* z2   = alloc((size_t)G * 64);
  if (off * sizeof(float) > ws_size) return;   // fail loudly rather than corrupt

  float* xf = P1;                                   // N x 128, dead before tK
  float* Oa = P1;                                   // 5000 x 256 (after tV dead)
  float* O0 = P1 + (size_t)G * KS1 * 256;           // 5000 x 256
  float* Q1v = P3;                                  // SAB slabs (after Vd dead)
  float* K1v = P3 + (size_t)G * KS1 * 128;
  float* V1v = P3 + (size_t)2 * G * KS1 * 128;
  float* Ob  = P3 + (size_t)3 * G * KS1 * 128;
  float* O1  = P3 + (size_t)4 * G * KS1 * 128;
  float* V2  = P2;                                  // after Kd dead

  dim3 blk(256);
  auto gemm = [&](const float* A, int lda, const float* B, int ldb, const float* bias,
                  const float* resid, int ldr, float* C, int ldc, int M, int Nc, int K, int mode){
    dim3 grid(ceil_div(M, BM), ceil_div(Nc, BN));
    gemm_f32<<<grid, blk, 0, stream>>>(A, lda, B, ldb, bias, resid, ldr, C, ldc, M, Nc, K, mode);
  };

  // dtype sniff + casts
  sniff_dtype<<<1, blk, 0, stream>>>((const unsigned short*)d_in[0], dflag);
  cast_in<<<ceil_div(N * FIN, 256), blk, 0, stream>>>(d_in[0], xf, N * FIN, dflag);
  cast_many<<<dim3(64, 36), blk, 0, stream>>>(cb, dflag);

  // symmetric-norm degrees (shared by all 4 GCNs)
  deg_init<<<ceil_div(N, 256), blk, 0, stream>>>(dinv, N);
  deg_edges<<<ceil_div(E, 256), blk, 0, stream>>>(dstp, dinv, E);
  deg_fin<<<ceil_div(N, 256), blk, 0, stream>>>(dinv, N);

  // GCN1: x1 = relu(prop(x@W1) + b1) -> xcat[:,0:128]; p1 pooling -> out[2000:27600]
  gemm(xf, 128, wf[3], 128, nullptr, nullptr, 0, P2, 128, N, 128, 128, 0);
  gcn_init<<<ceil_div(N * 128, 256), blk, 0, stream>>>(P2, 7, dinv, wf[4], P0, 256, N * 128);
  gcn_edges<<<ceil_div(E * 128, 256), blk, 0, stream>>>(srcp, dstp, P2, dinv, P0, 256, 7, E * 128);
  relu_strided<<<ceil_div(N * 128, 256), blk, 0, stream>>>(P0, 256, 7, N * 128);
  pool_sum<<<ceil_div(G * 128, 256), blk, 0, stream>>>(P0, 256, out + 2000, G * 128);

  // GCN2: x2 = relu(prop(x1@W2) + b2) -> xcat[:,128:256]; p2 pooling -> out[27600:53200]
  gemm(P0, 256, wf[5], 128, nullptr, nullptr, 0, P2, 128, N, 128, 128, 0);
  gcn_init<<<ceil_div(N * 128, 256), blk, 0, stream>>>(P2, 7, dinv, wf[6], P0 + 128, 256, N * 128);
  gcn_edges<<<ceil_div(E * 128, 256), blk, 0, stream>>>(srcp, dstp, P2, dinv, P0 + 128, 256, 7, E * 128);
  relu_strided<<<ceil_div(N * 128, 256), blk, 0, stream>>>(P0 + 128, 256, 7, N * 128);
  pool_sum<<<ceil_div(G * 128, 256), blk, 0, stream>>>(P0 + 128, 256, out + 27600, G * 128);

  // GCN K0: Kd = prop(xcat@Wk0) + bk0  (no relu)
  gemm(P0, 256, wf[10], 256, nullptr, nullptr, 0, P1, 256, N, 256, 256, 0);
  gcn_init<<<ceil_div(N * 256, 256), blk, 0, stream>>>(P1, 8, dinv, wf[11], P2, 256, N * 256);
  gcn_edges<<<ceil_div(E * 256, 256), blk, 0, stream>>>(srcp, dstp, P1, dinv, P2, 256, 8, E * 256);
  // GCN V0: Vd = prop(xcat@Wv0) + bv0
  gemm(P0, 256, wf[12], 256, nullptr, nullptr, 0, P1, 256, N, 256, 256, 0);
  gcn_init<<<ceil_div(N * 256, 256), blk, 0, stream>>>(P1, 8, dinv, wf[13], P3, 256, N * 256);
  gcn_edges<<<ceil_div(E * 256, 256), blk, 0, stream>>>(srcp, dstp, P1, dinv, P3, 256, 8, E * 256);

  // Q0 = S0 @ Wq0 + bq0 (shared across graphs)
  gemm(wf[7], 256, wf[8], 256, wf[9], nullptr, 0, Q0, 256, 25, 256, 256, 0);

  // --- GMPool_G (dv=256, dh=64, nk=100, softmax over q; mask bias == 0 since all graphs full) ---
  attn_score<<<dim3(G, HH), blk, 0, stream>>>(Q0, 1, 256, P2, 256, Sbuf, 25, 100, 64, 0.0625f);
  softmax_q<<<ceil_div(G * HH * 100, 256), blk, 0, stream>>>(Sbuf, 25, 100, G * HH * 100);
  attn_av<<<ceil_div(G * 25 * 256, 256), blk, 0, stream>>>(Sbuf, P3, 256, Q0, 1, 256, Oa, 256, 25, 100, HH, 64, G * 25 * 256);
  gemm(Oa, 256, wf[14], 256, wf[15], Oa, 256, O0, 256, G * KS1, 256, 256, 2);

  // --- SAB (dv=128, dh=32, nk=25) ---
  gemm(O0, 256, wf[16], 128, wf[17], nullptr, 0, Q1v, 128, G * KS1, 128, 256, 0);
  gemm(O0, 256, wf[18], 128, wf[19], nullptr, 0, K1v, 128, G * KS1, 128, 256, 0);
  gemm(O0, 256, wf[20], 128, wf[21], nullptr, 0, V1v, 128, G * KS1, 128, 256, 0);
  attn_score<<<dim3(G, HH), blk, 0, stream>>>(Q1v, 0, 128, K1v, 128, Sbuf, 25, 25, 32, 0.0883883476f);
  softmax_q<<<ceil_div(G * HH * 25, 256), blk, 0, stream>>>(Sbuf, 25, 25, G * HH * 25);
  attn_av<<<ceil_div(G * 25 * 128, 256), blk, 0, stream>>>(Sbuf, V1v, 128, Q1v, 0, 128, Ob, 128, 25, 25, HH, 32, G * 25 * 128);
  gemm(Ob, 128, wf[22], 128, wf[23], Ob, 128, O1, 128, G * KS1, 128, 128, 2);

  // --- GMPool_I (1 seed; softmax over q-axis of size 1 == 1 -> plain sum; Wk2 unused) ---
  gemm(O1, 128, wf[29], 128, wf[30], nullptr, 0, V2, 128, G * KS1, 128, 128, 0);
  gemm(wf[24], 128, wf[25], 128, wf[26], nullptr, 0, Q2c, 128, 1, 128, 128, 0);
  seed_sum<<<ceil_div(G * 128, 256), blk, 0, stream>>>(V2, Q2c, O2, G * 128);
  gemm(O2, 128, wf[31], 128, wf[32], O2, 128, O2f, 128, G, 128, 128, 2);

  // classifier head -> logits written straight to out[0:2000] as f32
  gemm(O2f, 128, wf[33], 128, wf[34], nullptr, 0, zb, 128, G, 128, 128, 0);
  gemm(zb, 128, wf[35], 128, wf[36], nullptr, 0, z1, 128, G, 128, 128, 1);
  gemm(z1, 128, wf[37], 64, wf[38], nullptr, 0, z2, 64, G, 64, 128, 1);
  gemm(z2, 64, wf[39], 10, wf[40], nullptr, 0, out, 10, G, 10, 64, 0);
}

// Round 4
// 1006.159 us; speedup vs baseline: 1.9369x; 1.9369x over previous
//
#include <hip/hip_runtime.h>
#include <hip/hip_bf16.h>
#include <cstdint>
#include <cstddef>

typedef __hip_bfloat16 bf16;

#define MAXN 100
#define HH   4
#define FIN  128
#define KS1  25

static inline int ceil_div(int a, int b){ return (a + b - 1) / b; }

// ---------------- input dtype sniff (kept from r2/r3; inputs proven f32) ----------------
__global__ __launch_bounds__(256) void sniff_dtype(const unsigned short* __restrict__ u,
                                                   float* __restrict__ flag){
  __shared__ int cnt;
  if (threadIdx.x == 0) cnt = 0;
  __syncthreads();
  unsigned short b = u[2 * threadIdx.x];
  unsigned int w = ((unsigned int)b) << 16;
  float v = __uint_as_float(w);
  float a = fabsf(v);
  if (a >= 6.1e-5f && a <= 16384.f) atomicAdd(&cnt, 1);
  __syncthreads();
  if (threadIdx.x == 0) *flag = (cnt >= 128) ? 1.0f : 0.0f;
}

__global__ __launch_bounds__(256) void cast_in(const void* __restrict__ s, float* __restrict__ d,
                                               int n, const float* __restrict__ flag){
  int i = blockIdx.x * 256 + threadIdx.x;
  if (i >= n) return;
  if (*flag != 0.0f) d[i] = __bfloat162float(((const bf16*)s)[i]);
  else               d[i] = ((const float*)s)[i];
}

struct CastBatch {
  const void* src[36];
  float*      dst[36];
  int         n[36];
};

__global__ __launch_bounds__(256) void cast_many(CastBatch cb, const float* __restrict__ flag){
  int t = blockIdx.y;
  int n = cb.n[t];
  bool isbf = (*flag != 0.0f);
  const void* s = cb.src[t];
  float* d = cb.dst[t];
  for (int i = blockIdx.x * 256 + threadIdx.x; i < n; i += gridDim.x * 256)
    d[i] = isbf ? __bfloat162float(((const bf16*)s)[i]) : ((const float*)s)[i];
}

// ---------------- degree / norm ----------------
__global__ __launch_bounds__(256) void deg_init(float* deg, int n){
  int i = blockIdx.x * 256 + threadIdx.x;
  if (i < n) deg[i] = 1.0f;                        // self-loop
}
__global__ __launch_bounds__(256) void deg_edges(const int* __restrict__ dst, float* deg, int e){
  int i = blockIdx.x * 256 + threadIdx.x;
  if (i < e) atomicAdd(&deg[dst[i]], 1.0f);
}
__global__ __launch_bounds__(256) void deg_fin(float* deg, int n){
  int i = blockIdx.x * 256 + threadIdx.x;
  if (i < n) deg[i] = 1.0f / sqrtf(deg[i]);        // deg >= 1 always
}

// ---------------- dense normalized adjacency A[g][dst_local][src_local] ----------------
// diag = dinv^2 (self-loop); edges accumulate dinv[s]*dinv[d] (duplicates & data
// self-edges add on top — identical to reference segment_sum semantics).
__global__ __launch_bounds__(256) void adj_init(const float* __restrict__ dinv,
                                                float* __restrict__ A, int total){
  int i = blockIdx.x * 256 + threadIdx.x;
  if (i >= total) return;
  int g = i / (MAXN * MAXN);
  int rem = i - g * (MAXN * MAXN);
  int r = rem / MAXN, s = rem - r * MAXN;
  float v = 0.f;
  if (r == s){ float dv = dinv[g * MAXN + r]; v = dv * dv; }
  A[i] = v;
}

__global__ __launch_bounds__(256) void adj_edges(const int* __restrict__ src, const int* __restrict__ dst,
                                                 const float* __restrict__ dinv,
                                                 float* __restrict__ A, int e){
  int i = blockIdx.x * 256 + threadIdx.x;
  if (i >= e) return;
  int s = src[i], d = dst[i];
  int g = d / MAXN;
  int dl = d - g * MAXN;
  int sl = s - (s / MAXN) * MAXN;
  atomicAdd(&A[(size_t)g * (MAXN * MAXN) + dl * MAXN + sl], dinv[s] * dinv[d]);
}

// ---------------- batched dense propagation: Y[g*100+r, c0+c] = act(sum_s A[g][r][s]*T[g*100+s, c0+c] + bias) ----------------
// grid (G, F/64), block 256 = 16 col-threads (4 cols ea) x 16 row-threads (7 rows ea, rows padded to 112)
#define ASTRIDE 101
#define TSTRIDE 68
__global__ __launch_bounds__(256) void prop_gemm(
    const float* __restrict__ A,
    const float* __restrict__ T, int ldt,
    const float* __restrict__ bias,
    float* __restrict__ Y, int ldy,
    int relu)
{
  __shared__ float As[112 * ASTRIDE];       // 45.2 KB, row stride 101 (conflict-free)
  __shared__ float Ts[MAXN * TSTRIDE];      // 27.2 KB
  int g = blockIdx.x;
  int c0 = blockIdx.y * 64;
  int tid = threadIdx.x;
  const float* Ag = A + (size_t)g * (MAXN * MAXN);
  for (int i = tid; i < MAXN * MAXN; i += 256){
    int r = i / MAXN, s = i - r * MAXN;
    As[r * ASTRIDE + s] = Ag[i];
  }
  for (int i = tid; i < MAXN * 16; i += 256){
    int s = i >> 4, jj = i & 15;
    float4 v = *reinterpret_cast<const float4*>(&T[(size_t)(g * MAXN + s) * ldt + c0 + jj * 4]);
    *reinterpret_cast<float4*>(&Ts[s * TSTRIDE + jj * 4]) = v;
  }
  __syncthreads();

  int tx = tid & 15, ty = tid >> 4;
  float acc[7][4] = {};
#pragma unroll 2
  for (int s = 0; s < MAXN; s++){
    float4 t4 = *reinterpret_cast<const float4*>(&Ts[s * TSTRIDE + tx * 4]);
    float t[4] = {t4.x, t4.y, t4.z, t4.w};
#pragma unroll
    for (int i = 0; i < 7; i++){
      float a = As[(ty * 7 + i) * ASTRIDE + s];
#pragma unroll
      for (int j = 0; j < 4; j++) acc[i][j] = fmaf(a, t[j], acc[i][j]);
    }
  }

  float4 b4 = make_float4(0.f, 0.f, 0.f, 0.f);
  if (bias) b4 = *reinterpret_cast<const float4*>(&bias[c0 + tx * 4]);
#pragma unroll
  for (int i = 0; i < 7; i++){
    int r = ty * 7 + i;
    if (r >= MAXN) continue;
    float v0 = acc[i][0] + b4.x, v1 = acc[i][1] + b4.y, v2 = acc[i][2] + b4.z, v3 = acc[i][3] + b4.w;
    if (relu){ v0 = fmaxf(v0, 0.f); v1 = fmaxf(v1, 0.f); v2 = fmaxf(v2, 0.f); v3 = fmaxf(v3, 0.f); }
    float4 o = make_float4(v0, v1, v2, v3);
    *reinterpret_cast<float4*>(&Y[(size_t)(g * MAXN + r) * ldy + c0 + tx * 4]) = o;
  }
}

// ---------------- generic fp32 GEMM ----------------
// C = epilogue(A[M,K] @ B[K,N] + bias); mode 0: none, 1: relu, 2: resid + relu(.)
#define BM 64
#define BN 64
#define BK 16
__global__ __launch_bounds__(256) void gemm_f32(
    const float* __restrict__ A, int lda,
    const float* __restrict__ B, int ldb,
    const float* __restrict__ bias,
    const float* __restrict__ resid, int ldr,
    float* __restrict__ C, int ldc,
    int M, int Nn, int K, int mode)
{
  __shared__ __align__(16) float As[BK][BM + 4];
  __shared__ __align__(16) float Bs[BK][BN + 4];
  int bm = blockIdx.x * BM, bn = blockIdx.y * BN;
  int tid = threadIdx.x;
  int tx = tid & 15, ty = tid >> 4;
  float acc[4][4] = {};
  for (int k0 = 0; k0 < K; k0 += BK){
    for (int i = tid; i < BM * BK; i += 256){
      int r = i >> 4, kk = i & 15;
      int gr = bm + r;
      As[kk][r] = (gr < M) ? A[(size_t)gr * lda + k0 + kk] : 0.f;
    }
    for (int i = tid; i < BK * BN; i += 256){
      int r = i >> 6, c = i & 63;
      int gc = bn + c;
      Bs[r][c] = (gc < Nn) ? B[(size_t)(k0 + r) * ldb + gc] : 0.f;
    }
    __syncthreads();
#pragma unroll
    for (int kk = 0; kk < BK; kk++){
      float4 a4 = *reinterpret_cast<const float4*>(&As[kk][ty * 4]);
      float4 b4 = *reinterpret_cast<const float4*>(&Bs[kk][tx * 4]);
      float a[4] = {a4.x, a4.y, a4.z, a4.w};
      float b[4] = {b4.x, b4.y, b4.z, b4.w};
#pragma unroll
      for (int i = 0; i < 4; i++)
#pragma unroll
        for (int j = 0; j < 4; j++)
          acc[i][j] = fmaf(a[i], b[j], acc[i][j]);
    }
    __syncthreads();
  }
#pragma unroll
  for (int i = 0; i < 4; i++){
    int gr = bm + ty * 4 + i;
    if (gr >= M) continue;
#pragma unroll
    for (int j = 0; j < 4; j++){
      int gc = bn + tx * 4 + j;
      if (gc >= Nn) continue;
      float v = acc[i][j];
      if (bias) v += bias[gc];
      if (mode == 1) v = fmaxf(v, 0.f);
      else if (mode == 2) v = resid[(size_t)gr * ldr + gc] + fmaxf(v, 0.f);
      C[(size_t)gr * ldc + gc] = v;
    }
  }
}

// ---------------- pooling (sum of 100 rows per graph), f32 out ----------------
__global__ __launch_bounds__(256) void pool_sum(const float* __restrict__ x, int ldx,
    float* __restrict__ out, int total /* G*128 */)
{
  int i = blockIdx.x * 256 + threadIdx.x;
  if (i >= total) return;
  int g = i >> 7, c = i & 127;
  float s = 0.f;
  const float* p = x + (size_t)g * MAXN * ldx + c;
  for (int k = 0; k < MAXN; k++) s += p[(size_t)k * ldx];
  out[i] = s;
}

// ---------------- attention: scores S[g,h,q,k] = scale * <Q[q,h,:], K[k,h,:]> ----------------
__global__ __launch_bounds__(256) void attn_score(
    const float* __restrict__ Q, int qbroadcast, int ldq,
    const float* __restrict__ Km, int ldk,
    float* __restrict__ S, int nq, int nk, int dh, float scale)
{
  __shared__ float Ks[100 * 65];
  __shared__ float Qs[25 * 65];
  int g = blockIdx.x, h = blockIdx.y;
  int H = gridDim.y;
  int tid = threadIdx.x;
  int pd = dh + 1;
  for (int i = tid; i < nk * dh; i += 256){
    int k = i / dh, d = i - k * dh;
    Ks[k * pd + d] = Km[(size_t)(g * nk + k) * ldk + h * dh + d];
  }
  for (int i = tid; i < nq * dh; i += 256){
    int q = i / dh, d = i - q * dh;
    int qr = qbroadcast ? q : g * nq + q;
    Qs[q * pd + d] = Q[(size_t)qr * ldq + h * dh + d];
  }
  __syncthreads();
  int tot = nq * nk;
  for (int o = tid; o < tot; o += 256){
    int q = o / nk, k = o - q * nk;
    float acc = 0.f;
    const float* qp = &Qs[q * pd];
    const float* kp = &Ks[k * pd];
    for (int d = 0; d < dh; d++) acc = fmaf(qp[d], kp[d], acc);
    S[(((size_t)g * H + h) * nq + q) * nk + k] = acc * scale;
  }
}

// softmax over the q axis (axis=2 of [G,H,nq,nk]) — one thread per (g,h,k)
__global__ __launch_bounds__(256) void softmax_q(float* __restrict__ S, int nq, int nk, int total){
  int i = blockIdx.x * 256 + threadIdx.x;
  if (i >= total) return;
  int gh = i / nk, k = i - gh * nk;
  float* base = S + (size_t)gh * nq * nk + k;
  float m = -1e30f;
  for (int q = 0; q < nq; q++) m = fmaxf(m, base[q * nk]);
  float s = 0.f;
  for (int q = 0; q < nq; q++){ float e = __expf(base[q * nk] - m); base[q * nk] = e; s += e; }
  float inv = 1.0f / s;
  for (int q = 0; q < nq; q++) base[q * nk] *= inv;
}

// O[g,q,c] = Q[.,q,c] + sum_k A[g,h(c),q,k] * V[g,k,c]
__global__ __launch_bounds__(256) void attn_av(
    const float* __restrict__ S, const float* __restrict__ V, int ldv,
    const float* __restrict__ Q, int qbroadcast, int ldq,
    float* __restrict__ O, int ldo,
    int nq, int nk, int H, int dh, int total)
{
  int i = blockIdx.x * 256 + threadIdx.x;
  if (i >= total) return;
  int dv = H * dh;
  int g = i / (nq * dv);
  int rem = i - g * (nq * dv);
  int q = rem / dv;
  int c = rem - q * dv;
  int h = c / dh;
  const float* a = S + (((size_t)g * H + h) * nq + q) * nk;
  const float* v = V + (size_t)(g * nk) * ldv + c;
  int qr = qbroadcast ? q : g * nq + q;
  float acc = Q[(size_t)qr * ldq + c];
  for (int k = 0; k < nk; k++) acc = fmaf(a[k], v[(size_t)k * ldv], acc);
  O[(size_t)(g * nq + q) * ldo + c] = acc;
}

// GMPool_I with 1 seed: softmax over singleton q-axis == 1 -> O2[g,c] = Q2[c] + sum_k V2[g,k,c]
__global__ __launch_bounds__(256) void seed_sum(const float* __restrict__ V, const float* __restrict__ Qc,
    float* __restrict__ O, int total /* G*128 */)
{
  int i = blockIdx.x * 256 + threadIdx.x;
  if (i >= total) return;
  int g = i >> 7, c = i & 127;
  float acc = Qc[c];
  const float* p = V + (size_t)(g * KS1) * 128 + c;
  for (int k = 0; k < KS1; k++) acc += p[k * 128];
  O[i] = acc;
}

// ---------------- host ----------------
extern "C" void kernel_launch(void* const* d_in, const int* in_sizes, int n_in,
                              void* d_out, int out_size, void* d_ws, size_t ws_size,
                              hipStream_t stream)
{
  const int*  edge = (const int*)d_in[1];
  const int N = in_sizes[0] / FIN;      // 20000
  const int E = in_sizes[1] / 2;        // 320000
  const int G = N / MAXN;               // 200
  const int* srcp = edge;
  const int* dstp = edge + E;
  float* out = (float*)d_out;           // f32: [logits 200x10 | p1 200x128 | p2 200x128]

  float* w = (float*)d_ws;
  size_t off = 0;
  auto alloc = [&](size_t nfl){ float* p = w + off; off += nfl; return p; };

  float* dflag = alloc(1);
  float* dinv = alloc(N);

  float* wf[41] = {nullptr};
  CastBatch cb;
  int nw = 0;
  for (int t = 3; t < 41; t++){
    if (t == 27 || t == 28) continue;            // Wk2/bk2 dead (1-seed pool)
    float* p = alloc((size_t)in_sizes[t]);
    wf[t] = p;
    cb.src[nw] = d_in[t];
    cb.dst[nw] = p;
    cb.n[nw]   = in_sizes[t];
    nw++;
  }

  float* P0 = alloc((size_t)N * 256);   // xcat = [x1 | x2]
  float* P1 = alloc((size_t)N * 256);   // xf, xagg; later attn0 slabs
  float* P2 = alloc((size_t)N * 256);   // t1/t2, Kd; later V2
  float* P3 = alloc((size_t)N * 256);   // Vd; later SAB slabs
  float* Sbuf = alloc((size_t)G * HH * KS1 * MAXN);  // 2M floats; aliased as adjacency A
  float* Q0   = alloc(25 * 256);
  float* Q2c  = alloc(128);
  float* O2   = alloc((size_t)G * 128);
  float* O2f  = alloc((size_t)G * 128);
  float* zb   = alloc((size_t)G * 128);
  float* z1   = alloc((size_t)G * 128);
  float* z2   = alloc((size_t)G * 64);
  if (off * sizeof(float) > ws_size) return;

  float* Adj = Sbuf;                    // A[g][100][100], dead before attention uses Sbuf
  float* xf = P1;
  float* Oa = P1;                                   // after xagg dead
  float* O0 = P1 + (size_t)G * KS1 * 256;
  float* Q1v = P3;                                  // SAB slabs (after Vd dead)
  float* K1v = P3 + (size_t)G * KS1 * 128;
  float* V1v = P3 + (size_t)2 * G * KS1 * 128;
  float* Ob  = P3 + (size_t)3 * G * KS1 * 128;
  float* O1  = P3 + (size_t)4 * G * KS1 * 128;
  float* V2  = P2;                                  // after Kd dead

  dim3 blk(256);
  auto gemm = [&](const float* A, int lda, const float* B, int ldb, const float* bias,
                  const float* resid, int ldr, float* C, int ldc, int M, int Nc, int K, int mode){
    dim3 grid(ceil_div(M, BM), ceil_div(Nc, BN));
    gemm_f32<<<grid, blk, 0, stream>>>(A, lda, B, ldb, bias, resid, ldr, C, ldc, M, Nc, K, mode);
  };

  // dtype sniff + casts
  sniff_dtype<<<1, blk, 0, stream>>>((const unsigned short*)d_in[0], dflag);
  cast_in<<<ceil_div(N * FIN, 256), blk, 0, stream>>>(d_in[0], xf, N * FIN, dflag);
  cast_many<<<dim3(64, 36), blk, 0, stream>>>(cb, dflag);

  // symmetric-norm degrees
  deg_init<<<ceil_div(N, 256), blk, 0, stream>>>(dinv, N);
  deg_edges<<<ceil_div(E, 256), blk, 0, stream>>>(dstp, dinv, E);
  deg_fin<<<ceil_div(N, 256), blk, 0, stream>>>(dinv, N);

  // dense normalized adjacency (shared by all propagations)
  adj_init<<<ceil_div(G * MAXN * MAXN, 256), blk, 0, stream>>>(dinv, Adj, G * MAXN * MAXN);
  adj_edges<<<ceil_div(E, 256), blk, 0, stream>>>(srcp, dstp, dinv, Adj, E);

  // GCN1: x1 = relu(A@(x@W1) + b1) -> xcat[:,0:128]; p1 -> out[2000:27600]
  gemm(xf, 128, wf[3], 128, nullptr, nullptr, 0, P2, 128, N, 128, 128, 0);
  prop_gemm<<<dim3(G, 2), blk, 0, stream>>>(Adj, P2, 128, wf[4], P0, 256, 1);
  pool_sum<<<ceil_div(G * 128, 256), blk, 0, stream>>>(P0, 256, out + 2000, G * 128);

  // GCN2: x2 = relu(A@(x1@W2) + b2) -> xcat[:,128:256]; p2 -> out[27600:53200]
  gemm(P0, 256, wf[5], 128, nullptr, nullptr, 0, P2, 128, N, 128, 128, 0);
  prop_gemm<<<dim3(G, 2), blk, 0, stream>>>(Adj, P2, 128, wf[6], P0 + 128, 256, 1);
  pool_sum<<<ceil_div(G * 128, 256), blk, 0, stream>>>(P0 + 128, 256, out + 27600, G * 128);

  // xagg = A @ xcat (propagation is linear: prop(xcat@W) == prop(xcat)@W)
  prop_gemm<<<dim3(G, 4), blk, 0, stream>>>(Adj, P0, 256, nullptr, P1, 256, 0);

  // Kd = xagg@Wk0 + bk0 ; Vd = xagg@Wv0 + bv0
  gemm(P1, 256, wf[10], 256, wf[11], nullptr, 0, P2, 256, N, 256, 256, 0);
  gemm(P1, 256, wf[12], 256, wf[13], nullptr, 0, P3, 256, N, 256, 256, 0);

  // Q0 = S0 @ Wq0 + bq0 (shared across graphs)
  gemm(wf[7], 256, wf[8], 256, wf[9], nullptr, 0, Q0, 256, 25, 256, 256, 0);

  // --- GMPool_G (dv=256, dh=64, nk=100; softmax over q; mask bias == 0: all graphs full) ---
  attn_score<<<dim3(G, HH), blk, 0, stream>>>(Q0, 1, 256, P2, 256, Sbuf, 25, 100, 64, 0.0625f);
  softmax_q<<<ceil_div(G * HH * 100, 256), blk, 0, stream>>>(Sbuf, 25, 100, G * HH * 100);
  attn_av<<<ceil_div(G * 25 * 256, 256), blk, 0, stream>>>(Sbuf, P3, 256, Q0, 1, 256, Oa, 256, 25, 100, HH, 64, G * 25 * 256);
  gemm(Oa, 256, wf[14], 256, wf[15], Oa, 256, O0, 256, G * KS1, 256, 256, 2);

  // --- SAB (dv=128, dh=32, nk=25) ---
  gemm(O0, 256, wf[16], 128, wf[17], nullptr, 0, Q1v, 128, G * KS1, 128, 256, 0);
  gemm(O0, 256, wf[18], 128, wf[19], nullptr, 0, K1v, 128, G * KS1, 128, 256, 0);
  gemm(O0, 256, wf[20], 128, wf[21], nullptr, 0, V1v, 128, G * KS1, 128, 256, 0);
  attn_score<<<dim3(G, HH), blk, 0, stream>>>(Q1v, 0, 128, K1v, 128, Sbuf, 25, 25, 32, 0.0883883476f);
  softmax_q<<<ceil_div(G * HH * 25, 256), blk, 0, stream>>>(Sbuf, 25, 25, G * HH * 25);
  attn_av<<<ceil_div(G * 25 * 128, 256), blk, 0, stream>>>(Sbuf, V1v, 128, Q1v, 0, 128, Ob, 128, 25, 25, HH, 32, G * 25 * 128);
  gemm(Ob, 128, wf[22], 128, wf[23], Ob, 128, O1, 128, G * KS1, 128, 128, 2);

  // --- GMPool_I (1 seed; q-softmax over size-1 axis == 1 -> plain sum; Wk2 unused) ---
  gemm(O1, 128, wf[29], 128, wf[30], nullptr, 0, V2, 128, G * KS1, 128, 128, 0);
  gemm(wf[24], 128, wf[25], 128, wf[26], nullptr, 0, Q2c, 128, 1, 128, 128, 0);
  seed_sum<<<ceil_div(G * 128, 256), blk, 0, stream>>>(V2, Q2c, O2, G * 128);
  gemm(O2, 128, wf[31], 128, wf[32], O2, 128, O2f, 128, G, 128, 128, 2);

  // classifier head -> logits to out[0:2000]
  gemm(O2f, 128, wf[33], 128, wf[34], nullptr, 0, zb, 128, G, 128, 128, 0);
  gemm(zb, 128, wf[35], 128, wf[36], nullptr, 0, z1, 128, G, 128, 128, 1);
  gemm(z1, 128, wf[37], 64, wf[38], nullptr, 0, z2, 64, G, 64, 128, 1);
  gemm(z2, 64, wf[39], 10, wf[40], nullptr, 0, out, 10, G, 10, 64, 0);
}

// Round 5
// 849.937 us; speedup vs baseline: 2.2929x; 1.1838x over previous
//
#include <hip/hip_runtime.h>
#include <hip/hip_bf16.h>
#include <cstdint>
#include <cstddef>

typedef __hip_bfloat16 bf16;

#define MAXN 100
#define HH   4
#define FIN  128
#define KS1  25

static inline int ceil_div(int a, int b){ return (a + b - 1) / b; }

// ---------------- input dtype sniff (inputs proven f32; cheap hedge kept) ----------------
__global__ __launch_bounds__(256) void sniff_dtype(const unsigned short* __restrict__ u,
                                                   float* __restrict__ flag){
  __shared__ int cnt;
  if (threadIdx.x == 0) cnt = 0;
  __syncthreads();
  unsigned short b = u[2 * threadIdx.x];
  unsigned int w = ((unsigned int)b) << 16;
  float v = __uint_as_float(w);
  float a = fabsf(v);
  if (a >= 6.1e-5f && a <= 16384.f) atomicAdd(&cnt, 1);
  __syncthreads();
  if (threadIdx.x == 0) *flag = (cnt >= 128) ? 1.0f : 0.0f;
}

__global__ __launch_bounds__(256) void cast_in(const void* __restrict__ s, float* __restrict__ d,
                                               int n, const float* __restrict__ flag){
  int i = blockIdx.x * 256 + threadIdx.x;
  if (i >= n) return;
  if (*flag != 0.0f) d[i] = __bfloat162float(((const bf16*)s)[i]);
  else               d[i] = ((const float*)s)[i];
}

struct CastBatch {
  const void* src[36];
  float*      dst[36];
  int         n[36];
};

__global__ __launch_bounds__(256) void cast_many(CastBatch cb, const float* __restrict__ flag){
  int t = blockIdx.y;
  int n = cb.n[t];
  bool isbf = (*flag != 0.0f);
  const void* s = cb.src[t];
  float* d = cb.dst[t];
  for (int i = blockIdx.x * 256 + threadIdx.x; i < n; i += gridDim.x * 256)
    d[i] = isbf ? __bfloat162float(((const bf16*)s)[i]) : ((const float*)s)[i];
}

// ---------------- degree / norm ----------------
__global__ __launch_bounds__(256) void deg_init(float* deg, int n){
  int i = blockIdx.x * 256 + threadIdx.x;
  if (i < n) deg[i] = 1.0f;                        // self-loop
}
__global__ __launch_bounds__(256) void deg_edges(const int* __restrict__ dst, float* deg, int e){
  int i = blockIdx.x * 256 + threadIdx.x;
  if (i < e) atomicAdd(&deg[dst[i]], 1.0f);
}
__global__ __launch_bounds__(256) void deg_fin(float* deg, int n){
  int i = blockIdx.x * 256 + threadIdx.x;
  if (i < n) deg[i] = 1.0f / sqrtf(deg[i]);
}

// ---------------- dense normalized adjacency A[g][dst_local][src_local] ----------------
__global__ __launch_bounds__(256) void adj_init(const float* __restrict__ dinv,
                                                float* __restrict__ A, int total){
  int i = blockIdx.x * 256 + threadIdx.x;
  if (i >= total) return;
  int g = i / (MAXN * MAXN);
  int rem = i - g * (MAXN * MAXN);
  int r = rem / MAXN, s = rem - r * MAXN;
  float v = 0.f;
  if (r == s){ float dv = dinv[g * MAXN + r]; v = dv * dv; }
  A[i] = v;
}

__global__ __launch_bounds__(256) void adj_edges(const int* __restrict__ src, const int* __restrict__ dst,
                                                 const float* __restrict__ dinv,
                                                 float* __restrict__ A, int e){
  int i = blockIdx.x * 256 + threadIdx.x;
  if (i >= e) return;
  int s = src[i], d = dst[i];
  int g = d / MAXN;
  int dl = d - g * MAXN;
  int sl = s - (s / MAXN) * MAXN;
  atomicAdd(&A[(size_t)g * (MAXN * MAXN) + dl * MAXN + sl], dinv[s] * dinv[d]);
}

// ---------------- batched dense propagation ----------------
#define ASTRIDE 101
#define TSTRIDE 68
__global__ __launch_bounds__(256) void prop_gemm(
    const float* __restrict__ A,
    const float* __restrict__ T, int ldt,
    const float* __restrict__ bias,
    float* __restrict__ Y, int ldy,
    int relu)
{
  __shared__ float As[112 * ASTRIDE];
  __shared__ float Ts[MAXN * TSTRIDE];
  int g = blockIdx.x;
  int c0 = blockIdx.y * 64;
  int tid = threadIdx.x;
  const float* Ag = A + (size_t)g * (MAXN * MAXN);
  for (int i = tid; i < MAXN * MAXN; i += 256){
    int r = i / MAXN, s = i - r * MAXN;
    As[r * ASTRIDE + s] = Ag[i];
  }
  for (int i = tid; i < MAXN * 16; i += 256){
    int s = i >> 4, jj = i & 15;
    float4 v = *reinterpret_cast<const float4*>(&T[(size_t)(g * MAXN + s) * ldt + c0 + jj * 4]);
    *reinterpret_cast<float4*>(&Ts[s * TSTRIDE + jj * 4]) = v;
  }
  __syncthreads();

  int tx = tid & 15, ty = tid >> 4;
  float acc[7][4] = {};
#pragma unroll 2
  for (int s = 0; s < MAXN; s++){
    float4 t4 = *reinterpret_cast<const float4*>(&Ts[s * TSTRIDE + tx * 4]);
    float t[4] = {t4.x, t4.y, t4.z, t4.w};
#pragma unroll
    for (int i = 0; i < 7; i++){
      float a = As[(ty * 7 + i) * ASTRIDE + s];
#pragma unroll
      for (int j = 0; j < 4; j++) acc[i][j] = fmaf(a, t[j], acc[i][j]);
    }
  }

  float4 b4 = make_float4(0.f, 0.f, 0.f, 0.f);
  if (bias) b4 = *reinterpret_cast<const float4*>(&bias[c0 + tx * 4]);
#pragma unroll
  for (int i = 0; i < 7; i++){
    int r = ty * 7 + i;
    if (r >= MAXN) continue;
    float v0 = acc[i][0] + b4.x, v1 = acc[i][1] + b4.y, v2 = acc[i][2] + b4.z, v3 = acc[i][3] + b4.w;
    if (relu){ v0 = fmaxf(v0, 0.f); v1 = fmaxf(v1, 0.f); v2 = fmaxf(v2, 0.f); v3 = fmaxf(v3, 0.f); }
    float4 o = make_float4(v0, v1, v2, v3);
    *reinterpret_cast<float4*>(&Y[(size_t)(g * MAXN + r) * ldy + c0 + tx * 4]) = o;
  }
}

// ---------------- generic fp32 GEMM ----------------
#define BM 64
#define BN 64
#define BK 16
__global__ __launch_bounds__(256) void gemm_f32(
    const float* __restrict__ A, int lda,
    const float* __restrict__ B, int ldb,
    const float* __restrict__ bias,
    const float* __restrict__ resid, int ldr,
    float* __restrict__ C, int ldc,
    int M, int Nn, int K, int mode)
{
  __shared__ __align__(16) float As[BK][BM + 4];
  __shared__ __align__(16) float Bs[BK][BN + 4];
  int bm = blockIdx.x * BM, bn = blockIdx.y * BN;
  int tid = threadIdx.x;
  int tx = tid & 15, ty = tid >> 4;
  float acc[4][4] = {};
  for (int k0 = 0; k0 < K; k0 += BK){
    for (int i = tid; i < BM * BK; i += 256){
      int r = i >> 4, kk = i & 15;
      int gr = bm + r;
      As[kk][r] = (gr < M) ? A[(size_t)gr * lda + k0 + kk] : 0.f;
    }
    for (int i = tid; i < BK * BN; i += 256){
      int r = i >> 6, c = i & 63;
      int gc = bn + c;
      Bs[r][c] = (gc < Nn) ? B[(size_t)(k0 + r) * ldb + gc] : 0.f;
    }
    __syncthreads();
#pragma unroll
    for (int kk = 0; kk < BK; kk++){
      float4 a4 = *reinterpret_cast<const float4*>(&As[kk][ty * 4]);
      float4 b4 = *reinterpret_cast<const float4*>(&Bs[kk][tx * 4]);
      float a[4] = {a4.x, a4.y, a4.z, a4.w};
      float b[4] = {b4.x, b4.y, b4.z, b4.w};
#pragma unroll
      for (int i = 0; i < 4; i++)
#pragma unroll
        for (int j = 0; j < 4; j++)
          acc[i][j] = fmaf(a[i], b[j], acc[i][j]);
    }
    __syncthreads();
  }
#pragma unroll
  for (int i = 0; i < 4; i++){
    int gr = bm + ty * 4 + i;
    if (gr >= M) continue;
#pragma unroll
    for (int j = 0; j < 4; j++){
      int gc = bn + tx * 4 + j;
      if (gc >= Nn) continue;
      float v = acc[i][j];
      if (bias) v += bias[gc];
      if (mode == 1) v = fmaxf(v, 0.f);
      else if (mode == 2) v = resid[(size_t)gr * ldr + gc] + fmaxf(v, 0.f);
      C[(size_t)gr * ldc + gc] = v;
    }
  }
}

// ---------------- pooling ----------------
__global__ __launch_bounds__(256) void pool_sum(const float* __restrict__ x, int ldx,
    float* __restrict__ out, int total)
{
  int i = blockIdx.x * 256 + threadIdx.x;
  if (i >= total) return;
  int g = i >> 7, c = i & 127;
  float s = 0.f;
  const float* p = x + (size_t)g * MAXN * ldx + c;
  for (int k = 0; k < MAXN; k++) s += p[(size_t)k * ldx];
  out[i] = s;
}

// ---------------- Ubar precompute: Ubar[e, j=h*25+q] = (1/16)*sum_d Wk0[e,h*64+d]*Q0[q,h*64+d]
// cvec[j] = (1/16)*sum_d bk0[h*64+d]*Q0[q,h*64+d]   (score GEMM trick: Q0 shared over graphs)
__global__ __launch_bounds__(256) void ubar_make(const float* __restrict__ Wk0,
    const float* __restrict__ bk0, const float* __restrict__ Q0,
    float* __restrict__ Ubar, float* __restrict__ cvec)
{
  int j = blockIdx.x;            // 0..99
  int h = j / 25, q = j - h * 25;
  int e = threadIdx.x;           // 0..255
  const float* qp = &Q0[q * 256 + h * 64];
  const float* wp = &Wk0[(size_t)e * 256 + h * 64];
  float acc = 0.f;
#pragma unroll
  for (int d = 0; d < 64; d++) acc = fmaf(wp[d], qp[d], acc);
  Ubar[(size_t)e * 100 + j] = acc * 0.0625f;
  if (e == 0){
    float cb = 0.f;
    const float* bp = &bk0[h * 64];
    for (int d = 0; d < 64; d++) cb = fmaf(bp[d], qp[d], cb);
    cvec[j] = cb * 0.0625f;
  }
}

// ---------------- GMPool_G fused softmax(q) + AV + residual ----------------
// S2d[g*100+k, h*25+q] already contains scaled scores. One block per graph.
__global__ __launch_bounds__(256) void av_pool0(const float* __restrict__ S2d,
    const float* __restrict__ Vd, const float* __restrict__ Q0,
    float* __restrict__ O)
{
  __shared__ float Ssh[100 * 101];
  int g = blockIdx.x;
  int tid = threadIdx.x;
  for (int i = tid; i < 100 * 100; i += 256){
    int k = i / 100, j = i - k * 100;
    Ssh[k * 101 + j] = S2d[(size_t)(g * 100 + k) * 100 + j];
  }
  __syncthreads();
  // softmax over q for each (k,h)
  for (int p = tid; p < 400; p += 256){
    int k = p >> 2, h = p & 3;
    float* base = &Ssh[k * 101 + h * 25];
    float m = -1e30f;
#pragma unroll
    for (int q = 0; q < 25; q++) m = fmaxf(m, base[q]);
    float s = 0.f;
#pragma unroll
    for (int q = 0; q < 25; q++){ float e = __expf(base[q] - m); base[q] = e; s += e; }
    float inv = 1.0f / s;
#pragma unroll
    for (int q = 0; q < 25; q++) base[q] *= inv;
  }
  __syncthreads();
  // AV: thread = column c; A broadcast from LDS (h uniform per wave)
  int c = tid;
  int h = c >> 6;
  float acc[25] = {};
  const float* vp = Vd + (size_t)g * 100 * 256 + c;
  for (int k = 0; k < 100; k++){
    float v = vp[(size_t)k * 256];
    const float* a = &Ssh[k * 101 + h * 25];
#pragma unroll
    for (int q = 0; q < 25; q++) acc[q] = fmaf(a[q], v, acc[q]);
  }
#pragma unroll
  for (int q = 0; q < 25; q++)
    O[(size_t)(g * 25 + q) * 256 + c] = Q0[q * 256 + c] + acc[q];
}

// ---------------- SAB fully-fused attention (nq=nk=25, dv=128, dh=32) ----------------
#define SST 132
__global__ __launch_bounds__(256) void sab_attn(const float* __restrict__ Q1,
    const float* __restrict__ K1, const float* __restrict__ V1,
    float* __restrict__ O)
{
  __shared__ float Qs[25 * SST];
  __shared__ float Ks[25 * SST];
  __shared__ float Vs[25 * SST];
  __shared__ float Ss[4 * 25 * 26];
  int g = blockIdx.x;
  int tid = threadIdx.x;
  for (int i = tid; i < 25 * 32; i += 256){
    int r = i >> 5, jj = i & 31;
    size_t src = (size_t)(g * 25 + r) * 128 + jj * 4;
    *reinterpret_cast<float4*>(&Qs[r * SST + jj * 4]) = *reinterpret_cast<const float4*>(&Q1[src]);
    *reinterpret_cast<float4*>(&Ks[r * SST + jj * 4]) = *reinterpret_cast<const float4*>(&K1[src]);
    *reinterpret_cast<float4*>(&Vs[r * SST + jj * 4]) = *reinterpret_cast<const float4*>(&V1[src]);
  }
  __syncthreads();
  // scores
  for (int idx = tid; idx < 2500; idx += 256){
    int h = idx / 625;
    int r = idx - h * 625;
    int q = r / 25, k = r - q * 25;
    const float* qp = &Qs[q * SST + h * 32];
    const float* kp = &Ks[k * SST + h * 32];
    float acc = 0.f;
#pragma unroll
    for (int d = 0; d < 32; d += 4){
      float4 a4 = *reinterpret_cast<const float4*>(&qp[d]);
      float4 b4 = *reinterpret_cast<const float4*>(&kp[d]);
      acc = fmaf(a4.x, b4.x, acc); acc = fmaf(a4.y, b4.y, acc);
      acc = fmaf(a4.z, b4.z, acc); acc = fmaf(a4.w, b4.w, acc);
    }
    Ss[(h * 25 + q) * 26 + k] = acc * 0.0883883476f;
  }
  __syncthreads();
  // softmax over q per (h,k)
  if (tid < 100){
    int h = tid / 25, k = tid - h * 25;
    float m = -1e30f;
#pragma unroll
    for (int q = 0; q < 25; q++) m = fmaxf(m, Ss[(h * 25 + q) * 26 + k]);
    float s = 0.f;
#pragma unroll
    for (int q = 0; q < 25; q++){ float e = __expf(Ss[(h * 25 + q) * 26 + k] - m); Ss[(h * 25 + q) * 26 + k] = e; s += e; }
    float inv = 1.0f / s;
#pragma unroll
    for (int q = 0; q < 25; q++) Ss[(h * 25 + q) * 26 + k] *= inv;
  }
  __syncthreads();
  // AV + residual
  if (tid < 128){
    int c = tid, h = c >> 5;
    float acc[25] = {};
    for (int k = 0; k < 25; k++){
      float v = Vs[k * SST + c];
#pragma unroll
      for (int q = 0; q < 25; q++) acc[q] = fmaf(Ss[(h * 25 + q) * 26 + k], v, acc[q]);
    }
#pragma unroll
    for (int q = 0; q < 25; q++)
      O[(size_t)(g * 25 + q) * 128 + c] = Qs[q * SST + c] + acc[q];
  }
}

// ---------------- GMPool_I 1-seed: O2[g,c] = Q2[c] + sum_k V2[g,k,c] ----------------
__global__ __launch_bounds__(256) void seed_sum(const float* __restrict__ V, const float* __restrict__ Qc,
    float* __restrict__ O, int total)
{
  int i = blockIdx.x * 256 + threadIdx.x;
  if (i >= total) return;
  int g = i >> 7, c = i & 127;
  float acc = Qc[c];
  const float* p = V + (size_t)(g * KS1) * 128 + c;
  for (int k = 0; k < KS1; k++) acc += p[k * 128];
  O[i] = acc;
}

// ---------------- host ----------------
extern "C" void kernel_launch(void* const* d_in, const int* in_sizes, int n_in,
                              void* d_out, int out_size, void* d_ws, size_t ws_size,
                              hipStream_t stream)
{
  const int*  edge = (const int*)d_in[1];
  const int N = in_sizes[0] / FIN;      // 20000
  const int E = in_sizes[1] / 2;        // 320000
  const int G = N / MAXN;               // 200
  const int* srcp = edge;
  const int* dstp = edge + E;
  float* out = (float*)d_out;           // f32: [logits 200x10 | p1 200x128 | p2 200x128]

  float* w = (float*)d_ws;
  size_t off = 0;
  auto alloc = [&](size_t nfl){ float* p = w + off; off += nfl; return p; };

  float* dflag = alloc(1);
  float* dinv = alloc(N);

  float* wf[41] = {nullptr};
  CastBatch cb;
  int nw = 0;
  for (int t = 3; t < 41; t++){
    if (t == 27 || t == 28) continue;            // Wk2/bk2 dead (1-seed pool)
    float* p = alloc((size_t)in_sizes[t]);
    wf[t] = p;
    cb.src[nw] = d_in[t];
    cb.dst[nw] = p;
    cb.n[nw]   = in_sizes[t];
    nw++;
  }

  float* P0 = alloc((size_t)N * 256);   // xcat
  float* P1 = alloc((size_t)N * 256);   // xf -> xagg -> [Oa | O0]
  float* P2 = alloc((size_t)N * 256);   // gemm temps; later V2
  float* P3 = alloc((size_t)N * 256);   // Vd; later SAB slabs
  float* Sbuf = alloc((size_t)G * HH * KS1 * MAXN);  // Adj, then S2d [N x 100]
  float* Q0   = alloc(25 * 256);
  float* Ubar = alloc(256 * 100);
  float* cvec = alloc(100);
  float* Q2c  = alloc(128);
  float* O2   = alloc((size_t)G * 128);
  float* O2f  = alloc((size_t)G * 128);
  float* zb   = alloc((size_t)G * 128);
  float* z1   = alloc((size_t)G * 128);
  float* z2   = alloc((size_t)G * 64);
  if (off * sizeof(float) > ws_size) return;

  float* Adj = Sbuf;                    // dead before S_gemm writes S2d
  float* S2d = Sbuf;
  float* xf = P1;
  float* Oa = P1;
  float* O0 = P1 + (size_t)G * KS1 * 256;
  float* Q1v = P3;                      // after Vd dead
  float* K1v = P3 + (size_t)G * KS1 * 128;
  float* V1v = P3 + (size_t)2 * G * KS1 * 128;
  float* Ob  = P3 + (size_t)3 * G * KS1 * 128;
  float* O1  = P3 + (size_t)4 * G * KS1 * 128;
  float* V2  = P2;

  dim3 blk(256);
  auto gemm = [&](const float* A, int lda, const float* B, int ldb, const float* bias,
                  const float* resid, int ldr, float* C, int ldc, int M, int Nc, int K, int mode){
    dim3 grid(ceil_div(M, BM), ceil_div(Nc, BN));
    gemm_f32<<<grid, blk, 0, stream>>>(A, lda, B, ldb, bias, resid, ldr, C, ldc, M, Nc, K, mode);
  };

  // dtype sniff + casts
  sniff_dtype<<<1, blk, 0, stream>>>((const unsigned short*)d_in[0], dflag);
  cast_in<<<ceil_div(N * FIN, 256), blk, 0, stream>>>(d_in[0], xf, N * FIN, dflag);
  cast_many<<<dim3(64, 36), blk, 0, stream>>>(cb, dflag);

  // degrees + dense normalized adjacency
  deg_init<<<ceil_div(N, 256), blk, 0, stream>>>(dinv, N);
  deg_edges<<<ceil_div(E, 256), blk, 0, stream>>>(dstp, dinv, E);
  deg_fin<<<ceil_div(N, 256), blk, 0, stream>>>(dinv, N);
  adj_init<<<ceil_div(G * MAXN * MAXN, 256), blk, 0, stream>>>(dinv, Adj, G * MAXN * MAXN);
  adj_edges<<<ceil_div(E, 256), blk, 0, stream>>>(srcp, dstp, dinv, Adj, E);

  // GCN1 / GCN2 + pools
  gemm(xf, 128, wf[3], 128, nullptr, nullptr, 0, P2, 128, N, 128, 128, 0);
  prop_gemm<<<dim3(G, 2), blk, 0, stream>>>(Adj, P2, 128, wf[4], P0, 256, 1);
  pool_sum<<<ceil_div(G * 128, 256), blk, 0, stream>>>(P0, 256, out + 2000, G * 128);

  gemm(P0, 256, wf[5], 128, nullptr, nullptr, 0, P2, 128, N, 128, 128, 0);
  prop_gemm<<<dim3(G, 2), blk, 0, stream>>>(Adj, P2, 128, wf[6], P0 + 128, 256, 1);
  pool_sum<<<ceil_div(G * 128, 256), blk, 0, stream>>>(P0 + 128, 256, out + 27600, G * 128);

  // xagg = A @ xcat (linearity: prop(xcat@W) == prop(xcat)@W)
  prop_gemm<<<dim3(G, 4), blk, 0, stream>>>(Adj, P0, 256, nullptr, P1, 256, 0);

  // Q0 = S0@Wq0+bq0 (shared); Ubar trick replaces the whole Kd GEMM + score kernel
  gemm(wf[7], 256, wf[8], 256, wf[9], nullptr, 0, Q0, 256, 25, 256, 256, 0);
  ubar_make<<<dim3(100), blk, 0, stream>>>(wf[10], wf[11], Q0, Ubar, cvec);

  // Vd = xagg@Wv0 + bv0
  gemm(P1, 256, wf[12], 256, wf[13], nullptr, 0, P3, 256, N, 256, 256, 0);

  // S2d[N,100] = xagg @ Ubar + cvec (scale folded); NOTE: overwrites Adj (dead)
  gemm(P1, 256, Ubar, 100, cvec, nullptr, 0, S2d, 100, N, 100, 256, 0);

  // fused q-softmax + AV + residual
  av_pool0<<<dim3(G), blk, 0, stream>>>(S2d, P3, Q0, Oa);
  gemm(Oa, 256, wf[14], 256, wf[15], Oa, 256, O0, 256, G * KS1, 256, 256, 2);

  // --- SAB ---
  gemm(O0, 256, wf[16], 128, wf[17], nullptr, 0, Q1v, 128, G * KS1, 128, 256, 0);
  gemm(O0, 256, wf[18], 128, wf[19], nullptr, 0, K1v, 128, G * KS1, 128, 256, 0);
  gemm(O0, 256, wf[20], 128, wf[21], nullptr, 0, V1v, 128, G * KS1, 128, 256, 0);
  sab_attn<<<dim3(G), blk, 0, stream>>>(Q1v, K1v, V1v, Ob);
  gemm(Ob, 128, wf[22], 128, wf[23], Ob, 128, O1, 128, G * KS1, 128, 128, 2);

  // --- GMPool_I (1 seed) ---
  gemm(O1, 128, wf[29], 128, wf[30], nullptr, 0, V2, 128, G * KS1, 128, 128, 0);
  gemm(wf[24], 128, wf[25], 128, wf[26], nullptr, 0, Q2c, 128, 1, 128, 128, 0);
  seed_sum<<<ceil_div(G * 128, 256), blk, 0, stream>>>(V2, Q2c, O2, G * 128);
  gemm(O2, 128, wf[31], 128, wf[32], O2, 128, O2f, 128, G, 128, 128, 2);

  // classifier head -> logits to out[0:2000]
  gemm(O2f, 128, wf[33], 128, wf[34], nullptr, 0, zb, 128, G, 128, 128, 0);
  gemm(zb, 128, wf[35], 128, wf[36], nullptr, 0, z1, 128, G, 128, 128, 1);
  gemm(z1, 128, wf[37], 64, wf[38], nullptr, 0, z2, 64, G, 64, 128, 1);
  gemm(z2, 64, wf[39], 10, wf[40], nullptr, 0, out, 10, G, 10, 64, 0);
}

// Round 6
// 622.084 us; speedup vs baseline: 3.1327x; 1.3663x over previous
//
#include <hip/hip_runtime.h>
#include <hip/hip_bf16.h>
#include <cstdint>
#include <cstddef>

typedef __hip_bfloat16 bf16;
typedef __attribute__((ext_vector_type(8))) short s16x8;
typedef __attribute__((ext_vector_type(4))) float f32x4;

#define MAXN 100
#define HH   4
#define FIN  128
#define KS1  25

static inline int ceil_div(int a, int b){ return (a + b - 1) / b; }

__device__ inline short f2bf(float f){               // RNE float->bf16 bits
  unsigned int u = __float_as_uint(f);
  u = (u + 0x7FFF + ((u >> 16) & 1)) >> 16;
  return (short)u;
}

// ---------------- input dtype sniff (inputs proven f32; cheap hedge kept) ----------------
__global__ __launch_bounds__(256) void sniff_dtype(const unsigned short* __restrict__ u,
                                                   float* __restrict__ flag){
  __shared__ int cnt;
  if (threadIdx.x == 0) cnt = 0;
  __syncthreads();
  unsigned short b = u[2 * threadIdx.x];
  unsigned int w = ((unsigned int)b) << 16;
  float v = __uint_as_float(w);
  float a = fabsf(v);
  if (a >= 6.1e-5f && a <= 16384.f) atomicAdd(&cnt, 1);
  __syncthreads();
  if (threadIdx.x == 0) *flag = (cnt >= 128) ? 1.0f : 0.0f;
}

__global__ __launch_bounds__(256) void cast_in(const void* __restrict__ s, float* __restrict__ d,
                                               int n, const float* __restrict__ flag){
  int i = blockIdx.x * 256 + threadIdx.x;
  if (i >= n) return;
  if (*flag != 0.0f) d[i] = __bfloat162float(((const bf16*)s)[i]);
  else               d[i] = ((const float*)s)[i];
}

struct CastBatch {
  const void* src[36];
  float*      dst[36];
  int         n[36];
};

__global__ __launch_bounds__(256) void cast_many(CastBatch cb, const float* __restrict__ flag){
  int t = blockIdx.y;
  int n = cb.n[t];
  bool isbf = (*flag != 0.0f);
  const void* s = cb.src[t];
  float* d = cb.dst[t];
  for (int i = blockIdx.x * 256 + threadIdx.x; i < n; i += gridDim.x * 256)
    d[i] = isbf ? __bfloat162float(((const bf16*)s)[i]) : ((const float*)s)[i];
}

// ---------------- weight transpose+convert: Wt[n][k] = bf16(W[k][n]), ld = K+8 ----------------
struct WprepBatch {
  const float* W[9];
  short*       Wt[9];
  int          K[9];
  int          Nn[9];
};

__global__ __launch_bounds__(256) void wprep_many(WprepBatch wb){
  int t = blockIdx.y;
  int K = wb.K[t], Nn = wb.Nn[t], ldt = K + 8;
  const float* W = wb.W[t];
  short* Wt = wb.Wt[t];
  int total = K * Nn;
  for (int i = blockIdx.x * 256 + threadIdx.x; i < total; i += gridDim.x * 256){
    int k = i / Nn, n = i - k * Nn;
    Wt[(size_t)n * ldt + k] = f2bf(W[i]);
  }
}

// ---------------- degree / norm ----------------
__global__ __launch_bounds__(256) void deg_init(float* deg, int n){
  int i = blockIdx.x * 256 + threadIdx.x;
  if (i < n) deg[i] = 1.0f;
}
__global__ __launch_bounds__(256) void deg_edges(const int* __restrict__ dst, float* deg, int e){
  int i = blockIdx.x * 256 + threadIdx.x;
  if (i < e) atomicAdd(&deg[dst[i]], 1.0f);
}
__global__ __launch_bounds__(256) void deg_fin(float* deg, int n){
  int i = blockIdx.x * 256 + threadIdx.x;
  if (i < n) deg[i] = 1.0f / sqrtf(deg[i]);
}

// ---------------- dense normalized adjacency ----------------
__global__ __launch_bounds__(256) void adj_init(const float* __restrict__ dinv,
                                                float* __restrict__ A, int total){
  int i = blockIdx.x * 256 + threadIdx.x;
  if (i >= total) return;
  int g = i / (MAXN * MAXN);
  int rem = i - g * (MAXN * MAXN);
  int r = rem / MAXN, s = rem - r * MAXN;
  float v = 0.f;
  if (r == s){ float dv = dinv[g * MAXN + r]; v = dv * dv; }
  A[i] = v;
}

__global__ __launch_bounds__(256) void adj_edges(const int* __restrict__ src, const int* __restrict__ dst,
                                                 const float* __restrict__ dinv,
                                                 float* __restrict__ A, int e){
  int i = blockIdx.x * 256 + threadIdx.x;
  if (i >= e) return;
  int s = src[i], d = dst[i];
  int g = d / MAXN;
  int dl = d - g * MAXN;
  int sl = s - (s / MAXN) * MAXN;
  atomicAdd(&A[(size_t)g * (MAXN * MAXN) + dl * MAXN + sl], dinv[s] * dinv[d]);
}

// ---------------- batched dense propagation (fp32; adjacency path) ----------------
#define ASTRIDE 101
#define TSTRIDE 68
__global__ __launch_bounds__(256) void prop_gemm(
    const float* __restrict__ A,
    const float* __restrict__ T, int ldt,
    const float* __restrict__ bias,
    float* __restrict__ Y, int ldy,
    int relu)
{
  __shared__ float As[112 * ASTRIDE];
  __shared__ float Ts[MAXN * TSTRIDE];
  int g = blockIdx.x;
  int c0 = blockIdx.y * 64;
  int tid = threadIdx.x;
  const float* Ag = A + (size_t)g * (MAXN * MAXN);
  for (int i = tid; i < MAXN * MAXN; i += 256){
    int r = i / MAXN, s = i - r * MAXN;
    As[r * ASTRIDE + s] = Ag[i];
  }
  for (int i = tid; i < MAXN * 16; i += 256){
    int s = i >> 4, jj = i & 15;
    float4 v = *reinterpret_cast<const float4*>(&T[(size_t)(g * MAXN + s) * ldt + c0 + jj * 4]);
    *reinterpret_cast<float4*>(&Ts[s * TSTRIDE + jj * 4]) = v;
  }
  __syncthreads();

  int tx = tid & 15, ty = tid >> 4;
  float acc[7][4] = {};
#pragma unroll 2
  for (int s = 0; s < MAXN; s++){
    float4 t4 = *reinterpret_cast<const float4*>(&Ts[s * TSTRIDE + tx * 4]);
    float t[4] = {t4.x, t4.y, t4.z, t4.w};
#pragma unroll
    for (int i = 0; i < 7; i++){
      float a = As[(ty * 7 + i) * ASTRIDE + s];
#pragma unroll
      for (int j = 0; j < 4; j++) acc[i][j] = fmaf(a, t[j], acc[i][j]);
    }
  }

  float4 b4 = make_float4(0.f, 0.f, 0.f, 0.f);
  if (bias) b4 = *reinterpret_cast<const float4*>(&bias[c0 + tx * 4]);
#pragma unroll
  for (int i = 0; i < 7; i++){
    int r = ty * 7 + i;
    if (r >= MAXN) continue;
    float v0 = acc[i][0] + b4.x, v1 = acc[i][1] + b4.y, v2 = acc[i][2] + b4.z, v3 = acc[i][3] + b4.w;
    if (relu){ v0 = fmaxf(v0, 0.f); v1 = fmaxf(v1, 0.f); v2 = fmaxf(v2, 0.f); v3 = fmaxf(v3, 0.f); }
    float4 o = make_float4(v0, v1, v2, v3);
    *reinterpret_cast<float4*>(&Y[(size_t)(g * MAXN + r) * ldy + c0 + tx * 4]) = o;
  }
}

// ---------------- MFMA bf16 GEMM: C = epi(A[M,K] @ Bt[N,K]^T + bias) ----------------
// A fp32 (converted on stage), Bt pre-converted bf16 with ld = K+8.
// Block: 64x64 tile, 4 waves (wave w -> cols w*16..+16, rows 0..63 as 4 MFMA tiles).
// Layouts per guide (m89/m92-verified): A-frag A[m=lane&15][k=quad*8+j];
// B-frag B[k=quad*8+j][n=lane&15] (from Bt rows); C/D col=lane&15,row=quad*4+r.
__global__ __launch_bounds__(256) void gemm_bf16(
    const float* __restrict__ A, int lda,
    const short* __restrict__ Bt, int ldbt,
    const float* __restrict__ bias,
    const float* __restrict__ resid, int ldr,
    float* __restrict__ C, int ldc,
    int M, int Nn, int K, int mode)
{
  extern __shared__ short lds[];
  const int ldk = K + 8;                 // 264 or 136: stride%32dw==4 -> conflict-benign
  short* As = lds;
  short* Bs = lds + 64 * ldk;
  int bm = blockIdx.x * 64, bn = blockIdx.y * 64;
  int tid = threadIdx.x;
  int ku = K >> 3;
  for (int u = tid; u < 64 * ku; u += 256){
    int r = u / ku, k8 = (u - r * ku) << 3;
    int gr = bm + r;
    s16x8 v;
    if (gr < M){
      const float* ap = &A[(size_t)gr * lda + k8];
      float4 f0 = *reinterpret_cast<const float4*>(ap);
      float4 f1 = *reinterpret_cast<const float4*>(ap + 4);
      v[0] = f2bf(f0.x); v[1] = f2bf(f0.y); v[2] = f2bf(f0.z); v[3] = f2bf(f0.w);
      v[4] = f2bf(f1.x); v[5] = f2bf(f1.y); v[6] = f2bf(f1.z); v[7] = f2bf(f1.w);
    } else {
#pragma unroll
      for (int j = 0; j < 8; j++) v[j] = 0;
    }
    *reinterpret_cast<s16x8*>(&As[r * ldk + k8]) = v;
  }
  for (int u = tid; u < 64 * ku; u += 256){
    int n = u / ku, k8 = (u - n * ku) << 3;
    int gn = bn + n;
    s16x8 v;
    if (gn < Nn) v = *reinterpret_cast<const s16x8*>(&Bt[(size_t)gn * ldbt + k8]);
    else {
#pragma unroll
      for (int j = 0; j < 8; j++) v[j] = 0;
    }
    *reinterpret_cast<s16x8*>(&Bs[n * ldk + k8]) = v;
  }
  __syncthreads();

  int wave = tid >> 6, lane = tid & 63;
  int quad = lane >> 4, l16 = lane & 15;
  f32x4 acc0 = {0.f,0.f,0.f,0.f}, acc1 = acc0, acc2 = acc0, acc3 = acc0;
  const short* brow = &Bs[(wave * 16 + l16) * ldk];
  const short* arow = &As[l16 * ldk];
  for (int kt = 0; kt < K; kt += 32){
    int kb = kt + quad * 8;
    s16x8 bfr = *reinterpret_cast<const s16x8*>(&brow[kb]);
    s16x8 a0 = *reinterpret_cast<const s16x8*>(&arow[kb]);
    s16x8 a1 = *reinterpret_cast<const s16x8*>(&arow[16 * ldk + kb]);
    s16x8 a2 = *reinterpret_cast<const s16x8*>(&arow[32 * ldk + kb]);
    s16x8 a3 = *reinterpret_cast<const s16x8*>(&arow[48 * ldk + kb]);
    acc0 = __builtin_amdgcn_mfma_f32_16x16x32_bf16(a0, bfr, acc0, 0, 0, 0);
    acc1 = __builtin_amdgcn_mfma_f32_16x16x32_bf16(a1, bfr, acc1, 0, 0, 0);
    acc2 = __builtin_amdgcn_mfma_f32_16x16x32_bf16(a2, bfr, acc2, 0, 0, 0);
    acc3 = __builtin_amdgcn_mfma_f32_16x16x32_bf16(a3, bfr, acc3, 0, 0, 0);
  }
  int gc = bn + wave * 16 + l16;
  if (gc >= Nn) return;
  float bv = bias ? bias[gc] : 0.f;
  f32x4 accs[4] = {acc0, acc1, acc2, acc3};
#pragma unroll
  for (int rt = 0; rt < 4; rt++){
#pragma unroll
    for (int r = 0; r < 4; r++){
      int gr = bm + rt * 16 + quad * 4 + r;
      if (gr >= M) continue;
      float vv = accs[rt][r] + bv;
      if (mode == 1) vv = fmaxf(vv, 0.f);
      else if (mode == 2) vv = resid[(size_t)gr * ldr + gc] + fmaxf(vv, 0.f);
      C[(size_t)gr * ldc + gc] = vv;
    }
  }
}

// ---------------- generic fp32 GEMM (small shapes only now) ----------------
#define BM 64
#define BN 64
#define BK 16
__global__ __launch_bounds__(256) void gemm_f32(
    const float* __restrict__ A, int lda,
    const float* __restrict__ B, int ldb,
    const float* __restrict__ bias,
    const float* __restrict__ resid, int ldr,
    float* __restrict__ C, int ldc,
    int M, int Nn, int K, int mode)
{
  __shared__ __align__(16) float As[BK][BM + 4];
  __shared__ __align__(16) float Bs[BK][BN + 4];
  int bm = blockIdx.x * BM, bn = blockIdx.y * BN;
  int tid = threadIdx.x;
  int tx = tid & 15, ty = tid >> 4;
  float acc[4][4] = {};
  for (int k0 = 0; k0 < K; k0 += BK){
    for (int i = tid; i < BM * BK; i += 256){
      int r = i >> 4, kk = i & 15;
      int gr = bm + r;
      As[kk][r] = (gr < M) ? A[(size_t)gr * lda + k0 + kk] : 0.f;
    }
    for (int i = tid; i < BK * BN; i += 256){
      int r = i >> 6, c = i & 63;
      int gc = bn + c;
      Bs[r][c] = (gc < Nn) ? B[(size_t)(k0 + r) * ldb + gc] : 0.f;
    }
    __syncthreads();
#pragma unroll
    for (int kk = 0; kk < BK; kk++){
      float4 a4 = *reinterpret_cast<const float4*>(&As[kk][ty * 4]);
      float4 b4 = *reinterpret_cast<const float4*>(&Bs[kk][tx * 4]);
      float a[4] = {a4.x, a4.y, a4.z, a4.w};
      float b[4] = {b4.x, b4.y, b4.z, b4.w};
#pragma unroll
      for (int i = 0; i < 4; i++)
#pragma unroll
        for (int j = 0; j < 4; j++)
          acc[i][j] = fmaf(a[i], b[j], acc[i][j]);
    }
    __syncthreads();
  }
#pragma unroll
  for (int i = 0; i < 4; i++){
    int gr = bm + ty * 4 + i;
    if (gr >= M) continue;
#pragma unroll
    for (int j = 0; j < 4; j++){
      int gc = bn + tx * 4 + j;
      if (gc >= Nn) continue;
      float v = acc[i][j];
      if (bias) v += bias[gc];
      if (mode == 1) v = fmaxf(v, 0.f);
      else if (mode == 2) v = resid[(size_t)gr * ldr + gc] + fmaxf(v, 0.f);
      C[(size_t)gr * ldc + gc] = v;
    }
  }
}

// ---------------- pooling ----------------
__global__ __launch_bounds__(256) void pool_sum(const float* __restrict__ x, int ldx,
    float* __restrict__ out, int total)
{
  int i = blockIdx.x * 256 + threadIdx.x;
  if (i >= total) return;
  int g = i >> 7, c = i & 127;
  float s = 0.f;
  const float* p = x + (size_t)g * MAXN * ldx + c;
  for (int k = 0; k < MAXN; k++) s += p[(size_t)k * ldx];
  out[i] = s;
}

// ---------------- Ubar^T precompute (bf16): Ubart[j=h*25+q][e] = bf16((1/16)*sum_d Wk0[e,h*64+d]*Q0[q,h*64+d])
__global__ __launch_bounds__(256) void ubar_make(const float* __restrict__ Wk0,
    const float* __restrict__ bk0, const float* __restrict__ Q0,
    short* __restrict__ Ubart, float* __restrict__ cvec)
{
  int j = blockIdx.x;            // 0..99
  int h = j / 25, q = j - h * 25;
  int e = threadIdx.x;           // 0..255
  const float* qp = &Q0[q * 256 + h * 64];
  const float* wp = &Wk0[(size_t)e * 256 + h * 64];
  float acc = 0.f;
#pragma unroll
  for (int d = 0; d < 64; d++) acc = fmaf(wp[d], qp[d], acc);
  Ubart[(size_t)j * 264 + e] = f2bf(acc * 0.0625f);
  if (e == 0){
    float cb = 0.f;
    const float* bp = &bk0[h * 64];
    for (int d = 0; d < 64; d++) cb = fmaf(bp[d], qp[d], cb);
    cvec[j] = cb * 0.0625f;
  }
}

// ---------------- GMPool_G fused softmax(q) + AV + residual ----------------
__global__ __launch_bounds__(256) void av_pool0(const float* __restrict__ S2d,
    const float* __restrict__ Vd, const float* __restrict__ Q0,
    float* __restrict__ O)
{
  __shared__ float Ssh[100 * 101];
  int g = blockIdx.x;
  int tid = threadIdx.x;
  for (int i = tid; i < 100 * 100; i += 256){
    int k = i / 100, j = i - k * 100;
    Ssh[k * 101 + j] = S2d[(size_t)(g * 100 + k) * 100 + j];
  }
  __syncthreads();
  for (int p = tid; p < 400; p += 256){
    int k = p >> 2, h = p & 3;
    float* base = &Ssh[k * 101 + h * 25];
    float m = -1e30f;
#pragma unroll
    for (int q = 0; q < 25; q++) m = fmaxf(m, base[q]);
    float s = 0.f;
#pragma unroll
    for (int q = 0; q < 25; q++){ float e = __expf(base[q] - m); base[q] = e; s += e; }
    float inv = 1.0f / s;
#pragma unroll
    for (int q = 0; q < 25; q++) base[q] *= inv;
  }
  __syncthreads();
  int c = tid;
  int h = c >> 6;
  float acc[25] = {};
  const float* vp = Vd + (size_t)g * 100 * 256 + c;
  for (int k = 0; k < 100; k++){
    float v = vp[(size_t)k * 256];
    const float* a = &Ssh[k * 101 + h * 25];
#pragma unroll
    for (int q = 0; q < 25; q++) acc[q] = fmaf(a[q], v, acc[q]);
  }
#pragma unroll
  for (int q = 0; q < 25; q++)
    O[(size_t)(g * 25 + q) * 256 + c] = Q0[q * 256 + c] + acc[q];
}

// ---------------- SAB fully-fused attention ----------------
#define SST 132
__global__ __launch_bounds__(256) void sab_attn(const float* __restrict__ Q1,
    const float* __restrict__ K1, const float* __restrict__ V1,
    float* __restrict__ O)
{
  __shared__ float Qs[25 * SST];
  __shared__ float Ks[25 * SST];
  __shared__ float Vs[25 * SST];
  __shared__ float Ss[4 * 25 * 26];
  int g = blockIdx.x;
  int tid = threadIdx.x;
  for (int i = tid; i < 25 * 32; i += 256){
    int r = i >> 5, jj = i & 31;
    size_t src = (size_t)(g * 25 + r) * 128 + jj * 4;
    *reinterpret_cast<float4*>(&Qs[r * SST + jj * 4]) = *reinterpret_cast<const float4*>(&Q1[src]);
    *reinterpret_cast<float4*>(&Ks[r * SST + jj * 4]) = *reinterpret_cast<const float4*>(&K1[src]);
    *reinterpret_cast<float4*>(&Vs[r * SST + jj * 4]) = *reinterpret_cast<const float4*>(&V1[src]);
  }
  __syncthreads();
  for (int idx = tid; idx < 2500; idx += 256){
    int h = idx / 625;
    int r = idx - h * 625;
    int q = r / 25, k = r - q * 25;
    const float* qp = &Qs[q * SST + h * 32];
    const float* kp = &Ks[k * SST + h * 32];
    float acc = 0.f;
#pragma unroll
    for (int d = 0; d < 32; d += 4){
      float4 a4 = *reinterpret_cast<const float4*>(&qp[d]);
      float4 b4 = *reinterpret_cast<const float4*>(&kp[d]);
      acc = fmaf(a4.x, b4.x, acc); acc = fmaf(a4.y, b4.y, acc);
      acc = fmaf(a4.z, b4.z, acc); acc = fmaf(a4.w, b4.w, acc);
    }
    Ss[(h * 25 + q) * 26 + k] = acc * 0.0883883476f;
  }
  __syncthreads();
  if (tid < 100){
    int h = tid / 25, k = tid - h * 25;
    float m = -1e30f;
#pragma unroll
    for (int q = 0; q < 25; q++) m = fmaxf(m, Ss[(h * 25 + q) * 26 + k]);
    float s = 0.f;
#pragma unroll
    for (int q = 0; q < 25; q++){ float e = __expf(Ss[(h * 25 + q) * 26 + k] - m); Ss[(h * 25 + q) * 26 + k] = e; s += e; }
    float inv = 1.0f / s;
#pragma unroll
    for (int q = 0; q < 25; q++) Ss[(h * 25 + q) * 26 + k] *= inv;
  }
  __syncthreads();
  if (tid < 128){
    int c = tid, h = c >> 5;
    float acc[25] = {};
    for (int k = 0; k < 25; k++){
      float v = Vs[k * SST + c];
#pragma unroll
      for (int q = 0; q < 25; q++) acc[q] = fmaf(Ss[(h * 25 + q) * 26 + k], v, acc[q]);
    }
#pragma unroll
    for (int q = 0; q < 25; q++)
      O[(size_t)(g * 25 + q) * 128 + c] = Qs[q * SST + c] + acc[q];
  }
}

// ---------------- GMPool_I 1-seed ----------------
__global__ __launch_bounds__(256) void seed_sum(const float* __restrict__ V, const float* __restrict__ Qc,
    float* __restrict__ O, int total)
{
  int i = blockIdx.x * 256 + threadIdx.x;
  if (i >= total) return;
  int g = i >> 7, c = i & 127;
  float acc = Qc[c];
  const float* p = V + (size_t)(g * KS1) * 128 + c;
  for (int k = 0; k < KS1; k++) acc += p[k * 128];
  O[i] = acc;
}

// ---------------- host ----------------
extern "C" void kernel_launch(void* const* d_in, const int* in_sizes, int n_in,
                              void* d_out, int out_size, void* d_ws, size_t ws_size,
                              hipStream_t stream)
{
  const int*  edge = (const int*)d_in[1];
  const int N = in_sizes[0] / FIN;      // 20000
  const int E = in_sizes[1] / 2;        // 320000
  const int G = N / MAXN;               // 200
  const int* srcp = edge;
  const int* dstp = edge + E;
  float* out = (float*)d_out;           // f32: [logits 200x10 | p1 200x128 | p2 200x128]

  float* w = (float*)d_ws;
  size_t off = 0;
  auto alloc = [&](size_t nfl){ nfl = (nfl + 3) & ~(size_t)3; float* p = w + off; off += nfl; return p; };
  auto allocS = [&](size_t nsh)->short*{ size_t nfl = ((nsh + 1) / 2 + 3) & ~(size_t)3; short* p = (short*)(w + off); off += nfl; return p; };

  float* dflag = alloc(1);
  float* dinv = alloc(N);

  float* wf[41] = {nullptr};
  CastBatch cb;
  int nw = 0;
  for (int t = 3; t < 41; t++){
    if (t == 27 || t == 28) continue;            // Wk2/bk2 dead (1-seed pool)
    float* p = alloc((size_t)in_sizes[t]);
    wf[t] = p;
    cb.src[nw] = d_in[t];
    cb.dst[nw] = p;
    cb.n[nw]   = in_sizes[t];
    nw++;
  }

  float* P0 = alloc((size_t)N * 256);   // xcat
  float* P1 = alloc((size_t)N * 256);   // xf -> xagg -> [Oa | O0]
  float* P2 = alloc((size_t)N * 256);   // gemm temps; later V2
  float* P3 = alloc((size_t)N * 256);   // Vd; later SAB slabs
  float* Sbuf = alloc((size_t)G * HH * KS1 * MAXN);  // Adj, then S2d [N x 100]
  float* Q0   = alloc(25 * 256);
  float* cvec = alloc(100);
  float* Q2c  = alloc(128);
  float* O2   = alloc((size_t)G * 128);
  float* O2f  = alloc((size_t)G * 128);
  float* zb   = alloc((size_t)G * 128);
  float* z1   = alloc((size_t)G * 128);
  float* z2   = alloc((size_t)G * 64);
  // bf16-transposed weights (ld = K+8)
  short* W1t  = allocS(128 * 136);
  short* W2t  = allocS(128 * 136);
  short* Wv0t = allocS(256 * 264);
  short* Wo0t = allocS(256 * 264);
  short* Wq1t = allocS(128 * 264);
  short* Wk1t = allocS(128 * 264);
  short* Wv1t = allocS(128 * 264);
  short* Wo1t = allocS(128 * 136);
  short* Wv2t = allocS(128 * 136);
  short* Ubart = allocS(100 * 264);
  if (off * sizeof(float) > ws_size) return;

  float* Adj = Sbuf;                    // dead before S2d written
  float* S2d = Sbuf;
  float* xf = P1;
  float* Oa = P1;
  float* O0 = P1 + (size_t)G * KS1 * 256;
  float* Q1v = P3;                      // after Vd dead
  float* K1v = P3 + (size_t)G * KS1 * 128;
  float* V1v = P3 + (size_t)2 * G * KS1 * 128;
  float* Ob  = P3 + (size_t)3 * G * KS1 * 128;
  float* O1  = P3 + (size_t)4 * G * KS1 * 128;
  float* V2  = P2;

  dim3 blk(256);
  auto gemm = [&](const float* A, int lda, const float* B, int ldb, const float* bias,
                  const float* resid, int ldr, float* C, int ldc, int M, int Nc, int K, int mode){
    dim3 grid(ceil_div(M, BM), ceil_div(Nc, BN));
    gemm_f32<<<grid, blk, 0, stream>>>(A, lda, B, ldb, bias, resid, ldr, C, ldc, M, Nc, K, mode);
  };
  auto gemmb = [&](const float* A, int lda, const short* Bt, int ldbt, const float* bias,
                   const float* resid, int ldr, float* C, int ldc, int M, int Nc, int K, int mode){
    dim3 grid(ceil_div(M, 64), ceil_div(Nc, 64));
    size_t lb = (size_t)2 * 64 * (K + 8) * sizeof(short);
    gemm_bf16<<<grid, blk, lb, stream>>>(A, lda, Bt, ldbt, bias, resid, ldr, C, ldc, M, Nc, K, mode);
  };

  // dtype sniff + casts
  sniff_dtype<<<1, blk, 0, stream>>>((const unsigned short*)d_in[0], dflag);
  cast_in<<<ceil_div(N * FIN, 256), blk, 0, stream>>>(d_in[0], xf, N * FIN, dflag);
  cast_many<<<dim3(64, 36), blk, 0, stream>>>(cb, dflag);

  // weight transpose+convert to bf16 (after cast_many)
  WprepBatch wb;
  const float* wsrc[9] = {wf[3], wf[5], wf[12], wf[14], wf[16], wf[18], wf[20], wf[22], wf[29]};
  short* wdst[9] = {W1t, W2t, Wv0t, Wo0t, Wq1t, Wk1t, Wv1t, Wo1t, Wv2t};
  int wK[9]  = {128, 128, 256, 256, 256, 256, 256, 128, 128};
  int wN[9]  = {128, 128, 256, 256, 128, 128, 128, 128, 128};
  for (int i = 0; i < 9; i++){ wb.W[i] = wsrc[i]; wb.Wt[i] = wdst[i]; wb.K[i] = wK[i]; wb.Nn[i] = wN[i]; }
  wprep_many<<<dim3(16, 9), blk, 0, stream>>>(wb);

  // degrees + dense normalized adjacency
  deg_init<<<ceil_div(N, 256), blk, 0, stream>>>(dinv, N);
  deg_edges<<<ceil_div(E, 256), blk, 0, stream>>>(dstp, dinv, E);
  deg_fin<<<ceil_div(N, 256), blk, 0, stream>>>(dinv, N);
  adj_init<<<ceil_div(G * MAXN * MAXN, 256), blk, 0, stream>>>(dinv, Adj, G * MAXN * MAXN);
  adj_edges<<<ceil_div(E, 256), blk, 0, stream>>>(srcp, dstp, dinv, Adj, E);

  // GCN1 / GCN2 + pools (MFMA for the Nx128x128 GEMMs)
  gemmb(xf, 128, W1t, 136, nullptr, nullptr, 0, P2, 128, N, 128, 128, 0);
  prop_gemm<<<dim3(G, 2), blk, 0, stream>>>(Adj, P2, 128, wf[4], P0, 256, 1);
  pool_sum<<<ceil_div(G * 128, 256), blk, 0, stream>>>(P0, 256, out + 2000, G * 128);

  gemmb(P0, 256, W2t, 136, nullptr, nullptr, 0, P2, 128, N, 128, 128, 0);
  prop_gemm<<<dim3(G, 2), blk, 0, stream>>>(Adj, P2, 128, wf[6], P0 + 128, 256, 1);
  pool_sum<<<ceil_div(G * 128, 256), blk, 0, stream>>>(P0 + 128, 256, out + 27600, G * 128);

  // xagg = A @ xcat
  prop_gemm<<<dim3(G, 4), blk, 0, stream>>>(Adj, P0, 256, nullptr, P1, 256, 0);

  // Q0 = S0@Wq0+bq0 (small, fp32); Ubar^T (bf16) replaces Kd GEMM + score kernel
  gemm(wf[7], 256, wf[8], 256, wf[9], nullptr, 0, Q0, 256, 25, 256, 256, 0);
  ubar_make<<<dim3(100), blk, 0, stream>>>(wf[10], wf[11], Q0, Ubart, cvec);

  // Vd = xagg@Wv0 + bv0 ; S2d = xagg@Ubar^T + cvec  (both MFMA; Adj dead before S2d)
  gemmb(P1, 256, Wv0t, 264, wf[13], nullptr, 0, P3, 256, N, 256, 256, 0);
  gemmb(P1, 256, Ubart, 264, cvec, nullptr, 0, S2d, 100, N, 100, 256, 0);

  // fused q-softmax + AV + residual
  av_pool0<<<dim3(G), blk, 0, stream>>>(S2d, P3, Q0, Oa);
  gemmb(Oa, 256, Wo0t, 264, wf[15], Oa, 256, O0, 256, G * KS1, 256, 256, 2);

  // --- SAB ---
  gemmb(O0, 256, Wq1t, 264, wf[17], nullptr, 0, Q1v, 128, G * KS1, 128, 256, 0);
  gemmb(O0, 256, Wk1t, 264, wf[19], nullptr, 0, K1v, 128, G * KS1, 128, 256, 0);
  gemmb(O0, 256, Wv1t, 264, wf[21], nullptr, 0, V1v, 128, G * KS1, 128, 256, 0);
  sab_attn<<<dim3(G), blk, 0, stream>>>(Q1v, K1v, V1v, Ob);
  gemmb(Ob, 128, Wo1t, 136, wf[23], Ob, 128, O1, 128, G * KS1, 128, 128, 2);

  // --- GMPool_I (1 seed) ---
  gemmb(O1, 128, Wv2t, 136, wf[30], nullptr, 0, V2, 128, G * KS1, 128, 128, 0);
  gemm(wf[24], 128, wf[25], 128, wf[26], nullptr, 0, Q2c, 128, 1, 128, 128, 0);
  seed_sum<<<ceil_div(G * 128, 256), blk, 0, stream>>>(V2, Q2c, O2, G * 128);
  gemm(O2, 128, wf[31], 128, wf[32], O2, 128, O2f, 128, G, 128, 128, 2);

  // classifier head -> logits to out[0:2000] (small, fp32)
  gemm(O2f, 128, wf[33], 128, wf[34], nullptr, 0, zb, 128, G, 128, 128, 0);
  gemm(zb, 128, wf[35], 128, wf[36], nullptr, 0, z1, 128, G, 128, 128, 1);
  gemm(z1, 128, wf[37], 64, wf[38], nullptr, 0, z2, 64, G, 64, 128, 1);
  gemm(z2, 64, wf[39], 10, wf[40], nullptr, 0, out, 10, G, 10, 64, 0);
}

// Round 7
// 463.503 us; speedup vs baseline: 4.2045x; 1.3421x over previous
//
#include <hip/hip_runtime.h>
#include <hip/hip_bf16.h>
#include <cstdint>
#include <cstddef>

typedef __hip_bfloat16 bf16;
typedef __attribute__((ext_vector_type(8))) short s16x8;
typedef __attribute__((ext_vector_type(4))) float f32x4;

#define MAXN 100
#define HH   4
#define FIN  128
#define KS1  25

static inline int ceil_div(int a, int b){ return (a + b - 1) / b; }

__device__ inline short f2bf(float f){               // RNE float->bf16 bits
  unsigned int u = __float_as_uint(f);
  u = (u + 0x7FFF + ((u >> 16) & 1)) >> 16;
  return (short)u;
}
__device__ inline float loadf(const void* s, int i, bool isbf){
  return isbf ? __bfloat162float(((const bf16*)s)[i]) : ((const float*)s)[i];
}

// ---------------- input dtype sniff (inputs proven f32; cheap hedge kept) ----------------
__global__ __launch_bounds__(256) void sniff_dtype(const unsigned short* __restrict__ u,
                                                   float* __restrict__ flag){
  __shared__ int cnt;
  if (threadIdx.x == 0) cnt = 0;
  __syncthreads();
  unsigned short b = u[2 * threadIdx.x];
  unsigned int w = ((unsigned int)b) << 16;
  float v = __uint_as_float(w);
  float a = fabsf(v);
  if (a >= 6.1e-5f && a <= 16384.f) atomicAdd(&cnt, 1);
  __syncthreads();
  if (threadIdx.x == 0) *flag = (cnt >= 128) ? 1.0f : 0.0f;
}

// ---------------- unified prep: fp32 casts + bf16 weight transposes ----------------
struct PrepBatch {
  const void* src[40];
  void*       dst[40];
  int         a[40];   // cast: n ; wprep: K
  int         b[40];   // cast: 0 ; wprep: N  (Wt[n][K+8] = bf16(W[k][n]))
};

__global__ __launch_bounds__(256) void prep_all(PrepBatch pb, const float* __restrict__ flag){
  int t = blockIdx.y;
  bool isbf = (*flag != 0.0f);
  const void* s = pb.src[t];
  int bb = pb.b[t];
  if (bb == 0){
    int n = pb.a[t];
    float* d = (float*)pb.dst[t];
    for (int i = blockIdx.x * 256 + threadIdx.x; i < n; i += gridDim.x * 256)
      d[i] = loadf(s, i, isbf);
  } else {
    int K = pb.a[t], Nn = bb, ldt = K + 8;
    short* d = (short*)pb.dst[t];
    int total = K * Nn;
    for (int i = blockIdx.x * 256 + threadIdx.x; i < total; i += gridDim.x * 256){
      int k = i / Nn, n = i - k * Nn;
      d[(size_t)n * ldt + k] = f2bf(loadf(s, i, isbf));
    }
  }
}

// ---------------- adjacency build (4 launches) ----------------
__global__ __launch_bounds__(256) void zero_init(float* __restrict__ A, float* __restrict__ deg,
                                                 int totalA, int n){
  int i = blockIdx.x * 256 + threadIdx.x;
  if (i < totalA) A[i] = 0.f;
  if (i < n) deg[i] = 1.0f;                        // self-loop
}
__global__ __launch_bounds__(256) void deg_edges(const int* __restrict__ dst, float* deg, int e){
  int i = blockIdx.x * 256 + threadIdx.x;
  if (i < e) atomicAdd(&deg[dst[i]], 1.0f);
}
__global__ __launch_bounds__(256) void adj_diag(const float* __restrict__ deg,
                                                float* __restrict__ dinv,
                                                float* __restrict__ A, int n){
  int i = blockIdx.x * 256 + threadIdx.x;
  if (i >= n) return;
  float dv = rsqrtf(deg[i]);                       // deg >= 1 always
  dinv[i] = dv;
  int g = i / MAXN, r = i - g * MAXN;
  A[(size_t)g * (MAXN * MAXN) + r * MAXN + r] = dv * dv;
}
__global__ __launch_bounds__(256) void adj_edges(const int* __restrict__ src, const int* __restrict__ dst,
                                                 const float* __restrict__ dinv,
                                                 float* __restrict__ A, int e){
  int i = blockIdx.x * 256 + threadIdx.x;
  if (i >= e) return;
  int s = src[i], d = dst[i];
  int g = d / MAXN;
  int dl = d - g * MAXN;
  int sl = s - (s / MAXN) * MAXN;
  atomicAdd(&A[(size_t)g * (MAXN * MAXN) + dl * MAXN + sl], dinv[s] * dinv[d]);
}

// ---------------- batched dense propagation (fp32) + optional fused graph-pool ----------------
#define ASTRIDE 101
#define TSTRIDE 68
__global__ __launch_bounds__(256) void prop_gemm(
    const float* __restrict__ A,
    const float* __restrict__ T, int ldt,
    const float* __restrict__ bias,
    float* __restrict__ Y, int ldy,
    int relu, float* __restrict__ pool)
{
  __shared__ float As[112 * ASTRIDE];
  __shared__ float Ts[MAXN * TSTRIDE];
  int g = blockIdx.x;
  int c0 = blockIdx.y * 64;
  int tid = threadIdx.x;
  const float* Ag = A + (size_t)g * (MAXN * MAXN);
  for (int i = tid; i < MAXN * MAXN; i += 256){
    int r = i / MAXN, s = i - r * MAXN;
    As[r * ASTRIDE + s] = Ag[i];
  }
  for (int i = tid; i < MAXN * 16; i += 256){
    int s = i >> 4, jj = i & 15;
    float4 v = *reinterpret_cast<const float4*>(&T[(size_t)(g * MAXN + s) * ldt + c0 + jj * 4]);
    *reinterpret_cast<float4*>(&Ts[s * TSTRIDE + jj * 4]) = v;
  }
  __syncthreads();

  int tx = tid & 15, ty = tid >> 4;
  float acc[7][4] = {};
#pragma unroll 2
  for (int s = 0; s < MAXN; s++){
    float4 t4 = *reinterpret_cast<const float4*>(&Ts[s * TSTRIDE + tx * 4]);
    float t[4] = {t4.x, t4.y, t4.z, t4.w};
#pragma unroll
    for (int i = 0; i < 7; i++){
      float a = As[(ty * 7 + i) * ASTRIDE + s];
#pragma unroll
      for (int j = 0; j < 4; j++) acc[i][j] = fmaf(a, t[j], acc[i][j]);
    }
  }

  float4 b4 = make_float4(0.f, 0.f, 0.f, 0.f);
  if (bias) b4 = *reinterpret_cast<const float4*>(&bias[c0 + tx * 4]);
  float bv[4] = {b4.x, b4.y, b4.z, b4.w};
  float ps[4] = {0.f, 0.f, 0.f, 0.f};
#pragma unroll
  for (int i = 0; i < 7; i++){
    int r = ty * 7 + i;
    if (r >= MAXN) continue;
    float o[4];
#pragma unroll
    for (int j = 0; j < 4; j++){
      float v = acc[i][j] + bv[j];
      if (relu) v = fmaxf(v, 0.f);
      o[j] = v;
      ps[j] += v;
    }
    *reinterpret_cast<float4*>(&Y[(size_t)(g * MAXN + r) * ldy + c0 + tx * 4]) =
        make_float4(o[0], o[1], o[2], o[3]);
  }

  if (pool){
    __syncthreads();                 // As re-used as reduction scratch
    float* red = As;
#pragma unroll
    for (int j = 0; j < 4; j++) red[(tx * 4 + j) * 17 + ty] = ps[j];
    __syncthreads();
    if (tid < 64){
      float s = 0.f;
#pragma unroll
      for (int t2 = 0; t2 < 16; t2++) s += red[tid * 17 + t2];
      pool[g * 128 + c0 + tid] = s;
    }
  }
}

// ---------------- MFMA bf16 GEMM: C = epi(A[M,K] @ Bt[N,K]^T + bias) ----------------
__global__ __launch_bounds__(256) void gemm_bf16(
    const float* __restrict__ A, int lda,
    const short* __restrict__ Bt, int ldbt,
    const float* __restrict__ bias,
    const float* __restrict__ resid, int ldr,
    float* __restrict__ C, int ldc,
    int M, int Nn, int K, int mode)
{
  extern __shared__ short lds[];
  const int ldk = K + 8;
  short* As = lds;
  short* Bs = lds + 64 * ldk;
  int bm = blockIdx.x * 64, bn = blockIdx.y * 64;
  int tid = threadIdx.x;
  int ku = K >> 3;
  for (int u = tid; u < 64 * ku; u += 256){
    int r = u / ku, k8 = (u - r * ku) << 3;
    int gr = bm + r;
    s16x8 v;
    if (gr < M){
      const float* ap = &A[(size_t)gr * lda + k8];
      float4 f0 = *reinterpret_cast<const float4*>(ap);
      float4 f1 = *reinterpret_cast<const float4*>(ap + 4);
      v[0] = f2bf(f0.x); v[1] = f2bf(f0.y); v[2] = f2bf(f0.z); v[3] = f2bf(f0.w);
      v[4] = f2bf(f1.x); v[5] = f2bf(f1.y); v[6] = f2bf(f1.z); v[7] = f2bf(f1.w);
    } else {
#pragma unroll
      for (int j = 0; j < 8; j++) v[j] = 0;
    }
    *reinterpret_cast<s16x8*>(&As[r * ldk + k8]) = v;
  }
  for (int u = tid; u < 64 * ku; u += 256){
    int n = u / ku, k8 = (u - n * ku) << 3;
    int gn = bn + n;
    s16x8 v;
    if (gn < Nn) v = *reinterpret_cast<const s16x8*>(&Bt[(size_t)gn * ldbt + k8]);
    else {
#pragma unroll
      for (int j = 0; j < 8; j++) v[j] = 0;
    }
    *reinterpret_cast<s16x8*>(&Bs[n * ldk + k8]) = v;
  }
  __syncthreads();

  int wave = tid >> 6, lane = tid & 63;
  int quad = lane >> 4, l16 = lane & 15;
  f32x4 acc0 = {0.f,0.f,0.f,0.f}, acc1 = acc0, acc2 = acc0, acc3 = acc0;
  const short* brow = &Bs[(wave * 16 + l16) * ldk];
  const short* arow = &As[l16 * ldk];
  for (int kt = 0; kt < K; kt += 32){
    int kb = kt + quad * 8;
    s16x8 bfr = *reinterpret_cast<const s16x8*>(&brow[kb]);
    s16x8 a0 = *reinterpret_cast<const s16x8*>(&arow[kb]);
    s16x8 a1 = *reinterpret_cast<const s16x8*>(&arow[16 * ldk + kb]);
    s16x8 a2 = *reinterpret_cast<const s16x8*>(&arow[32 * ldk + kb]);
    s16x8 a3 = *reinterpret_cast<const s16x8*>(&arow[48 * ldk + kb]);
    acc0 = __builtin_amdgcn_mfma_f32_16x16x32_bf16(a0, bfr, acc0, 0, 0, 0);
    acc1 = __builtin_amdgcn_mfma_f32_16x16x32_bf16(a1, bfr, acc1, 0, 0, 0);
    acc2 = __builtin_amdgcn_mfma_f32_16x16x32_bf16(a2, bfr, acc2, 0, 0, 0);
    acc3 = __builtin_amdgcn_mfma_f32_16x16x32_bf16(a3, bfr, acc3, 0, 0, 0);
  }
  int gc = bn + wave * 16 + l16;
  if (gc >= Nn) return;
  float bvv = bias ? bias[gc] : 0.f;
  f32x4 accs[4] = {acc0, acc1, acc2, acc3};
#pragma unroll
  for (int rt = 0; rt < 4; rt++){
#pragma unroll
    for (int r = 0; r < 4; r++){
      int gr = bm + rt * 16 + quad * 4 + r;
      if (gr >= M) continue;
      float vv = accs[rt][r] + bvv;
      if (mode == 1) vv = fmaxf(vv, 0.f);
      else if (mode == 2) vv = resid[(size_t)gr * ldr + gc] + fmaxf(vv, 0.f);
      C[(size_t)gr * ldc + gc] = vv;
    }
  }
}

// ---------------- ubar_q0: Q0 (25x256) + Ubar^T bf16 + cvec, one kernel ----------------
// block j=(h,q): Q0[q,h*64+d] = bq0 + S0[q]@Wq0 col; Ubart[j][e] = (1/16)<Wk0[e,h],Q0[q,h]>
__global__ __launch_bounds__(256) void ubar_q0(const float* __restrict__ S0,
    const float* __restrict__ Wq0, const float* __restrict__ bq0,
    const float* __restrict__ Wk0, const float* __restrict__ bk0,
    float* __restrict__ Q0, short* __restrict__ Ubart, float* __restrict__ cvec)
{
  __shared__ float q0s[64];
  int j = blockIdx.x, h = j / 25, q = j - h * 25;
  int tid = threadIdx.x;
  if (tid < 64){
    int c = h * 64 + tid;
    float acc = bq0[c];
    for (int e = 0; e < 256; e++) acc = fmaf(S0[q * 256 + e], Wq0[e * 256 + c], acc);
    q0s[tid] = acc;
    Q0[q * 256 + c] = acc;
  }
  __syncthreads();
  float acc = 0.f;
  const float* wp = &Wk0[(size_t)tid * 256 + h * 64];
#pragma unroll
  for (int d = 0; d < 64; d++) acc = fmaf(wp[d], q0s[d], acc);
  Ubart[(size_t)j * 264 + tid] = f2bf(acc * 0.0625f);
  if (tid == 0){
    float cb = 0.f;
    for (int d = 0; d < 64; d++) cb = fmaf(bk0[h * 64 + d], q0s[d], cb);
    cvec[j] = cb * 0.0625f;
  }
}

// ---------------- GMPool_G fused softmax(q) + AV + residual (VdS combined layout) ----------------
__global__ __launch_bounds__(256) void av_pool0(const float* __restrict__ VdS,
    const float* __restrict__ Q0, float* __restrict__ O)
{
  __shared__ float Ssh[100 * 101];
  int g = blockIdx.x;
  int tid = threadIdx.x;
  for (int i = tid; i < 100 * 100; i += 256){
    int k = i / 100, jq = i - k * 100;
    Ssh[k * 101 + jq] = VdS[(size_t)(g * 100 + k) * 356 + 256 + jq];
  }
  __syncthreads();
  for (int p = tid; p < 400; p += 256){
    int k = p >> 2, h = p & 3;
    float* base = &Ssh[k * 101 + h * 25];
    float m = -1e30f;
#pragma unroll
    for (int q = 0; q < 25; q++) m = fmaxf(m, base[q]);
    float s = 0.f;
#pragma unroll
    for (int q = 0; q < 25; q++){ float e = __expf(base[q] - m); base[q] = e; s += e; }
    float inv = 1.0f / s;
#pragma unroll
    for (int q = 0; q < 25; q++) base[q] *= inv;
  }
  __syncthreads();
  int c = tid;
  int h = c >> 6;
  float acc[25] = {};
  const float* vp = VdS + (size_t)g * 100 * 356 + c;
  for (int k = 0; k < 100; k++){
    float v = vp[(size_t)k * 356];
    const float* a = &Ssh[k * 101 + h * 25];
#pragma unroll
    for (int q = 0; q < 25; q++) acc[q] = fmaf(a[q], v, acc[q]);
  }
#pragma unroll
  for (int q = 0; q < 25; q++)
    O[(size_t)(g * 25 + q) * 256 + c] = Q0[q * 256 + c] + acc[q];
}

// ---------------- SAB fully-fused attention (reads packed QKV, ld 384) ----------------
#define SST 132
__global__ __launch_bounds__(256) void sab_attn(const float* __restrict__ QKV,
    float* __restrict__ O)
{
  __shared__ float Qs[25 * SST];
  __shared__ float Ks[25 * SST];
  __shared__ float Vs[25 * SST];
  __shared__ float Ss[4 * 25 * 26];
  int g = blockIdx.x;
  int tid = threadIdx.x;
  for (int i = tid; i < 25 * 32; i += 256){
    int r = i >> 5, jj = i & 31;
    size_t src = (size_t)(g * 25 + r) * 384 + jj * 4;
    *reinterpret_cast<float4*>(&Qs[r * SST + jj * 4]) = *reinterpret_cast<const float4*>(&QKV[src]);
    *reinterpret_cast<float4*>(&Ks[r * SST + jj * 4]) = *reinterpret_cast<const float4*>(&QKV[src + 128]);
    *reinterpret_cast<float4*>(&Vs[r * SST + jj * 4]) = *reinterpret_cast<const float4*>(&QKV[src + 256]);
  }
  __syncthreads();
  for (int idx = tid; idx < 2500; idx += 256){
    int h = idx / 625;
    int r = idx - h * 625;
    int q = r / 25, k = r - q * 25;
    const float* qp = &Qs[q * SST + h * 32];
    const float* kp = &Ks[k * SST + h * 32];
    float acc = 0.f;
#pragma unroll
    for (int d = 0; d < 32; d += 4){
      float4 a4 = *reinterpret_cast<const float4*>(&qp[d]);
      float4 b4 = *reinterpret_cast<const float4*>(&kp[d]);
      acc = fmaf(a4.x, b4.x, acc); acc = fmaf(a4.y, b4.y, acc);
      acc = fmaf(a4.z, b4.z, acc); acc = fmaf(a4.w, b4.w, acc);
    }
    Ss[(h * 25 + q) * 26 + k] = acc * 0.0883883476f;
  }
  __syncthreads();
  if (tid < 100){
    int h = tid / 25, k = tid - h * 25;
    float m = -1e30f;
#pragma unroll
    for (int q = 0; q < 25; q++) m = fmaxf(m, Ss[(h * 25 + q) * 26 + k]);
    float s = 0.f;
#pragma unroll
    for (int q = 0; q < 25; q++){ float e = __expf(Ss[(h * 25 + q) * 26 + k] - m); Ss[(h * 25 + q) * 26 + k] = e; s += e; }
    float inv = 1.0f / s;
#pragma unroll
    for (int q = 0; q < 25; q++) Ss[(h * 25 + q) * 26 + k] *= inv;
  }
  __syncthreads();
  if (tid < 128){
    int c = tid, h = c >> 5;
    float acc[25] = {};
    for (int k = 0; k < 25; k++){
      float v = Vs[k * SST + c];
#pragma unroll
      for (int q = 0; q < 25; q++) acc[q] = fmaf(Ss[(h * 25 + q) * 26 + k], v, acc[q]);
    }
#pragma unroll
    for (int q = 0; q < 25; q++)
      O[(size_t)(g * 25 + q) * 128 + c] = Qs[q * SST + c] + acc[q];
  }
}

// ---------------- fully-fused head: O1 -> logits (replaces 8 small launches) ----------------
// O2 = Q2c + sum_k(O1@Wv2+bv2) = (bq2 + S2@Wq2) + 25*bv2 + (sum_k O1)@Wv2
// O2f = O2 + relu(O2@Wo2+bo2); z = O2f@Wl+bl; z1 = relu(z@Wc1+bc1);
// z2 = relu(z1@Wc2+bc2); logits = z2@Wc3+bc3
__global__ __launch_bounds__(128) void head_fused(const float* __restrict__ O1,
    const float* __restrict__ S2,
    const float* __restrict__ Wq2, const float* __restrict__ bq2,
    const float* __restrict__ Wv2, const float* __restrict__ bv2,
    const float* __restrict__ Wo2, const float* __restrict__ bo2,
    const float* __restrict__ Wl,  const float* __restrict__ bl,
    const float* __restrict__ Wc1, const float* __restrict__ bc1,
    const float* __restrict__ Wc2, const float* __restrict__ bc2,
    const float* __restrict__ Wc3, const float* __restrict__ bc3,
    float* __restrict__ out)
{
  __shared__ float va[128], vb[128];
  int g = blockIdx.x, c = threadIdx.x;
  float s = 0.f;
  for (int k = 0; k < 25; k++) s += O1[(size_t)(g * 25 + k) * 128 + c];
  va[c] = s;
  __syncthreads();
  float o2 = bq2[c];
  for (int k = 0; k < 128; k++) o2 = fmaf(S2[k], Wq2[k * 128 + c], o2);
  o2 += 25.f * bv2[c];
  for (int k = 0; k < 128; k++) o2 = fmaf(va[k], Wv2[k * 128 + c], o2);
  __syncthreads(); vb[c] = o2; __syncthreads();
  float t = bo2[c];
  for (int k = 0; k < 128; k++) t = fmaf(vb[k], Wo2[k * 128 + c], t);
  float o2f = o2 + fmaxf(t, 0.f);
  va[c] = o2f; __syncthreads();
  float z = bl[c];
  for (int k = 0; k < 128; k++) z = fmaf(va[k], Wl[k * 128 + c], z);
  vb[c] = z; __syncthreads();
  float z1 = bc1[c];
  for (int k = 0; k < 128; k++) z1 = fmaf(vb[k], Wc1[k * 128 + c], z1);
  z1 = fmaxf(z1, 0.f);
  va[c] = z1; __syncthreads();
  if (c < 64){
    float z2 = bc2[c];
    for (int k = 0; k < 128; k++) z2 = fmaf(va[k], Wc2[k * 64 + c], z2);
    vb[c] = fmaxf(z2, 0.f);
  }
  __syncthreads();
  if (c < 10){
    float lg = bc3[c];
    for (int k = 0; k < 64; k++) lg = fmaf(vb[k], Wc3[k * 10 + c], lg);
    out[g * 10 + c] = lg;
  }
}

// ---------------- host ----------------
extern "C" void kernel_launch(void* const* d_in, const int* in_sizes, int n_in,
                              void* d_out, int out_size, void* d_ws, size_t ws_size,
                              hipStream_t stream)
{
  const int*  edge = (const int*)d_in[1];
  const int N = in_sizes[0] / FIN;      // 20000
  const int E = in_sizes[1] / 2;        // 320000
  const int G = N / MAXN;               // 200
  const int* srcp = edge;
  const int* dstp = edge + E;
  float* out = (float*)d_out;           // f32: [logits 200x10 | p1 200x128 | p2 200x128]

  float* w = (float*)d_ws;
  size_t off = 0;
  auto alloc = [&](size_t nfl){ nfl = (nfl + 3) & ~(size_t)3; float* p = w + off; off += nfl; return p; };
  auto allocS = [&](size_t nsh)->short*{ size_t nfl = ((nsh + 1) / 2 + 3) & ~(size_t)3; short* p = (short*)(w + off); off += nfl; return p; };

  float* dflag = alloc(1);
  float* dinv  = alloc(N);
  float* degb  = alloc(N);

  // joint bias buffers for concat-GEMMs
  float* biasVS  = alloc(356);          // [bv0 (256) | cvec (100)]
  float* biasQKV = alloc(384);          // [bq1 | bk1 | bv1]
  float* cvec = biasVS + 256;

  // fp32 copies only where fp32 math needs them
  const int castT[24] = {4,6,7,8,9,10,11,15,23,24,25,26,29,30,31,32,33,34,35,36,37,38,39,40};
  float* wf[41] = {nullptr};
  for (int i = 0; i < 24; i++) wf[castT[i]] = alloc((size_t)in_sizes[castT[i]]);
  wf[13] = biasVS; wf[17] = biasQKV; wf[19] = biasQKV + 128; wf[21] = biasQKV + 256;

  float* P0 = alloc((size_t)N * 256);   // xcat
  float* P1 = alloc((size_t)N * 256);   // xf -> xagg -> [Oa | O0]
  float* P2 = alloc((size_t)N * 256);   // GCN temps; later QKV + ...
  float* P3 = alloc((size_t)N * 356);   // VdS; later Ob/O1
  float* Adj = alloc((size_t)G * MAXN * MAXN);
  float* Q0  = alloc(25 * 256);

  // bf16-transposed weights (ld = K+8)
  short* W1t   = allocS(128 * 136);
  short* W2t   = allocS(128 * 136);
  short* WVSt  = allocS(356 * 264);     // [Wv0t (256 rows) | Ubart (100 rows)]
  short* WQKVt = allocS(384 * 264);     // [Wq1t | Wk1t | Wv1t]
  short* Wo0t  = allocS(256 * 264);
  short* Wo1t  = allocS(128 * 136);
  short* Ubart = WVSt + (size_t)256 * 264;
  if (off * sizeof(float) > ws_size) return;

  float* xf  = P1;
  float* Oa  = P1;
  float* O0  = P1 + (size_t)G * KS1 * 256;
  float* QKV = P2;
  float* Ob  = P3;
  float* O1  = P3 + (size_t)G * KS1 * 128;

  dim3 blk(256);
  auto gemmb = [&](const float* A, int lda, const short* Bt, int ldbt, const float* bias,
                   const float* resid, int ldr, float* C, int ldc, int M, int Nc, int K, int mode){
    dim3 grid(ceil_div(M, 64), ceil_div(Nc, 64));
    size_t lb = (size_t)2 * 64 * (K + 8) * sizeof(short);
    gemm_bf16<<<grid, blk, lb, stream>>>(A, lda, Bt, ldbt, bias, resid, ldr, C, ldc, M, Nc, K, mode);
  };

  // 1. dtype sniff
  sniff_dtype<<<1, blk, 0, stream>>>((const unsigned short*)d_in[0], dflag);

  // 2. unified prep (casts + bf16 transposes, biases into joint buffers)
  PrepBatch pb; int ne = 0;
  auto addC = [&](const void* s, float* d, int n){ pb.src[ne]=s; pb.dst[ne]=d; pb.a[ne]=n; pb.b[ne]=0; ne++; };
  auto addW = [&](const void* s, short* d, int K, int Nn){ pb.src[ne]=s; pb.dst[ne]=d; pb.a[ne]=K; pb.b[ne]=Nn; ne++; };
  addC(d_in[0], xf, N * FIN);
  for (int i = 0; i < 24; i++){ int t = castT[i]; addC(d_in[t], wf[t], in_sizes[t]); }
  addC(d_in[13], biasVS, 256);
  addC(d_in[17], biasQKV, 128); addC(d_in[19], biasQKV + 128, 128); addC(d_in[21], biasQKV + 256, 128);
  addW(d_in[3],  W1t, 128, 128);          addW(d_in[5],  W2t, 128, 128);
  addW(d_in[12], WVSt, 256, 256);         addW(d_in[16], WQKVt, 256, 128);
  addW(d_in[18], WQKVt + 128*264, 256, 128); addW(d_in[20], WQKVt + 256*264, 256, 128);
  addW(d_in[14], Wo0t, 256, 256);         addW(d_in[22], Wo1t, 128, 128);
  prep_all<<<dim3(64, ne), blk, 0, stream>>>(pb, dflag);

  // 3-6. adjacency
  int totalA = G * MAXN * MAXN;
  zero_init<<<ceil_div(totalA, 256), blk, 0, stream>>>(Adj, degb, totalA, N);
  deg_edges<<<ceil_div(E, 256), blk, 0, stream>>>(dstp, degb, E);
  adj_diag<<<ceil_div(N, 256), blk, 0, stream>>>(degb, dinv, Adj, N);
  adj_edges<<<ceil_div(E, 256), blk, 0, stream>>>(srcp, dstp, dinv, Adj, E);

  // 7-10. GCN1 / GCN2 with fused pooling (p1/p2 straight to out)
  gemmb(xf, 128, W1t, 136, nullptr, nullptr, 0, P2, 128, N, 128, 128, 0);
  prop_gemm<<<dim3(G, 2), blk, 0, stream>>>(Adj, P2, 128, wf[4], P0, 256, 1, out + 2000);
  gemmb(P0, 256, W2t, 136, nullptr, nullptr, 0, P2, 128, N, 128, 128, 0);
  prop_gemm<<<dim3(G, 2), blk, 0, stream>>>(Adj, P2, 128, wf[6], P0 + 128, 256, 1, out + 27600);

  // 11. xagg = A @ xcat (prop linearity)
  prop_gemm<<<dim3(G, 4), blk, 0, stream>>>(Adj, P0, 256, nullptr, P1, 256, 0, nullptr);

  // 12. Q0 + Ubar^T + cvec in one kernel
  ubar_q0<<<dim3(100), blk, 0, stream>>>(wf[7], wf[8], wf[9], wf[10], wf[11], Q0, Ubart, cvec);

  // 13. [Vd | S2d] = xagg @ [Wv0 | Ubar]^T + [bv0 | cvec]   (one MFMA GEMM, N=356)
  gemmb(P1, 256, WVSt, 264, biasVS, nullptr, 0, P3, 356, N, 356, 256, 0);

  // 14-15. fused q-softmax+AV+residual, then Wo0 block (MFMA, mode2)
  av_pool0<<<dim3(G), blk, 0, stream>>>(P3, Q0, Oa);
  gemmb(Oa, 256, Wo0t, 264, wf[15], Oa, 256, O0, 256, G * KS1, 256, 256, 2);

  // 16-18. SAB: packed QKV GEMM (N=384), fused attention, Wo1 (mode2)
  gemmb(O0, 256, WQKVt, 264, biasQKV, nullptr, 0, QKV, 384, G * KS1, 384, 256, 0);
  sab_attn<<<dim3(G), blk, 0, stream>>>(QKV, Ob);
  gemmb(Ob, 128, Wo1t, 136, wf[23], Ob, 128, O1, 128, G * KS1, 128, 128, 2);

  // 19. fused head -> logits
  head_fused<<<dim3(G), dim3(128), 0, stream>>>(O1, wf[24], wf[25], wf[26], wf[29], wf[30],
      wf[31], wf[32], wf[33], wf[34], wf[35], wf[36], wf[37], wf[38], wf[39], wf[40], out);
}

// Round 8
// 418.478 us; speedup vs baseline: 4.6568x; 1.1076x over previous
//
#include <hip/hip_runtime.h>
#include <hip/hip_bf16.h>
#include <cstdint>
#include <cstddef>

typedef __hip_bfloat16 bf16;
typedef __attribute__((ext_vector_type(8))) short s16x8;
typedef __attribute__((ext_vector_type(4))) float f32x4;

#define MAXN 100
#define HH   4
#define FIN  128
#define KS1  25

static inline int ceil_div(int a, int b){ return (a + b - 1) / b; }

__device__ inline short f2bf(float f){               // RNE float->bf16 bits
  unsigned int u = __float_as_uint(f);
  u = (u + 0x7FFF + ((u >> 16) & 1)) >> 16;
  return (short)u;
}
__device__ inline float loadf(const void* s, int i, bool isbf){
  return isbf ? __bfloat162float(((const bf16*)s)[i]) : ((const float*)s)[i];
}

// ---------------- input dtype sniff (inputs proven f32; cheap hedge kept) ----------------
__global__ __launch_bounds__(256) void sniff_dtype(const unsigned short* __restrict__ u,
                                                   float* __restrict__ flag){
  __shared__ int cnt;
  if (threadIdx.x == 0) cnt = 0;
  __syncthreads();
  unsigned short b = u[2 * threadIdx.x];
  unsigned int w = ((unsigned int)b) << 16;
  float v = __uint_as_float(w);
  float a = fabsf(v);
  if (a >= 6.1e-5f && a <= 16384.f) atomicAdd(&cnt, 1);
  __syncthreads();
  if (threadIdx.x == 0) *flag = (cnt >= 128) ? 1.0f : 0.0f;
}

// ---------------- unified prep: flat 1-D grid, blocks proportional to work ----------------
struct PrepBatch {
  const void* src[40];
  void*       dst[40];
  int         a[40];     // cast: n elements ; wprep: K
  int         b[40];     // cast: 0 ; wprep: N  (Wt[n][K+8] = bf16(W[k][n]))
  int         blk0[41];  // block prefix starts
  int         ne;
};

__global__ __launch_bounds__(256) void prep_all(PrepBatch pb, const float* __restrict__ flag){
  int blk = blockIdx.x;
  int t = 0;
  while (t + 1 < pb.ne && pb.blk0[t + 1] <= blk) t++;
  int local = blk - pb.blk0[t];
  bool isbf = (*flag != 0.0f);
  const void* s = pb.src[t];
  if (pb.b[t] == 0){
    int n = pb.a[t];
    float* d = (float*)pb.dst[t];
    int v = local * 256 + threadIdx.x;     // float4 unit index
    int base = v * 4;
    if (base + 3 < n){
      float4 f;
      if (isbf){
        ushort4 u = ((const ushort4*)s)[v];
        f.x = __uint_as_float(((unsigned)u.x) << 16);
        f.y = __uint_as_float(((unsigned)u.y) << 16);
        f.z = __uint_as_float(((unsigned)u.z) << 16);
        f.w = __uint_as_float(((unsigned)u.w) << 16);
      } else f = ((const float4*)s)[v];
      ((float4*)d)[v] = f;
    } else {
      for (int j = base; j < n && j < base + 4; j++) d[j] = loadf(s, j, isbf);
    }
  } else {
    int K = pb.a[t], Nn = pb.b[t], ldt = K + 8;
    short* d = (short*)pb.dst[t];
    int i = local * 256 + threadIdx.x;
    if (i < K * Nn){
      int n = i / K, k = i - n * K;        // k-fast: coalesced 2B writes
      d[(size_t)n * ldt + k] = f2bf(loadf(s, (size_t)k * Nn + n, isbf));
    }
  }
}

// ---------------- adjacency build (3 launches) ----------------
__global__ __launch_bounds__(256) void zero_init(float* __restrict__ A, float* __restrict__ deg,
                                                 int totalA, int n){
  int i = blockIdx.x * 256 + threadIdx.x;
  if (i < totalA) A[i] = 0.f;
  if (i < n) deg[i] = 1.0f;                        // self-loop
}
__global__ __launch_bounds__(256) void deg_edges(const int* __restrict__ dst, float* deg, int e){
  int i = blockIdx.x * 256 + threadIdx.x;
  if (i < e) atomicAdd(&deg[dst[i]], 1.0f);
}
// diag + edges in one kernel, all-atomic (commutes; preserves data self-edge semantics)
__global__ __launch_bounds__(256) void adj_fin(const int* __restrict__ src, const int* __restrict__ dst,
                                               const float* __restrict__ deg,
                                               float* __restrict__ A, int n, int e){
  int i = blockIdx.x * 256 + threadIdx.x;
  if (i < n){
    float dv = rsqrtf(deg[i]);
    int g = i / MAXN, r = i - g * MAXN;
    atomicAdd(&A[(size_t)g * (MAXN * MAXN) + r * MAXN + r], dv * dv);
  } else if (i < n + e){
    int j = i - n;
    int s = src[j], d = dst[j];
    float nv = rsqrtf(deg[s]) * rsqrtf(deg[d]);
    int g = d / MAXN;
    int dl = d - g * MAXN;
    int sl = s - (s / MAXN) * MAXN;
    atomicAdd(&A[(size_t)g * (MAXN * MAXN) + dl * MAXN + sl], nv);
  }
}

// ---------------- batched dense propagation + fused pool + fused second hop (xagg) ----------------
#define ASTRIDE 101
#define TSTRIDE 68
__global__ __launch_bounds__(256) void prop_gemm(
    const float* __restrict__ A,
    const float* __restrict__ T, int ldt,
    const float* __restrict__ bias,
    float* __restrict__ Y, int ldy,
    int relu, float* __restrict__ pool,
    float* __restrict__ Yagg, int ldya)
{
  __shared__ float As[112 * ASTRIDE];
  __shared__ float Ts[MAXN * TSTRIDE];
  int g = blockIdx.x;
  int c0 = blockIdx.y * 64;
  int tid = threadIdx.x;
  const float* Ag = A + (size_t)g * (MAXN * MAXN);
  for (int i = tid; i < MAXN * MAXN; i += 256){
    int r = i / MAXN, s = i - r * MAXN;
    As[r * ASTRIDE + s] = Ag[i];
  }
  for (int i = tid; i < MAXN * 16; i += 256){
    int s = i >> 4, jj = i & 15;
    float4 v = *reinterpret_cast<const float4*>(&T[(size_t)(g * MAXN + s) * ldt + c0 + jj * 4]);
    *reinterpret_cast<float4*>(&Ts[s * TSTRIDE + jj * 4]) = v;
  }
  __syncthreads();

  int tx = tid & 15, ty = tid >> 4;
  float acc[7][4] = {};
#pragma unroll 2
  for (int s = 0; s < MAXN; s++){
    float4 t4 = *reinterpret_cast<const float4*>(&Ts[s * TSTRIDE + tx * 4]);
    float t[4] = {t4.x, t4.y, t4.z, t4.w};
#pragma unroll
    for (int i = 0; i < 7; i++){
      float a = As[(ty * 7 + i) * ASTRIDE + s];
#pragma unroll
      for (int j = 0; j < 4; j++) acc[i][j] = fmaf(a, t[j], acc[i][j]);
    }
  }

  float4 b4 = make_float4(0.f, 0.f, 0.f, 0.f);
  if (bias) b4 = *reinterpret_cast<const float4*>(&bias[c0 + tx * 4]);
  float bv[4] = {b4.x, b4.y, b4.z, b4.w};
  float ps[4] = {0.f, 0.f, 0.f, 0.f};
#pragma unroll
  for (int i = 0; i < 7; i++){
    int r = ty * 7 + i;
    if (r >= MAXN) continue;
#pragma unroll
    for (int j = 0; j < 4; j++){
      float v = acc[i][j] + bv[j];
      if (relu) v = fmaxf(v, 0.f);
      acc[i][j] = v;
      ps[j] += v;
    }
    *reinterpret_cast<float4*>(&Y[(size_t)(g * MAXN + r) * ldy + c0 + tx * 4]) =
        make_float4(acc[i][0], acc[i][1], acc[i][2], acc[i][3]);
  }

  if (Yagg){                           // second hop: Yagg = A @ Y (columns c0..c0+63)
    __syncthreads();                   // Ts fully consumed; safe to overwrite
#pragma unroll
    for (int i = 0; i < 7; i++){
      int r = ty * 7 + i;
      if (r >= MAXN) continue;
      *reinterpret_cast<float4*>(&Ts[r * TSTRIDE + tx * 4]) =
          make_float4(acc[i][0], acc[i][1], acc[i][2], acc[i][3]);
    }
    __syncthreads();
    float acc2[7][4] = {};
#pragma unroll 2
    for (int s = 0; s < MAXN; s++){
      float4 t4 = *reinterpret_cast<const float4*>(&Ts[s * TSTRIDE + tx * 4]);
      float t[4] = {t4.x, t4.y, t4.z, t4.w};
#pragma unroll
      for (int i = 0; i < 7; i++){
        float a = As[(ty * 7 + i) * ASTRIDE + s];
#pragma unroll
        for (int j = 0; j < 4; j++) acc2[i][j] = fmaf(a, t[j], acc2[i][j]);
      }
    }
#pragma unroll
    for (int i = 0; i < 7; i++){
      int r = ty * 7 + i;
      if (r >= MAXN) continue;
      *reinterpret_cast<float4*>(&Yagg[(size_t)(g * MAXN + r) * ldya + c0 + tx * 4]) =
          make_float4(acc2[i][0], acc2[i][1], acc2[i][2], acc2[i][3]);
    }
  }

  if (pool){
    __syncthreads();                   // multiply passes done; As reusable as scratch
    float* red = As;
#pragma unroll
    for (int j = 0; j < 4; j++) red[(tx * 4 + j) * 17 + ty] = ps[j];
    __syncthreads();
    if (tid < 64){
      float s = 0.f;
#pragma unroll
      for (int t2 = 0; t2 < 16; t2++) s += red[tid * 17 + t2];
      pool[g * 128 + c0 + tid] = s;
    }
  }
}

// ---------------- MFMA bf16 GEMM: C = epi(A[M,K] @ Bt[N,K]^T + bias) ----------------
// A fp32 or (aflag-selected) bf16; Bt pre-converted bf16, ld = K+8.
// gridDim.y==1 -> loop all N panels (stage A once); else one panel per blockIdx.y.
__global__ __launch_bounds__(256) void gemm_bf16(
    const void* __restrict__ A, int lda,
    const short* __restrict__ Bt, int ldbt,
    const float* __restrict__ bias,
    const float* __restrict__ resid, int ldr,
    float* __restrict__ C, int ldc,
    int M, int Nn, int K, int mode,
    const float* __restrict__ aflag)
{
  extern __shared__ short lds[];
  const int ldk = K + 8;
  short* As = lds;
  short* Bs = lds + 64 * ldk;
  int bm = blockIdx.x * 64;
  int tid = threadIdx.x;
  int ku = K >> 3;
  bool isbf = aflag ? (*aflag != 0.0f) : false;

  for (int u = tid; u < 64 * ku; u += 256){
    int r = u / ku, k8 = (u - r * ku) << 3;
    int gr = bm + r;
    s16x8 v;
    if (gr < M){
      if (isbf){
        v = *reinterpret_cast<const s16x8*>((const short*)A + (size_t)gr * lda + k8);
      } else {
        const float* ap = (const float*)A + (size_t)gr * lda + k8;
        float4 f0 = *reinterpret_cast<const float4*>(ap);
        float4 f1 = *reinterpret_cast<const float4*>(ap + 4);
        v[0] = f2bf(f0.x); v[1] = f2bf(f0.y); v[2] = f2bf(f0.z); v[3] = f2bf(f0.w);
        v[4] = f2bf(f1.x); v[5] = f2bf(f1.y); v[6] = f2bf(f1.z); v[7] = f2bf(f1.w);
      }
    } else {
#pragma unroll
      for (int j = 0; j < 8; j++) v[j] = 0;
    }
    *reinterpret_cast<s16x8*>(&As[r * ldk + k8]) = v;
  }

  int panels = (Nn + 63) >> 6;
  int p0 = 0, p1 = panels;
  if (gridDim.y > 1){ p0 = blockIdx.y; p1 = p0 + 1; }

  int wave = tid >> 6, lane = tid & 63;
  int quad = lane >> 4, l16 = lane & 15;

  for (int pan = p0; pan < p1; pan++){
    int bn = pan * 64;
    __syncthreads();                   // A staged (1st iter) / Bs consumers done (later iters)
    for (int u = tid; u < 64 * ku; u += 256){
      int n = u / ku, k8 = (u - n * ku) << 3;
      int gn = bn + n;
      s16x8 v;
      if (gn < Nn) v = *reinterpret_cast<const s16x8*>(&Bt[(size_t)gn * ldbt + k8]);
      else {
#pragma unroll
        for (int j = 0; j < 8; j++) v[j] = 0;
      }
      *reinterpret_cast<s16x8*>(&Bs[n * ldk + k8]) = v;
    }
    __syncthreads();

    f32x4 acc0 = {0.f,0.f,0.f,0.f}, acc1 = acc0, acc2 = acc0, acc3 = acc0;
    const short* brow = &Bs[(wave * 16 + l16) * ldk];
    const short* arow = &As[l16 * ldk];
    for (int kt = 0; kt < K; kt += 32){
      int kb = kt + quad * 8;
      s16x8 bfr = *reinterpret_cast<const s16x8*>(&brow[kb]);
      s16x8 a0 = *reinterpret_cast<const s16x8*>(&arow[kb]);
      s16x8 a1 = *reinterpret_cast<const s16x8*>(&arow[16 * ldk + kb]);
      s16x8 a2 = *reinterpret_cast<const s16x8*>(&arow[32 * ldk + kb]);
      s16x8 a3 = *reinterpret_cast<const s16x8*>(&arow[48 * ldk + kb]);
      acc0 = __builtin_amdgcn_mfma_f32_16x16x32_bf16(a0, bfr, acc0, 0, 0, 0);
      acc1 = __builtin_amdgcn_mfma_f32_16x16x32_bf16(a1, bfr, acc1, 0, 0, 0);
      acc2 = __builtin_amdgcn_mfma_f32_16x16x32_bf16(a2, bfr, acc2, 0, 0, 0);
      acc3 = __builtin_amdgcn_mfma_f32_16x16x32_bf16(a3, bfr, acc3, 0, 0, 0);
    }
    int gc = bn + wave * 16 + l16;
    if (gc < Nn){
      float bvv = bias ? bias[gc] : 0.f;
      f32x4 accs[4] = {acc0, acc1, acc2, acc3};
#pragma unroll
      for (int rt = 0; rt < 4; rt++){
#pragma unroll
        for (int r = 0; r < 4; r++){
          int gr = bm + rt * 16 + quad * 4 + r;
          if (gr >= M) continue;
          float vv = accs[rt][r] + bvv;
          if (mode == 1) vv = fmaxf(vv, 0.f);
          else if (mode == 2) vv = resid[(size_t)gr * ldr + gc] + fmaxf(vv, 0.f);
          C[(size_t)gr * ldc + gc] = vv;
        }
      }
    }
  }
}

// ---------------- ubar_q0: Q0 (25x256) + Ubar^T bf16 + cvec, one kernel ----------------
__global__ __launch_bounds__(256) void ubar_q0(const float* __restrict__ S0,
    const float* __restrict__ Wq0, const float* __restrict__ bq0,
    const float* __restrict__ Wk0, const float* __restrict__ bk0,
    float* __restrict__ Q0, short* __restrict__ Ubart, float* __restrict__ cvec)
{
  __shared__ float q0s[64];
  int j = blockIdx.x, h = j / 25, q = j - h * 25;
  int tid = threadIdx.x;
  if (tid < 64){
    int c = h * 64 + tid;
    float acc = bq0[c];
    for (int e = 0; e < 256; e++) acc = fmaf(S0[q * 256 + e], Wq0[e * 256 + c], acc);
    q0s[tid] = acc;
    Q0[q * 256 + c] = acc;
  }
  __syncthreads();
  float acc = 0.f;
  const float* wp = &Wk0[(size_t)tid * 256 + h * 64];
#pragma unroll
  for (int d = 0; d < 64; d++) acc = fmaf(wp[d], q0s[d], acc);
  Ubart[(size_t)j * 264 + tid] = f2bf(acc * 0.0625f);
  if (tid == 0){
    float cb = 0.f;
    for (int d = 0; d < 64; d++) cb = fmaf(bk0[h * 64 + d], q0s[d], cb);
    cvec[j] = cb * 0.0625f;
  }
}

// ---------------- GMPool_G fused softmax(q) + AV + residual (VdS combined layout) ----------------
__global__ __launch_bounds__(256) void av_pool0(const float* __restrict__ VdS,
    const float* __restrict__ Q0, float* __restrict__ O)
{
  __shared__ float Ssh[100 * 101];
  int g = blockIdx.x;
  int tid = threadIdx.x;
  for (int i = tid; i < 100 * 100; i += 256){
    int k = i / 100, jq = i - k * 100;
    Ssh[k * 101 + jq] = VdS[(size_t)(g * 100 + k) * 356 + 256 + jq];
  }
  __syncthreads();
  for (int p = tid; p < 400; p += 256){
    int k = p >> 2, h = p & 3;
    float* base = &Ssh[k * 101 + h * 25];
    float m = -1e30f;
#pragma unroll
    for (int q = 0; q < 25; q++) m = fmaxf(m, base[q]);
    float s = 0.f;
#pragma unroll
    for (int q = 0; q < 25; q++){ float e = __expf(base[q] - m); base[q] = e; s += e; }
    float inv = 1.0f / s;
#pragma unroll
    for (int q = 0; q < 25; q++) base[q] *= inv;
  }
  __syncthreads();
  int c = tid;
  int h = c >> 6;
  float acc[25] = {};
  const float* vp = VdS + (size_t)g * 100 * 356 + c;
  for (int k = 0; k < 100; k++){
    float v = vp[(size_t)k * 356];
    const float* a = &Ssh[k * 101 + h * 25];
#pragma unroll
    for (int q = 0; q < 25; q++) acc[q] = fmaf(a[q], v, acc[q]);
  }
#pragma unroll
  for (int q = 0; q < 25; q++)
    O[(size_t)(g * 25 + q) * 256 + c] = Q0[q * 256 + c] + acc[q];
}

// ---------------- SAB fully-fused attention (reads packed QKV, ld 384) ----------------
#define SST 132
__global__ __launch_bounds__(256) void sab_attn(const float* __restrict__ QKV,
    float* __restrict__ O)
{
  __shared__ float Qs[25 * SST];
  __shared__ float Ks[25 * SST];
  __shared__ float Vs[25 * SST];
  __shared__ float Ss[4 * 25 * 26];
  int g = blockIdx.x;
  int tid = threadIdx.x;
  for (int i = tid; i < 25 * 32; i += 256){
    int r = i >> 5, jj = i & 31;
    size_t src = (size_t)(g * 25 + r) * 384 + jj * 4;
    *reinterpret_cast<float4*>(&Qs[r * SST + jj * 4]) = *reinterpret_cast<const float4*>(&QKV[src]);
    *reinterpret_cast<float4*>(&Ks[r * SST + jj * 4]) = *reinterpret_cast<const float4*>(&QKV[src + 128]);
    *reinterpret_cast<float4*>(&Vs[r * SST + jj * 4]) = *reinterpret_cast<const float4*>(&QKV[src + 256]);
  }
  __syncthreads();
  for (int idx = tid; idx < 2500; idx += 256){
    int h = idx / 625;
    int r = idx - h * 625;
    int q = r / 25, k = r - q * 25;
    const float* qp = &Qs[q * SST + h * 32];
    const float* kp = &Ks[k * SST + h * 32];
    float acc = 0.f;
#pragma unroll
    for (int d = 0; d < 32; d += 4){
      float4 a4 = *reinterpret_cast<const float4*>(&qp[d]);
      float4 b4 = *reinterpret_cast<const float4*>(&kp[d]);
      acc = fmaf(a4.x, b4.x, acc); acc = fmaf(a4.y, b4.y, acc);
      acc = fmaf(a4.z, b4.z, acc); acc = fmaf(a4.w, b4.w, acc);
    }
    Ss[(h * 25 + q) * 26 + k] = acc * 0.0883883476f;
  }
  __syncthreads();
  if (tid < 100){
    int h = tid / 25, k = tid - h * 25;
    float m = -1e30f;
#pragma unroll
    for (int q = 0; q < 25; q++) m = fmaxf(m, Ss[(h * 25 + q) * 26 + k]);
    float s = 0.f;
#pragma unroll
    for (int q = 0; q < 25; q++){ float e = __expf(Ss[(h * 25 + q) * 26 + k] - m); Ss[(h * 25 + q) * 26 + k] = e; s += e; }
    float inv = 1.0f / s;
#pragma unroll
    for (int q = 0; q < 25; q++) Ss[(h * 25 + q) * 26 + k] *= inv;
  }
  __syncthreads();
  if (tid < 128){
    int c = tid, h = c >> 5;
    float acc[25] = {};
    for (int k = 0; k < 25; k++){
      float v = Vs[k * SST + c];
#pragma unroll
      for (int q = 0; q < 25; q++) acc[q] = fmaf(Ss[(h * 25 + q) * 26 + k], v, acc[q]);
    }
#pragma unroll
    for (int q = 0; q < 25; q++)
      O[(size_t)(g * 25 + q) * 128 + c] = Qs[q * SST + c] + acc[q];
  }
}

// ---------------- fully-fused head: O1 -> logits ----------------
__global__ __launch_bounds__(128) void head_fused(const float* __restrict__ O1,
    const float* __restrict__ S2,
    const float* __restrict__ Wq2, const float* __restrict__ bq2,
    const float* __restrict__ Wv2, const float* __restrict__ bv2,
    const float* __restrict__ Wo2, const float* __restrict__ bo2,
    const float* __restrict__ Wl,  const float* __restrict__ bl,
    const float* __restrict__ Wc1, const float* __restrict__ bc1,
    const float* __restrict__ Wc2, const float* __restrict__ bc2,
    const float* __restrict__ Wc3, const float* __restrict__ bc3,
    float* __restrict__ out)
{
  __shared__ float va[128], vb[128];
  int g = blockIdx.x, c = threadIdx.x;
  float s = 0.f;
  for (int k = 0; k < 25; k++) s += O1[(size_t)(g * 25 + k) * 128 + c];
  va[c] = s;
  __syncthreads();
  float o2 = bq2[c];
  for (int k = 0; k < 128; k++) o2 = fmaf(S2[k], Wq2[k * 128 + c], o2);
  o2 += 25.f * bv2[c];
  for (int k = 0; k < 128; k++) o2 = fmaf(va[k], Wv2[k * 128 + c], o2);
  __syncthreads(); vb[c] = o2; __syncthreads();
  float t = bo2[c];
  for (int k = 0; k < 128; k++) t = fmaf(vb[k], Wo2[k * 128 + c], t);
  float o2f = o2 + fmaxf(t, 0.f);
  va[c] = o2f; __syncthreads();
  float z = bl[c];
  for (int k = 0; k < 128; k++) z = fmaf(va[k], Wl[k * 128 + c], z);
  vb[c] = z; __syncthreads();
  float z1 = bc1[c];
  for (int k = 0; k < 128; k++) z1 = fmaf(vb[k], Wc1[k * 128 + c], z1);
  z1 = fmaxf(z1, 0.f);
  va[c] = z1; __syncthreads();
  if (c < 64){
    float z2 = bc2[c];
    for (int k = 0; k < 128; k++) z2 = fmaf(va[k], Wc2[k * 64 + c], z2);
    vb[c] = fmaxf(z2, 0.f);
  }
  __syncthreads();
  if (c < 10){
    float lg = bc3[c];
    for (int k = 0; k < 64; k++) lg = fmaf(vb[k], Wc3[k * 10 + c], lg);
    out[g * 10 + c] = lg;
  }
}

// ---------------- host ----------------
extern "C" void kernel_launch(void* const* d_in, const int* in_sizes, int n_in,
                              void* d_out, int out_size, void* d_ws, size_t ws_size,
                              hipStream_t stream)
{
  const int*  edge = (const int*)d_in[1];
  const int N = in_sizes[0] / FIN;      // 20000
  const int E = in_sizes[1] / 2;        // 320000
  const int G = N / MAXN;               // 200
  const int* srcp = edge;
  const int* dstp = edge + E;
  float* out = (float*)d_out;           // f32: [logits 200x10 | p1 200x128 | p2 200x128]

  float* w = (float*)d_ws;
  size_t off = 0;
  auto alloc = [&](size_t nfl){ nfl = (nfl + 3) & ~(size_t)3; float* p = w + off; off += nfl; return p; };
  auto allocS = [&](size_t nsh)->short*{ size_t nfl = ((nsh + 1) / 2 + 3) & ~(size_t)3; short* p = (short*)(w + off); off += nfl; return p; };

  float* dflag = alloc(1);
  float* degb  = alloc(N);

  // joint bias buffers for concat-GEMMs
  float* biasVS  = alloc(356);          // [bv0 (256) | cvec (100)]
  float* biasQKV = alloc(384);          // [bq1 | bk1 | bv1]
  float* cvec = biasVS + 256;

  const int castT[24] = {4,6,7,8,9,10,11,15,23,24,25,26,29,30,31,32,33,34,35,36,37,38,39,40};
  float* wf[41] = {nullptr};
  for (int i = 0; i < 24; i++) wf[castT[i]] = alloc((size_t)in_sizes[castT[i]]);
  wf[13] = biasVS; wf[17] = biasQKV; wf[19] = biasQKV + 128; wf[21] = biasQKV + 256;

  float* P0 = alloc((size_t)N * 256);   // xcat
  float* P1 = alloc((size_t)N * 256);   // xagg -> [Oa | O0]
  float* P2 = alloc((size_t)N * 256);   // GCN temps; later QKV
  float* P3 = alloc((size_t)N * 356);   // VdS; later Ob/O1
  float* Adj = alloc((size_t)G * MAXN * MAXN);
  float* Q0  = alloc(25 * 256);

  short* W1t   = allocS(128 * 136);
  short* W2t   = allocS(128 * 136);
  short* WVSt  = allocS(356 * 264);     // [Wv0t | Ubart]
  short* WQKVt = allocS(384 * 264);     // [Wq1t | Wk1t | Wv1t]
  short* Wo0t  = allocS(256 * 264);
  short* Wo1t  = allocS(128 * 136);
  short* Ubart = WVSt + (size_t)256 * 264;
  if (off * sizeof(float) > ws_size) return;

  float* Oa  = P1;
  float* O0  = P1 + (size_t)G * KS1 * 256;
  float* QKV = P2;
  float* Ob  = P3;
  float* O1  = P3 + (size_t)G * KS1 * 128;

  dim3 blk(256);
  auto gemmb = [&](const void* A, int lda, const short* Bt, int ldbt, const float* bias,
                   const float* resid, int ldr, float* C, int ldc, int M, int Nc, int K, int mode,
                   const float* aflag, bool nloop){
    dim3 grid(ceil_div(M, 64), nloop ? 1 : ceil_div(Nc, 64));
    size_t lb = (size_t)2 * 64 * (K + 8) * sizeof(short);
    gemm_bf16<<<grid, blk, lb, stream>>>(A, lda, Bt, ldbt, bias, resid, ldr, C, ldc, M, Nc, K, mode, aflag);
  };

  // 1. dtype sniff
  sniff_dtype<<<1, blk, 0, stream>>>((const unsigned short*)d_in[0], dflag);

  // 2. unified prep (flat 1-D: blocks proportional to work)
  PrepBatch pb; int ne = 0, blks = 0;
  auto addC = [&](const void* s, float* d, int n){
    pb.src[ne]=s; pb.dst[ne]=d; pb.a[ne]=n; pb.b[ne]=0; pb.blk0[ne]=blks;
    blks += ceil_div(ceil_div(n, 4), 256); ne++; };
  auto addW = [&](const void* s, short* d, int K, int Nn){
    pb.src[ne]=s; pb.dst[ne]=d; pb.a[ne]=K; pb.b[ne]=Nn; pb.blk0[ne]=blks;
    blks += ceil_div(K * Nn, 256); ne++; };
  for (int i = 0; i < 24; i++){ int t = castT[i]; addC(d_in[t], wf[t], in_sizes[t]); }
  addC(d_in[13], biasVS, 256);
  addC(d_in[17], biasQKV, 128); addC(d_in[19], biasQKV + 128, 128); addC(d_in[21], biasQKV + 256, 128);
  addW(d_in[3],  W1t, 128, 128);             addW(d_in[5],  W2t, 128, 128);
  addW(d_in[12], WVSt, 256, 256);            addW(d_in[16], WQKVt, 256, 128);
  addW(d_in[18], WQKVt + 128*264, 256, 128); addW(d_in[20], WQKVt + 256*264, 256, 128);
  addW(d_in[14], Wo0t, 256, 256);            addW(d_in[22], Wo1t, 128, 128);
  pb.blk0[ne] = blks; pb.ne = ne;
  prep_all<<<dim3(blks), blk, 0, stream>>>(pb, dflag);

  // 3-5. adjacency (A zero + deg init; deg atomics; diag+edges all-atomic)
  int totalA = G * MAXN * MAXN;
  zero_init<<<ceil_div(totalA, 256), blk, 0, stream>>>(Adj, degb, totalA, N);
  deg_edges<<<ceil_div(E, 256), blk, 0, stream>>>(dstp, degb, E);
  adj_fin<<<ceil_div(N + E, 256), blk, 0, stream>>>(srcp, dstp, degb, Adj, N, E);

  // 6-9. GCN1 / GCN2: gemm, then prop with fused pool AND fused second hop (xagg half)
  gemmb(d_in[0], 128, W1t, 136, nullptr, nullptr, 0, P2, 128, N, 128, 128, 0, dflag, true);
  prop_gemm<<<dim3(G, 2), blk, 0, stream>>>(Adj, P2, 128, wf[4], P0, 256, 1, out + 2000, P1, 256);
  gemmb(P0, 256, W2t, 136, nullptr, nullptr, 0, P2, 128, N, 128, 128, 0, nullptr, true);
  prop_gemm<<<dim3(G, 2), blk, 0, stream>>>(Adj, P2, 128, wf[6], P0 + 128, 256, 1, out + 27600, P1 + 128, 256);

  // 10. Q0 + Ubar^T + cvec
  ubar_q0<<<dim3(100), blk, 0, stream>>>(wf[7], wf[8], wf[9], wf[10], wf[11], Q0, Ubart, cvec);

  // 11. [Vd | S2d] = xagg @ [Wv0 | Ubar]^T + [bv0 | cvec] (N-loop: stage A once)
  gemmb(P1, 256, WVSt, 264, biasVS, nullptr, 0, P3, 356, N, 356, 256, 0, nullptr, true);

  // 12-13. fused q-softmax+AV+residual, then Wo0 (mode2)
  av_pool0<<<dim3(G), blk, 0, stream>>>(P3, Q0, Oa);
  gemmb(Oa, 256, Wo0t, 264, wf[15], Oa, 256, O0, 256, G * KS1, 256, 256, 2, nullptr, false);

  // 14-16. SAB: packed QKV GEMM, fused attention, Wo1 (mode2)
  gemmb(O0, 256, WQKVt, 264, biasQKV, nullptr, 0, QKV, 384, G * KS1, 384, 256, 0, nullptr, false);
  sab_attn<<<dim3(G), blk, 0, stream>>>(QKV, Ob);
  gemmb(Ob, 128, Wo1t, 136, wf[23], Ob, 128, O1, 128, G * KS1, 128, 128, 2, nullptr, false);

  // 17. fused head -> logits
  head_fused<<<dim3(G), dim3(128), 0, stream>>>(O1, wf[24], wf[25], wf[26], wf[29], wf[30],
      wf[31], wf[32], wf[33], wf[34], wf[35], wf[36], wf[37], wf[38], wf[39], wf[40], out);
}

// Round 9
// 398.478 us; speedup vs baseline: 4.8906x; 1.0502x over previous
//
#include <hip/hip_runtime.h>
#include <hip/hip_bf16.h>
#include <cstdint>
#include <cstddef>

typedef __hip_bfloat16 bf16;
typedef __attribute__((ext_vector_type(8))) short s16x8;
typedef __attribute__((ext_vector_type(4))) float f32x4;

#define MAXN 100
#define HH   4
#define FIN  128
#define KS1  25

static inline int ceil_div(int a, int b){ return (a + b - 1) / b; }

__device__ inline short f2bf(float f){               // RNE float->bf16 bits
  unsigned int u = __float_as_uint(f);
  u = (u + 0x7FFF + ((u >> 16) & 1)) >> 16;
  return (short)u;
}
__device__ inline float loadf(const void* s, int i, bool isbf){
  return isbf ? __bfloat162float(((const bf16*)s)[i]) : ((const float*)s)[i];
}

// ---------------- input dtype sniff ----------------
__global__ __launch_bounds__(256) void sniff_dtype(const unsigned short* __restrict__ u,
                                                   float* __restrict__ flag){
  __shared__ int cnt;
  if (threadIdx.x == 0) cnt = 0;
  __syncthreads();
  unsigned short b = u[2 * threadIdx.x];
  unsigned int w = ((unsigned int)b) << 16;
  float v = __uint_as_float(w);
  float a = fabsf(v);
  if (a >= 6.1e-5f && a <= 16384.f) atomicAdd(&cnt, 1);
  __syncthreads();
  if (threadIdx.x == 0) *flag = (cnt >= 128) ? 1.0f : 0.0f;
}

// ---------------- unified prep: flat 1-D grid, blocks proportional to work ----------------
struct PrepBatch {
  const void* src[40];
  void*       dst[40];
  int         a[40];     // cast: n elements ; wprep: K
  int         b[40];     // cast: 0 ; wprep: N  (Wt[n][K+8] = bf16(W[k][n]))
  int         blk0[41];
  int         ne;
};

__global__ __launch_bounds__(256) void prep_all(PrepBatch pb, const float* __restrict__ flag){
  int blk = blockIdx.x;
  int t = 0;
  while (t + 1 < pb.ne && pb.blk0[t + 1] <= blk) t++;
  int local = blk - pb.blk0[t];
  bool isbf = (*flag != 0.0f);
  const void* s = pb.src[t];
  if (pb.b[t] == 0){
    int n = pb.a[t];
    float* d = (float*)pb.dst[t];
    int v = local * 256 + threadIdx.x;
    int base = v * 4;
    if (base + 3 < n){
      float4 f;
      if (isbf){
        ushort4 u = ((const ushort4*)s)[v];
        f.x = __uint_as_float(((unsigned)u.x) << 16);
        f.y = __uint_as_float(((unsigned)u.y) << 16);
        f.z = __uint_as_float(((unsigned)u.z) << 16);
        f.w = __uint_as_float(((unsigned)u.w) << 16);
      } else f = ((const float4*)s)[v];
      ((float4*)d)[v] = f;
    } else {
      for (int j = base; j < n && j < base + 4; j++) d[j] = loadf(s, j, isbf);
    }
  } else {
    int K = pb.a[t], Nn = pb.b[t], ldt = K + 8;
    short* d = (short*)pb.dst[t];
    int i = local * 256 + threadIdx.x;
    if (i < K * Nn){
      int n = i / K, k = i - n * K;        // k-fast: coalesced 2B writes
      d[(size_t)n * ldt + k] = f2bf(loadf(s, (size_t)k * Nn + n, isbf));
    }
  }
}

// ---------------- adjacency build ----------------
__global__ __launch_bounds__(256) void zero_init(float* __restrict__ A, float* __restrict__ deg,
                                                 int totalA, int n){
  int i = blockIdx.x * 256 + threadIdx.x;
  if (i < totalA) A[i] = 0.f;
  if (i < n) deg[i] = 1.0f;
}
__global__ __launch_bounds__(256) void deg_edges(const int* __restrict__ dst, float* deg, int e){
  int i = blockIdx.x * 256 + threadIdx.x;
  if (i < e) atomicAdd(&deg[dst[i]], 1.0f);
}
__global__ __launch_bounds__(256) void adj_fin(const int* __restrict__ src, const int* __restrict__ dst,
                                               const float* __restrict__ deg,
                                               float* __restrict__ A, int n, int e){
  int i = blockIdx.x * 256 + threadIdx.x;
  if (i < n){
    float dv = rsqrtf(deg[i]);
    int g = i / MAXN, r = i - g * MAXN;
    atomicAdd(&A[(size_t)g * (MAXN * MAXN) + r * MAXN + r], dv * dv);
  } else if (i < n + e){
    int j = i - n;
    int s = src[j], d = dst[j];
    float nv = rsqrtf(deg[s]) * rsqrtf(deg[d]);
    int g = d / MAXN;
    int dl = d - g * MAXN;
    int sl = s - (s / MAXN) * MAXN;
    atomicAdd(&A[(size_t)g * (MAXN * MAXN) + dl * MAXN + sl], nv);
  }
}

// ---------------- batched dense propagation + fused pool + fused bf16 second hop ----------------
#define ASTRIDE 101
#define TSTRIDE 68
__global__ __launch_bounds__(256) void prop_gemm(
    const float* __restrict__ A,
    const float* __restrict__ T, int ldt,
    const float* __restrict__ bias,
    float* __restrict__ Y, int ldy,
    int relu, float* __restrict__ pool,
    short* __restrict__ YaggB, int ldya)   // bf16 second-hop output (xagg)
{
  __shared__ float As[112 * ASTRIDE];
  __shared__ float Ts[MAXN * TSTRIDE];
  int g = blockIdx.x;
  int c0 = blockIdx.y * 64;
  int tid = threadIdx.x;
  const float* Ag = A + (size_t)g * (MAXN * MAXN);
  for (int i = tid; i < MAXN * MAXN; i += 256){
    int r = i / MAXN, s = i - r * MAXN;
    As[r * ASTRIDE + s] = Ag[i];
  }
  for (int i = tid; i < MAXN * 16; i += 256){
    int s = i >> 4, jj = i & 15;
    float4 v = *reinterpret_cast<const float4*>(&T[(size_t)(g * MAXN + s) * ldt + c0 + jj * 4]);
    *reinterpret_cast<float4*>(&Ts[s * TSTRIDE + jj * 4]) = v;
  }
  __syncthreads();

  int tx = tid & 15, ty = tid >> 4;
  float acc[7][4] = {};
#pragma unroll 2
  for (int s = 0; s < MAXN; s++){
    float4 t4 = *reinterpret_cast<const float4*>(&Ts[s * TSTRIDE + tx * 4]);
    float t[4] = {t4.x, t4.y, t4.z, t4.w};
#pragma unroll
    for (int i = 0; i < 7; i++){
      float a = As[(ty * 7 + i) * ASTRIDE + s];
#pragma unroll
      for (int j = 0; j < 4; j++) acc[i][j] = fmaf(a, t[j], acc[i][j]);
    }
  }

  float4 b4 = make_float4(0.f, 0.f, 0.f, 0.f);
  if (bias) b4 = *reinterpret_cast<const float4*>(&bias[c0 + tx * 4]);
  float bv[4] = {b4.x, b4.y, b4.z, b4.w};
  float ps[4] = {0.f, 0.f, 0.f, 0.f};
#pragma unroll
  for (int i = 0; i < 7; i++){
    int r = ty * 7 + i;
    if (r >= MAXN) continue;
#pragma unroll
    for (int j = 0; j < 4; j++){
      float v = acc[i][j] + bv[j];
      if (relu) v = fmaxf(v, 0.f);
      acc[i][j] = v;
      ps[j] += v;
    }
    *reinterpret_cast<float4*>(&Y[(size_t)(g * MAXN + r) * ldy + c0 + tx * 4]) =
        make_float4(acc[i][0], acc[i][1], acc[i][2], acc[i][3]);
  }

  if (YaggB){                          // second hop: xagg = A @ Y, written as bf16
    __syncthreads();
#pragma unroll
    for (int i = 0; i < 7; i++){
      int r = ty * 7 + i;
      if (r >= MAXN) continue;
      *reinterpret_cast<float4*>(&Ts[r * TSTRIDE + tx * 4]) =
          make_float4(acc[i][0], acc[i][1], acc[i][2], acc[i][3]);
    }
    __syncthreads();
    float acc2[7][4] = {};
#pragma unroll 2
    for (int s = 0; s < MAXN; s++){
      float4 t4 = *reinterpret_cast<const float4*>(&Ts[s * TSTRIDE + tx * 4]);
      float t[4] = {t4.x, t4.y, t4.z, t4.w};
#pragma unroll
      for (int i = 0; i < 7; i++){
        float a = As[(ty * 7 + i) * ASTRIDE + s];
#pragma unroll
        for (int j = 0; j < 4; j++) acc2[i][j] = fmaf(a, t[j], acc2[i][j]);
      }
    }
#pragma unroll
    for (int i = 0; i < 7; i++){
      int r = ty * 7 + i;
      if (r >= MAXN) continue;
      short4 o;
      o.x = f2bf(acc2[i][0]); o.y = f2bf(acc2[i][1]);
      o.z = f2bf(acc2[i][2]); o.w = f2bf(acc2[i][3]);
      *reinterpret_cast<short4*>(&YaggB[(size_t)(g * MAXN + r) * ldya + c0 + tx * 4]) = o;
    }
  }

  if (pool){
    __syncthreads();
    float* red = As;
#pragma unroll
    for (int j = 0; j < 4; j++) red[(tx * 4 + j) * 17 + ty] = ps[j];
    __syncthreads();
    if (tid < 64){
      float s = 0.f;
#pragma unroll
      for (int t2 = 0; t2 < 16; t2++) s += red[tid * 17 + t2];
      pool[g * 128 + c0 + tid] = s;
    }
  }
}

// ---------------- MFMA bf16 GEMM, occupancy-first structure ----------------
// Block = 64 rows x 128 cols; A-only LDS (bf16); B preloaded into VGPRs from
// L2-resident Bt; 2 col-groups per wave; 2-D grid; K templated (128/256).
// abf: 0 = A fp32, 1 = A bf16, -1 = runtime via aflag.
template<int K>
__global__ __launch_bounds__(256) void gemm_bf16_t(
    const void* __restrict__ A, int lda,
    const short* __restrict__ Bt, int ldbt,
    const float* __restrict__ bias,
    const float* __restrict__ resid, int ldr,
    float* __restrict__ C, int ldc,
    int M, int Nn, int mode,
    const float* __restrict__ aflag, int abf)
{
  constexpr int LDK = K + 8;
  constexpr int KU = K / 8;
  constexpr int KT = K / 32;
  __shared__ short As[64 * LDK];
  int bm = blockIdx.x * 64, bn = blockIdx.y * 128;
  int tid = threadIdx.x;
  int wave = tid >> 6, lane = tid & 63;
  int quad = lane >> 4, l16 = lane & 15;
  bool isbf = (abf == 1) || (abf == -1 && *aflag != 0.0f);

  // preload B fragments (registers); overlaps with A staging below
  int gn0 = bn + wave * 16 + l16;
  int gn1 = gn0 + 64;
  s16x8 B0[KT], B1[KT];
#pragma unroll
  for (int kt = 0; kt < KT; kt++){
    int kb = kt * 32 + quad * 8;
    s16x8 z; 
#pragma unroll
    for (int j = 0; j < 8; j++) z[j] = 0;
    B0[kt] = (gn0 < Nn) ? *reinterpret_cast<const s16x8*>(&Bt[(size_t)gn0 * ldbt + kb]) : z;
    B1[kt] = (gn1 < Nn) ? *reinterpret_cast<const s16x8*>(&Bt[(size_t)gn1 * ldbt + kb]) : z;
  }

  // stage A tile (bf16) into LDS
  for (int u = tid; u < 64 * KU; u += 256){
    int r = u / KU, k8 = (u - r * KU) << 3;
    int gr = bm + r;
    s16x8 v;
    if (gr < M){
      if (isbf){
        v = *reinterpret_cast<const s16x8*>((const short*)A + (size_t)gr * lda + k8);
      } else {
        const float* ap = (const float*)A + (size_t)gr * lda + k8;
        float4 f0 = *reinterpret_cast<const float4*>(ap);
        float4 f1 = *reinterpret_cast<const float4*>(ap + 4);
        v[0] = f2bf(f0.x); v[1] = f2bf(f0.y); v[2] = f2bf(f0.z); v[3] = f2bf(f0.w);
        v[4] = f2bf(f1.x); v[5] = f2bf(f1.y); v[6] = f2bf(f1.z); v[7] = f2bf(f1.w);
      }
    } else {
#pragma unroll
      for (int j = 0; j < 8; j++) v[j] = 0;
    }
    *reinterpret_cast<s16x8*>(&As[r * LDK + k8]) = v;
  }
  __syncthreads();

  f32x4 acc[4][2];
#pragma unroll
  for (int rt = 0; rt < 4; rt++)
#pragma unroll
    for (int g2 = 0; g2 < 2; g2++) acc[rt][g2] = (f32x4){0.f,0.f,0.f,0.f};

  const short* arow = &As[l16 * LDK];
#pragma unroll
  for (int kt = 0; kt < KT; kt++){
    int kb = kt * 32 + quad * 8;
#pragma unroll
    for (int rt = 0; rt < 4; rt++){
      s16x8 a = *reinterpret_cast<const s16x8*>(&arow[rt * 16 * LDK + kb]);
      acc[rt][0] = __builtin_amdgcn_mfma_f32_16x16x32_bf16(a, B0[kt], acc[rt][0], 0, 0, 0);
      acc[rt][1] = __builtin_amdgcn_mfma_f32_16x16x32_bf16(a, B1[kt], acc[rt][1], 0, 0, 0);
    }
  }

#pragma unroll
  for (int g2 = 0; g2 < 2; g2++){
    int gc = (g2 == 0) ? gn0 : gn1;
    if (gc >= Nn) continue;
    float bvv = bias ? bias[gc] : 0.f;
#pragma unroll
    for (int rt = 0; rt < 4; rt++){
#pragma unroll
      for (int r = 0; r < 4; r++){
        int gr = bm + rt * 16 + quad * 4 + r;
        if (gr >= M) continue;
        float vv = acc[rt][g2][r] + bvv;
        if (mode == 1) vv = fmaxf(vv, 0.f);
        else if (mode == 2) vv = resid[(size_t)gr * ldr + gc] + fmaxf(vv, 0.f);
        C[(size_t)gr * ldc + gc] = vv;
      }
    }
  }
}

// ---------------- ubar_q0 ----------------
__global__ __launch_bounds__(256) void ubar_q0(const float* __restrict__ S0,
    const float* __restrict__ Wq0, const float* __restrict__ bq0,
    const float* __restrict__ Wk0, const float* __restrict__ bk0,
    float* __restrict__ Q0, short* __restrict__ Ubart, float* __restrict__ cvec)
{
  __shared__ float q0s[64];
  int j = blockIdx.x, h = j / 25, q = j - h * 25;
  int tid = threadIdx.x;
  if (tid < 64){
    int c = h * 64 + tid;
    float acc = bq0[c];
    for (int e = 0; e < 256; e++) acc = fmaf(S0[q * 256 + e], Wq0[e * 256 + c], acc);
    q0s[tid] = acc;
    Q0[q * 256 + c] = acc;
  }
  __syncthreads();
  float acc = 0.f;
  const float* wp = &Wk0[(size_t)tid * 256 + h * 64];
#pragma unroll
  for (int d = 0; d < 64; d++) acc = fmaf(wp[d], q0s[d], acc);
  Ubart[(size_t)j * 264 + tid] = f2bf(acc * 0.0625f);
  if (tid == 0){
    float cb = 0.f;
    for (int d = 0; d < 64; d++) cb = fmaf(bk0[h * 64 + d], q0s[d], cb);
    cvec[j] = cb * 0.0625f;
  }
}

// ---------------- GMPool_G fused softmax(q) + AV + residual ----------------
__global__ __launch_bounds__(256) void av_pool0(const float* __restrict__ VdS,
    const float* __restrict__ Q0, float* __restrict__ O)
{
  __shared__ float Ssh[100 * 101];
  int g = blockIdx.x;
  int tid = threadIdx.x;
  for (int i = tid; i < 100 * 100; i += 256){
    int k = i / 100, jq = i - k * 100;
    Ssh[k * 101 + jq] = VdS[(size_t)(g * 100 + k) * 356 + 256 + jq];
  }
  __syncthreads();
  for (int p = tid; p < 400; p += 256){
    int k = p >> 2, h = p & 3;
    float* base = &Ssh[k * 101 + h * 25];
    float m = -1e30f;
#pragma unroll
    for (int q = 0; q < 25; q++) m = fmaxf(m, base[q]);
    float s = 0.f;
#pragma unroll
    for (int q = 0; q < 25; q++){ float e = __expf(base[q] - m); base[q] = e; s += e; }
    float inv = 1.0f / s;
#pragma unroll
    for (int q = 0; q < 25; q++) base[q] *= inv;
  }
  __syncthreads();
  int c = tid;
  int h = c >> 6;
  float acc[25] = {};
  const float* vp = VdS + (size_t)g * 100 * 356 + c;
  for (int k = 0; k < 100; k++){
    float v = vp[(size_t)k * 356];
    const float* a = &Ssh[k * 101 + h * 25];
#pragma unroll
    for (int q = 0; q < 25; q++) acc[q] = fmaf(a[q], v, acc[q]);
  }
#pragma unroll
  for (int q = 0; q < 25; q++)
    O[(size_t)(g * 25 + q) * 256 + c] = Q0[q * 256 + c] + acc[q];
}

// ---------------- SAB fully-fused attention ----------------
#define SST 132
__global__ __launch_bounds__(256) void sab_attn(const float* __restrict__ QKV,
    float* __restrict__ O)
{
  __shared__ float Qs[25 * SST];
  __shared__ float Ks[25 * SST];
  __shared__ float Vs[25 * SST];
  __shared__ float Ss[4 * 25 * 26];
  int g = blockIdx.x;
  int tid = threadIdx.x;
  for (int i = tid; i < 25 * 32; i += 256){
    int r = i >> 5, jj = i & 31;
    size_t src = (size_t)(g * 25 + r) * 384 + jj * 4;
    *reinterpret_cast<float4*>(&Qs[r * SST + jj * 4]) = *reinterpret_cast<const float4*>(&QKV[src]);
    *reinterpret_cast<float4*>(&Ks[r * SST + jj * 4]) = *reinterpret_cast<const float4*>(&QKV[src + 128]);
    *reinterpret_cast<float4*>(&Vs[r * SST + jj * 4]) = *reinterpret_cast<const float4*>(&QKV[src + 256]);
  }
  __syncthreads();
  for (int idx = tid; idx < 2500; idx += 256){
    int h = idx / 625;
    int r = idx - h * 625;
    int q = r / 25, k = r - q * 25;
    const float* qp = &Qs[q * SST + h * 32];
    const float* kp = &Ks[k * SST + h * 32];
    float acc = 0.f;
#pragma unroll
    for (int d = 0; d < 32; d += 4){
      float4 a4 = *reinterpret_cast<const float4*>(&qp[d]);
      float4 b4 = *reinterpret_cast<const float4*>(&kp[d]);
      acc = fmaf(a4.x, b4.x, acc); acc = fmaf(a4.y, b4.y, acc);
      acc = fmaf(a4.z, b4.z, acc); acc = fmaf(a4.w, b4.w, acc);
    }
    Ss[(h * 25 + q) * 26 + k] = acc * 0.0883883476f;
  }
  __syncthreads();
  if (tid < 100){
    int h = tid / 25, k = tid - h * 25;
    float m = -1e30f;
#pragma unroll
    for (int q = 0; q < 25; q++) m = fmaxf(m, Ss[(h * 25 + q) * 26 + k]);
    float s = 0.f;
#pragma unroll
    for (int q = 0; q < 25; q++){ float e = __expf(Ss[(h * 25 + q) * 26 + k] - m); Ss[(h * 25 + q) * 26 + k] = e; s += e; }
    float inv = 1.0f / s;
#pragma unroll
    for (int q = 0; q < 25; q++) Ss[(h * 25 + q) * 26 + k] *= inv;
  }
  __syncthreads();
  if (tid < 128){
    int c = tid, h = c >> 5;
    float acc[25] = {};
    for (int k = 0; k < 25; k++){
      float v = Vs[k * SST + c];
#pragma unroll
      for (int q = 0; q < 25; q++) acc[q] = fmaf(Ss[(h * 25 + q) * 26 + k], v, acc[q]);
    }
#pragma unroll
    for (int q = 0; q < 25; q++)
      O[(size_t)(g * 25 + q) * 128 + c] = Qs[q * SST + c] + acc[q];
  }
}

// ---------------- fully-fused head ----------------
__global__ __launch_bounds__(128) void head_fused(const float* __restrict__ O1,
    const float* __restrict__ S2,
    const float* __restrict__ Wq2, const float* __restrict__ bq2,
    const float* __restrict__ Wv2, const float* __restrict__ bv2,
    const float* __restrict__ Wo2, const float* __restrict__ bo2,
    const float* __restrict__ Wl,  const float* __restrict__ bl,
    const float* __restrict__ Wc1, const float* __restrict__ bc1,
    const float* __restrict__ Wc2, const float* __restrict__ bc2,
    const float* __restrict__ Wc3, const float* __restrict__ bc3,
    float* __restrict__ out)
{
  __shared__ float va[128], vb[128];
  int g = blockIdx.x, c = threadIdx.x;
  float s = 0.f;
  for (int k = 0; k < 25; k++) s += O1[(size_t)(g * 25 + k) * 128 + c];
  va[c] = s;
  __syncthreads();
  float o2 = bq2[c];
  for (int k = 0; k < 128; k++) o2 = fmaf(S2[k], Wq2[k * 128 + c], o2);
  o2 += 25.f * bv2[c];
  for (int k = 0; k < 128; k++) o2 = fmaf(va[k], Wv2[k * 128 + c], o2);
  __syncthreads(); vb[c] = o2; __syncthreads();
  float t = bo2[c];
  for (int k = 0; k < 128; k++) t = fmaf(vb[k], Wo2[k * 128 + c], t);
  float o2f = o2 + fmaxf(t, 0.f);
  va[c] = o2f; __syncthreads();
  float z = bl[c];
  for (int k = 0; k < 128; k++) z = fmaf(va[k], Wl[k * 128 + c], z);
  vb[c] = z; __syncthreads();
  float z1 = bc1[c];
  for (int k = 0; k < 128; k++) z1 = fmaf(vb[k], Wc1[k * 128 + c], z1);
  z1 = fmaxf(z1, 0.f);
  va[c] = z1; __syncthreads();
  if (c < 64){
    float z2 = bc2[c];
    for (int k = 0; k < 128; k++) z2 = fmaf(va[k], Wc2[k * 64 + c], z2);
    vb[c] = fmaxf(z2, 0.f);
  }
  __syncthreads();
  if (c < 10){
    float lg = bc3[c];
    for (int k = 0; k < 64; k++) lg = fmaf(vb[k], Wc3[k * 10 + c], lg);
    out[g * 10 + c] = lg;
  }
}

// ---------------- host ----------------
extern "C" void kernel_launch(void* const* d_in, const int* in_sizes, int n_in,
                              void* d_out, int out_size, void* d_ws, size_t ws_size,
                              hipStream_t stream)
{
  const int*  edge = (const int*)d_in[1];
  const int N = in_sizes[0] / FIN;      // 20000
  const int E = in_sizes[1] / 2;        // 320000
  const int G = N / MAXN;               // 200
  const int* srcp = edge;
  const int* dstp = edge + E;
  float* out = (float*)d_out;           // f32: [logits 200x10 | p1 200x128 | p2 200x128]

  float* w = (float*)d_ws;
  size_t off = 0;
  auto alloc = [&](size_t nfl){ nfl = (nfl + 3) & ~(size_t)3; float* p = w + off; off += nfl; return p; };
  auto allocS = [&](size_t nsh)->short*{ size_t nfl = ((nsh + 1) / 2 + 3) & ~(size_t)3; short* p = (short*)(w + off); off += nfl; return p; };

  float* dflag = alloc(1);
  float* degb  = alloc(N);

  float* biasVS  = alloc(356);          // [bv0 | cvec]
  float* biasQKV = alloc(384);          // [bq1 | bk1 | bv1]
  float* cvec = biasVS + 256;

  const int castT[24] = {4,6,7,8,9,10,11,15,23,24,25,26,29,30,31,32,33,34,35,36,37,38,39,40};
  float* wf[41] = {nullptr};
  for (int i = 0; i < 24; i++) wf[castT[i]] = alloc((size_t)in_sizes[castT[i]]);
  wf[13] = biasVS; wf[17] = biasQKV; wf[19] = biasQKV + 128; wf[21] = biasQKV + 256;

  float* P0 = alloc((size_t)N * 256);   // xcat
  float* P1 = alloc((size_t)N * 256);   // [Oa | O0]
  float* P2 = alloc((size_t)N * 256);   // GCN temps; later QKV
  float* P3 = alloc((size_t)N * 356);   // VdS; later Ob/O1
  float* Adj = alloc((size_t)G * MAXN * MAXN);
  float* Q0  = alloc(25 * 256);
  short* xaggB = allocS((size_t)N * 256);  // bf16 xagg

  short* W1t   = allocS(128 * 136);
  short* W2t   = allocS(128 * 136);
  short* WVSt  = allocS(356 * 264);     // [Wv0t | Ubart]
  short* WQKVt = allocS(384 * 264);     // [Wq1t | Wk1t | Wv1t]
  short* Wo0t  = allocS(256 * 264);
  short* Wo1t  = allocS(128 * 136);
  short* Ubart = WVSt + (size_t)256 * 264;
  if (off * sizeof(float) > ws_size) return;

  float* Oa  = P1;
  float* O0  = P1 + (size_t)G * KS1 * 256;
  float* QKV = P2;
  float* Ob  = P3;
  float* O1  = P3 + (size_t)G * KS1 * 128;

  dim3 blk(256);
  auto gemmb = [&](const void* A, int lda, const short* Bt, int ldbt, const float* bias,
                   const float* resid, int ldr, float* C, int ldc, int M, int Nc, int K, int mode,
                   const float* aflag, int abf){
    dim3 grid(ceil_div(M, 64), ceil_div(Nc, 128));
    if (K == 128)
      gemm_bf16_t<128><<<grid, blk, 0, stream>>>(A, lda, Bt, ldbt, bias, resid, ldr, C, ldc, M, Nc, mode, aflag, abf);
    else
      gemm_bf16_t<256><<<grid, blk, 0, stream>>>(A, lda, Bt, ldbt, bias, resid, ldr, C, ldc, M, Nc, mode, aflag, abf);
  };

  // 1. dtype sniff
  sniff_dtype<<<1, blk, 0, stream>>>((const unsigned short*)d_in[0], dflag);

  // 2. unified prep
  PrepBatch pb; int ne = 0, blks = 0;
  auto addC = [&](const void* s, float* d, int n){
    pb.src[ne]=s; pb.dst[ne]=d; pb.a[ne]=n; pb.b[ne]=0; pb.blk0[ne]=blks;
    blks += ceil_div(ceil_div(n, 4), 256); ne++; };
  auto addW = [&](const void* s, short* d, int K, int Nn){
    pb.src[ne]=s; pb.dst[ne]=d; pb.a[ne]=K; pb.b[ne]=Nn; pb.blk0[ne]=blks;
    blks += ceil_div(K * Nn, 256); ne++; };
  for (int i = 0; i < 24; i++){ int t = castT[i]; addC(d_in[t], wf[t], in_sizes[t]); }
  addC(d_in[13], biasVS, 256);
  addC(d_in[17], biasQKV, 128); addC(d_in[19], biasQKV + 128, 128); addC(d_in[21], biasQKV + 256, 128);
  addW(d_in[3],  W1t, 128, 128);             addW(d_in[5],  W2t, 128, 128);
  addW(d_in[12], WVSt, 256, 256);            addW(d_in[16], WQKVt, 256, 128);
  addW(d_in[18], WQKVt + 128*264, 256, 128); addW(d_in[20], WQKVt + 256*264, 256, 128);
  addW(d_in[14], Wo0t, 256, 256);            addW(d_in[22], Wo1t, 128, 128);
  pb.blk0[ne] = blks; pb.ne = ne;
  prep_all<<<dim3(blks), blk, 0, stream>>>(pb, dflag);

  // 3-5. adjacency
  int totalA = G * MAXN * MAXN;
  zero_init<<<ceil_div(totalA, 256), blk, 0, stream>>>(Adj, degb, totalA, N);
  deg_edges<<<ceil_div(E, 256), blk, 0, stream>>>(dstp, degb, E);
  adj_fin<<<ceil_div(N + E, 256), blk, 0, stream>>>(srcp, dstp, degb, Adj, N, E);

  // 6-9. GCN1 / GCN2: gemm, prop (fused pool + fused bf16 xagg half)
  gemmb(d_in[0], 128, W1t, 136, nullptr, nullptr, 0, P2, 128, N, 128, 128, 0, dflag, -1);
  prop_gemm<<<dim3(G, 2), blk, 0, stream>>>(Adj, P2, 128, wf[4], P0, 256, 1, out + 2000, xaggB, 256);
  gemmb(P0, 256, W2t, 136, nullptr, nullptr, 0, P2, 128, N, 128, 128, 0, nullptr, 0);
  prop_gemm<<<dim3(G, 2), blk, 0, stream>>>(Adj, P2, 128, wf[6], P0 + 128, 256, 1, out + 27600, xaggB + 128, 256);

  // 10. Q0 + Ubar^T + cvec
  ubar_q0<<<dim3(100), blk, 0, stream>>>(wf[7], wf[8], wf[9], wf[10], wf[11], Q0, Ubart, cvec);

  // 11. [Vd | S2d] = xagg @ [Wv0 | Ubar]^T + [bv0 | cvec]  (A already bf16)
  gemmb(xaggB, 256, WVSt, 264, biasVS, nullptr, 0, P3, 356, N, 356, 256, 0, nullptr, 1);

  // 12-13. fused q-softmax+AV+residual, then Wo0 (mode2)
  av_pool0<<<dim3(G), blk, 0, stream>>>(P3, Q0, Oa);
  gemmb(Oa, 256, Wo0t, 264, wf[15], Oa, 256, O0, 256, G * KS1, 256, 256, 2, nullptr, 0);

  // 14-16. SAB
  gemmb(O0, 256, WQKVt, 264, biasQKV, nullptr, 0, QKV, 384, G * KS1, 384, 256, 0, nullptr, 0);
  sab_attn<<<dim3(G), blk, 0, stream>>>(QKV, Ob);
  gemmb(Ob, 128, Wo1t, 136, wf[23], Ob, 128, O1, 128, G * KS1, 128, 128, 2, nullptr, 0);

  // 17. fused head -> logits
  head_fused<<<dim3(G), dim3(128), 0, stream>>>(O1, wf[24], wf[25], wf[26], wf[29], wf[30],
      wf[31], wf[32], wf[33], wf[34], wf[35], wf[36], wf[37], wf[38], wf[39], wf[40], out);
}

// Round 10
// 340.079 us; speedup vs baseline: 5.7304x; 1.1717x over previous
//
#include <hip/hip_runtime.h>
#include <hip/hip_bf16.h>
#include <cstdint>
#include <cstddef>

typedef __hip_bfloat16 bf16;
typedef __attribute__((ext_vector_type(8))) short s16x8;
typedef __attribute__((ext_vector_type(4))) float f32x4;

#define MAXN 100
#define HH   4
#define FIN  128
#define KS1  25

static inline int ceil_div(int a, int b){ return (a + b - 1) / b; }

__device__ inline short f2bf(float f){               // RNE float->bf16 bits
  unsigned int u = __float_as_uint(f);
  u = (u + 0x7FFF + ((u >> 16) & 1)) >> 16;
  return (short)u;
}
__device__ inline float loadf(const void* s, int i, bool isbf){
  return isbf ? __bfloat162float(((const bf16*)s)[i]) : ((const float*)s)[i];
}

// ---------------- input dtype sniff ----------------
__global__ __launch_bounds__(256) void sniff_dtype(const unsigned short* __restrict__ u,
                                                   float* __restrict__ flag){
  __shared__ int cnt;
  if (threadIdx.x == 0) cnt = 0;
  __syncthreads();
  unsigned short b = u[2 * threadIdx.x];
  unsigned int w = ((unsigned int)b) << 16;
  float v = __uint_as_float(w);
  float a = fabsf(v);
  if (a >= 6.1e-5f && a <= 16384.f) atomicAdd(&cnt, 1);
  __syncthreads();
  if (threadIdx.x == 0) *flag = (cnt >= 128) ? 1.0f : 0.0f;
}

// ---------------- unified prep: flat 1-D grid, blocks proportional to work ----------------
struct PrepBatch {
  const void* src[40];
  void*       dst[40];
  int         a[40];     // cast: n elements ; wprep: K
  int         b[40];     // cast: 0 ; wprep: N  (Wt[n][K+8] = bf16(W[k][n]))
  int         blk0[41];
  int         ne;
};

__global__ __launch_bounds__(256) void prep_all(PrepBatch pb, const float* __restrict__ flag){
  int blk = blockIdx.x;
  int t = 0;
  while (t + 1 < pb.ne && pb.blk0[t + 1] <= blk) t++;
  int local = blk - pb.blk0[t];
  bool isbf = (*flag != 0.0f);
  const void* s = pb.src[t];
  if (pb.b[t] == 0){
    int n = pb.a[t];
    float* d = (float*)pb.dst[t];
    int v = local * 256 + threadIdx.x;
    int base = v * 4;
    if (base + 3 < n){
      float4 f;
      if (isbf){
        ushort4 u = ((const ushort4*)s)[v];
        f.x = __uint_as_float(((unsigned)u.x) << 16);
        f.y = __uint_as_float(((unsigned)u.y) << 16);
        f.z = __uint_as_float(((unsigned)u.z) << 16);
        f.w = __uint_as_float(((unsigned)u.w) << 16);
      } else f = ((const float4*)s)[v];
      ((float4*)d)[v] = f;
    } else {
      for (int j = base; j < n && j < base + 4; j++) d[j] = loadf(s, j, isbf);
    }
  } else {
    int K = pb.a[t], Nn = pb.b[t], ldt = K + 8;
    short* d = (short*)pb.dst[t];
    int i = local * 256 + threadIdx.x;
    if (i < K * Nn){
      int n = i / K, k = i - n * K;        // k-fast: coalesced 2B writes
      d[(size_t)n * ldt + k] = f2bf(loadf(s, (size_t)k * Nn + n, isbf));
    }
  }
}

// ---------------- adjacency build ----------------
__global__ __launch_bounds__(256) void zero_init(float* __restrict__ A, float* __restrict__ deg,
                                                 int totalA, int n){
  int i = blockIdx.x * 256 + threadIdx.x;
  if (i < totalA) A[i] = 0.f;
  if (i < n) deg[i] = 1.0f;
}
__global__ __launch_bounds__(256) void deg_edges(const int* __restrict__ dst, float* deg, int e){
  int i = blockIdx.x * 256 + threadIdx.x;
  if (i < e) atomicAdd(&deg[dst[i]], 1.0f);
}
__global__ __launch_bounds__(256) void adj_fin(const int* __restrict__ src, const int* __restrict__ dst,
                                               const float* __restrict__ deg,
                                               float* __restrict__ A, int n, int e){
  int i = blockIdx.x * 256 + threadIdx.x;
  if (i < n){
    float dv = rsqrtf(deg[i]);
    int g = i / MAXN, r = i - g * MAXN;
    atomicAdd(&A[(size_t)g * (MAXN * MAXN) + r * MAXN + r], dv * dv);
  } else if (i < n + e){
    int j = i - n;
    int s = src[j], d = dst[j];
    float nv = rsqrtf(deg[s]) * rsqrtf(deg[d]);
    int g = d / MAXN;
    int dl = d - g * MAXN;
    int sl = s - (s / MAXN) * MAXN;
    atomicAdd(&A[(size_t)g * (MAXN * MAXN) + dl * MAXN + sl], nv);
  }
}

// ---------------- gcn_all: whole GCN stage per graph, all-MFMA ----------------
// One block per graph. Six MFMA passes (t1, hop1, xagg1, t2, hop2, xagg2);
// pools p1/p2 fused (fp32 accumulate + shfl reduce); xagg written bf16 to global.
// All K padded to 128; LDS fully zeroed first (NaN-safe: pads are exact zeros).
#define GLDK 136   // row stride in shorts: 272B (16B-aligned rows, 2-way-free banks)
__global__ __launch_bounds__(256) void gcn_all(
    const void* __restrict__ X, const float* __restrict__ xflag,
    const float* __restrict__ Adj,
    const short* __restrict__ W1t, const float* __restrict__ b1,
    const short* __restrict__ W2t, const float* __restrict__ b2,
    short* __restrict__ xaggB,
    float* __restrict__ p1, float* __restrict__ p2)
{
  __shared__ short As[112 * GLDK];   // adjacency bf16 [dst][src pad128]
  __shared__ short S1[112 * GLDK];   // Xs then x1A   [row][k]
  __shared__ short S2[128 * GLDK];   // t1B then t2B  [col][node pad128]
  __shared__ short S4[128 * GLDK];   // x1B then x2B  [col][node pad128]
  int g = blockIdx.x;
  int tid = threadIdx.x;
  int wave = tid >> 6, lane = tid & 63;
  int quad = lane >> 4, l16 = lane & 15;
  int gn0 = wave * 16 + l16, gn1 = gn0 + 64;
  bool isbf = (*xflag != 0.0f);

  // zero all LDS (pads must be exact zeros)
  for (int i = tid; i < 112 * GLDK / 2; i += 256){ ((int*)As)[i] = 0; ((int*)S1)[i] = 0; }
  for (int i = tid; i < 128 * GLDK / 2; i += 256){ ((int*)S2)[i] = 0; ((int*)S4)[i] = 0; }
  __syncthreads();

  // stage adjacency (fp32 -> bf16) and X rows (g*100 .. +99)
  const float* Ag = Adj + (size_t)g * (MAXN * MAXN);
  for (int i = tid; i < MAXN * MAXN; i += 256){
    int r = i / MAXN, s = i - r * MAXN;
    As[r * GLDK + s] = f2bf(Ag[i]);
  }
  for (int i = tid; i < MAXN * 16; i += 256){
    int r = i >> 4, k8 = (i & 15) << 3;
    s16x8 v;
    if (isbf){
      v = *reinterpret_cast<const s16x8*>((const short*)X + (size_t)(g * MAXN + r) * 128 + k8);
    } else {
      const float* ap = (const float*)X + (size_t)(g * MAXN + r) * 128 + k8;
      float4 f0 = *reinterpret_cast<const float4*>(ap);
      float4 f1 = *reinterpret_cast<const float4*>(ap + 4);
      v[0] = f2bf(f0.x); v[1] = f2bf(f0.y); v[2] = f2bf(f0.z); v[3] = f2bf(f0.w);
      v[4] = f2bf(f1.x); v[5] = f2bf(f1.y); v[6] = f2bf(f1.z); v[7] = f2bf(f1.w);
    }
    *reinterpret_cast<s16x8*>(&S1[r * GLDK + k8]) = v;
  }
  __syncthreads();

  f32x4 acc[7][2];
  auto zacc = [&](){
#pragma unroll
    for (int rt = 0; rt < 7; rt++){ acc[rt][0] = (f32x4){0.f,0.f,0.f,0.f}; acc[rt][1] = (f32x4){0.f,0.f,0.f,0.f}; }
  };
  auto passL = [&](const short* Abuf, const short* Bbuf){   // B in LDS [n][k]
#pragma unroll
    for (int kt = 0; kt < 4; kt++){
      int kb = kt * 32 + quad * 8;
      s16x8 bf0 = *reinterpret_cast<const s16x8*>(&Bbuf[gn0 * GLDK + kb]);
      s16x8 bf1 = *reinterpret_cast<const s16x8*>(&Bbuf[gn1 * GLDK + kb]);
#pragma unroll
      for (int rt = 0; rt < 7; rt++){
        s16x8 a = *reinterpret_cast<const s16x8*>(&Abuf[(rt * 16 + l16) * GLDK + kb]);
        acc[rt][0] = __builtin_amdgcn_mfma_f32_16x16x32_bf16(a, bf0, acc[rt][0], 0, 0, 0);
        acc[rt][1] = __builtin_amdgcn_mfma_f32_16x16x32_bf16(a, bf1, acc[rt][1], 0, 0, 0);
      }
    }
  };
  auto passG = [&](const short* Abuf, const short* __restrict__ Bt){  // B global, ld 136
#pragma unroll
    for (int kt = 0; kt < 4; kt++){
      int kb = kt * 32 + quad * 8;
      s16x8 bf0 = *reinterpret_cast<const s16x8*>(&Bt[(size_t)gn0 * 136 + kb]);
      s16x8 bf1 = *reinterpret_cast<const s16x8*>(&Bt[(size_t)gn1 * 136 + kb]);
#pragma unroll
      for (int rt = 0; rt < 7; rt++){
        s16x8 a = *reinterpret_cast<const s16x8*>(&Abuf[(rt * 16 + l16) * GLDK + kb]);
        acc[rt][0] = __builtin_amdgcn_mfma_f32_16x16x32_bf16(a, bf0, acc[rt][0], 0, 0, 0);
        acc[rt][1] = __builtin_amdgcn_mfma_f32_16x16x32_bf16(a, bf1, acc[rt][1], 0, 0, 0);
      }
    }
  };
  auto writeB = [&](short* Bbuf){                           // D -> [col][row] bf16
#pragma unroll
    for (int rt = 0; rt < 7; rt++){
      int row = rt * 16 + quad * 4;
#pragma unroll
      for (int g2 = 0; g2 < 2; g2++){
        int col = g2 ? gn1 : gn0;
        short4 o;
        o.x = f2bf(acc[rt][g2][0]); o.y = f2bf(acc[rt][g2][1]);
        o.z = f2bf(acc[rt][g2][2]); o.w = f2bf(acc[rt][g2][3]);
        *reinterpret_cast<short4*>(&Bbuf[col * GLDK + row]) = o;
      }
    }
  };

  float s10 = 0.f, s11 = 0.f, s20 = 0.f, s21 = 0.f;
  auto hopEpi = [&](const float* bias, short* AoutA, short* BoutB, float& sum0, float& sum1){
    float bv0 = bias[gn0], bv1 = bias[gn1];
#pragma unroll
    for (int rt = 0; rt < 7; rt++){
#pragma unroll
      for (int g2 = 0; g2 < 2; g2++){
        int col = g2 ? gn1 : gn0;
        float bv = g2 ? bv1 : bv0;
        float vals[4];
#pragma unroll
        for (int r = 0; r < 4; r++){
          int row = rt * 16 + quad * 4 + r;
          float v = fmaxf(acc[rt][g2][r] + bv, 0.f);
          vals[r] = v;
          if (row < MAXN){ if (g2) sum1 += v; else sum0 += v; }
        }
        short4 o;
        o.x = f2bf(vals[0]); o.y = f2bf(vals[1]); o.z = f2bf(vals[2]); o.w = f2bf(vals[3]);
        *reinterpret_cast<short4*>(&BoutB[col * GLDK + rt * 16 + quad * 4]) = o;
        if (AoutA){
          AoutA[(rt * 16 + quad * 4 + 0) * GLDK + col] = o.x;
          AoutA[(rt * 16 + quad * 4 + 1) * GLDK + col] = o.y;
          AoutA[(rt * 16 + quad * 4 + 2) * GLDK + col] = o.z;
          AoutA[(rt * 16 + quad * 4 + 3) * GLDK + col] = o.w;
        }
      }
    }
  };
  auto xaggEpi = [&](int colbase){
#pragma unroll
    for (int rt = 0; rt < 7; rt++){
#pragma unroll
      for (int g2 = 0; g2 < 2; g2++){
        int col = (g2 ? gn1 : gn0) + colbase;
#pragma unroll
        for (int r = 0; r < 4; r++){
          int row = rt * 16 + quad * 4 + r;
          if (row < MAXN) xaggB[(size_t)(g * MAXN + row) * 256 + col] = f2bf(acc[rt][g2][r]);
        }
      }
    }
  };

  // t1 = X @ W1
  zacc(); passG(S1, W1t); writeB(S2);
  __syncthreads();
  // x1 = relu(A @ t1 + b1): pool p1; x1A -> S1 (Xs dead), x1B -> S4
  zacc(); passL(As, S2); hopEpi(b1, S1, S4, s10, s11);
  __syncthreads();
  // xagg[:,0:128] = A @ x1
  zacc(); passL(As, S4); xaggEpi(0);
  // t2 = x1 @ W2
  zacc(); passG(S1, W2t); writeB(S2);
  __syncthreads();
  // x2 = relu(A @ t2 + b2): pool p2; x2B -> S4 (x1B dead)
  zacc(); passL(As, S2); hopEpi(b2, nullptr, S4, s20, s21);
  __syncthreads();
  // xagg[:,128:256] = A @ x2
  zacc(); passL(As, S4); xaggEpi(128);

  // pools: reduce across quads (lanes l16 share a column)
  s10 += __shfl_xor(s10, 16); s10 += __shfl_xor(s10, 32);
  s11 += __shfl_xor(s11, 16); s11 += __shfl_xor(s11, 32);
  s20 += __shfl_xor(s20, 16); s20 += __shfl_xor(s20, 32);
  s21 += __shfl_xor(s21, 16); s21 += __shfl_xor(s21, 32);
  if (quad == 0){
    p1[g * 128 + gn0] = s10; p1[g * 128 + gn1] = s11;
    p2[g * 128 + gn0] = s20; p2[g * 128 + gn1] = s21;
  }
}

// ---------------- MFMA bf16 GEMM, occupancy-first (unchanged from r9) ----------------
template<int K>
__global__ __launch_bounds__(256) void gemm_bf16_t(
    const void* __restrict__ A, int lda,
    const short* __restrict__ Bt, int ldbt,
    const float* __restrict__ bias,
    const float* __restrict__ resid, int ldr,
    float* __restrict__ C, int ldc,
    int M, int Nn, int mode,
    const float* __restrict__ aflag, int abf)
{
  constexpr int LDK = K + 8;
  constexpr int KU = K / 8;
  constexpr int KT = K / 32;
  __shared__ short As[64 * LDK];
  int bm = blockIdx.x * 64, bn = blockIdx.y * 128;
  int tid = threadIdx.x;
  int wave = tid >> 6, lane = tid & 63;
  int quad = lane >> 4, l16 = lane & 15;
  bool isbf = (abf == 1) || (abf == -1 && *aflag != 0.0f);

  int gn0 = bn + wave * 16 + l16;
  int gn1 = gn0 + 64;
  s16x8 B0[KT], B1[KT];
#pragma unroll
  for (int kt = 0; kt < KT; kt++){
    int kb = kt * 32 + quad * 8;
    s16x8 z;
#pragma unroll
    for (int j = 0; j < 8; j++) z[j] = 0;
    B0[kt] = (gn0 < Nn) ? *reinterpret_cast<const s16x8*>(&Bt[(size_t)gn0 * ldbt + kb]) : z;
    B1[kt] = (gn1 < Nn) ? *reinterpret_cast<const s16x8*>(&Bt[(size_t)gn1 * ldbt + kb]) : z;
  }

  for (int u = tid; u < 64 * KU; u += 256){
    int r = u / KU, k8 = (u - r * KU) << 3;
    int gr = bm + r;
    s16x8 v;
    if (gr < M){
      if (isbf){
        v = *reinterpret_cast<const s16x8*>((const short*)A + (size_t)gr * lda + k8);
      } else {
        const float* ap = (const float*)A + (size_t)gr * lda + k8;
        float4 f0 = *reinterpret_cast<const float4*>(ap);
        float4 f1 = *reinterpret_cast<const float4*>(ap + 4);
        v[0] = f2bf(f0.x); v[1] = f2bf(f0.y); v[2] = f2bf(f0.z); v[3] = f2bf(f0.w);
        v[4] = f2bf(f1.x); v[5] = f2bf(f1.y); v[6] = f2bf(f1.z); v[7] = f2bf(f1.w);
      }
    } else {
#pragma unroll
      for (int j = 0; j < 8; j++) v[j] = 0;
    }
    *reinterpret_cast<s16x8*>(&As[r * LDK + k8]) = v;
  }
  __syncthreads();

  f32x4 acc[4][2];
#pragma unroll
  for (int rt = 0; rt < 4; rt++)
#pragma unroll
    for (int g2 = 0; g2 < 2; g2++) acc[rt][g2] = (f32x4){0.f,0.f,0.f,0.f};

  const short* arow = &As[l16 * LDK];
#pragma unroll
  for (int kt = 0; kt < KT; kt++){
    int kb = kt * 32 + quad * 8;
#pragma unroll
    for (int rt = 0; rt < 4; rt++){
      s16x8 a = *reinterpret_cast<const s16x8*>(&arow[rt * 16 * LDK + kb]);
      acc[rt][0] = __builtin_amdgcn_mfma_f32_16x16x32_bf16(a, B0[kt], acc[rt][0], 0, 0, 0);
      acc[rt][1] = __builtin_amdgcn_mfma_f32_16x16x32_bf16(a, B1[kt], acc[rt][1], 0, 0, 0);
    }
  }

#pragma unroll
  for (int g2 = 0; g2 < 2; g2++){
    int gc = (g2 == 0) ? gn0 : gn1;
    if (gc >= Nn) continue;
    float bvv = bias ? bias[gc] : 0.f;
#pragma unroll
    for (int rt = 0; rt < 4; rt++){
#pragma unroll
      for (int r = 0; r < 4; r++){
        int gr = bm + rt * 16 + quad * 4 + r;
        if (gr >= M) continue;
        float vv = acc[rt][g2][r] + bvv;
        if (mode == 1) vv = fmaxf(vv, 0.f);
        else if (mode == 2) vv = resid[(size_t)gr * ldr + gc] + fmaxf(vv, 0.f);
        C[(size_t)gr * ldc + gc] = vv;
      }
    }
  }
}

// ---------------- ubar_q0 ----------------
__global__ __launch_bounds__(256) void ubar_q0(const float* __restrict__ S0,
    const float* __restrict__ Wq0, const float* __restrict__ bq0,
    const float* __restrict__ Wk0, const float* __restrict__ bk0,
    float* __restrict__ Q0, short* __restrict__ Ubart, float* __restrict__ cvec)
{
  __shared__ float q0s[64];
  int j = blockIdx.x, h = j / 25, q = j - h * 25;
  int tid = threadIdx.x;
  if (tid < 64){
    int c = h * 64 + tid;
    float acc = bq0[c];
    for (int e = 0; e < 256; e++) acc = fmaf(S0[q * 256 + e], Wq0[e * 256 + c], acc);
    q0s[tid] = acc;
    Q0[q * 256 + c] = acc;
  }
  __syncthreads();
  float acc = 0.f;
  const float* wp = &Wk0[(size_t)tid * 256 + h * 64];
#pragma unroll
  for (int d = 0; d < 64; d++) acc = fmaf(wp[d], q0s[d], acc);
  Ubart[(size_t)j * 264 + tid] = f2bf(acc * 0.0625f);
  if (tid == 0){
    float cb = 0.f;
    for (int d = 0; d < 64; d++) cb = fmaf(bk0[h * 64 + d], q0s[d], cb);
    cvec[j] = cb * 0.0625f;
  }
}

// ---------------- GMPool_G fused softmax(q) + AV + residual ----------------
__global__ __launch_bounds__(256) void av_pool0(const float* __restrict__ VdS,
    const float* __restrict__ Q0, float* __restrict__ O)
{
  __shared__ float Ssh[100 * 101];
  int g = blockIdx.x;
  int tid = threadIdx.x;
  for (int i = tid; i < 100 * 100; i += 256){
    int k = i / 100, jq = i - k * 100;
    Ssh[k * 101 + jq] = VdS[(size_t)(g * 100 + k) * 356 + 256 + jq];
  }
  __syncthreads();
  for (int p = tid; p < 400; p += 256){
    int k = p >> 2, h = p & 3;
    float* base = &Ssh[k * 101 + h * 25];
    float m = -1e30f;
#pragma unroll
    for (int q = 0; q < 25; q++) m = fmaxf(m, base[q]);
    float s = 0.f;
#pragma unroll
    for (int q = 0; q < 25; q++){ float e = __expf(base[q] - m); base[q] = e; s += e; }
    float inv = 1.0f / s;
#pragma unroll
    for (int q = 0; q < 25; q++) base[q] *= inv;
  }
  __syncthreads();
  int c = tid;
  int h = c >> 6;
  float acc[25] = {};
  const float* vp = VdS + (size_t)g * 100 * 356 + c;
  for (int k = 0; k < 100; k++){
    float v = vp[(size_t)k * 356];
    const float* a = &Ssh[k * 101 + h * 25];
#pragma unroll
    for (int q = 0; q < 25; q++) acc[q] = fmaf(a[q], v, acc[q]);
  }
#pragma unroll
  for (int q = 0; q < 25; q++)
    O[(size_t)(g * 25 + q) * 256 + c] = Q0[q * 256 + c] + acc[q];
}

// ---------------- SAB fully-fused attention ----------------
#define SST 132
__global__ __launch_bounds__(256) void sab_attn(const float* __restrict__ QKV,
    float* __restrict__ O)
{
  __shared__ float Qs[25 * SST];
  __shared__ float Ks[25 * SST];
  __shared__ float Vs[25 * SST];
  __shared__ float Ss[4 * 25 * 26];
  int g = blockIdx.x;
  int tid = threadIdx.x;
  for (int i = tid; i < 25 * 32; i += 256){
    int r = i >> 5, jj = i & 31;
    size_t src = (size_t)(g * 25 + r) * 384 + jj * 4;
    *reinterpret_cast<float4*>(&Qs[r * SST + jj * 4]) = *reinterpret_cast<const float4*>(&QKV[src]);
    *reinterpret_cast<float4*>(&Ks[r * SST + jj * 4]) = *reinterpret_cast<const float4*>(&QKV[src + 128]);
    *reinterpret_cast<float4*>(&Vs[r * SST + jj * 4]) = *reinterpret_cast<const float4*>(&QKV[src + 256]);
  }
  __syncthreads();
  for (int idx = tid; idx < 2500; idx += 256){
    int h = idx / 625;
    int r = idx - h * 625;
    int q = r / 25, k = r - q * 25;
    const float* qp = &Qs[q * SST + h * 32];
    const float* kp = &Ks[k * SST + h * 32];
    float acc = 0.f;
#pragma unroll
    for (int d = 0; d < 32; d += 4){
      float4 a4 = *reinterpret_cast<const float4*>(&qp[d]);
      float4 b4 = *reinterpret_cast<const float4*>(&kp[d]);
      acc = fmaf(a4.x, b4.x, acc); acc = fmaf(a4.y, b4.y, acc);
      acc = fmaf(a4.z, b4.z, acc); acc = fmaf(a4.w, b4.w, acc);
    }
    Ss[(h * 25 + q) * 26 + k] = acc * 0.0883883476f;
  }
  __syncthreads();
  if (tid < 100){
    int h = tid / 25, k = tid - h * 25;
    float m = -1e30f;
#pragma unroll
    for (int q = 0; q < 25; q++) m = fmaxf(m, Ss[(h * 25 + q) * 26 + k]);
    float s = 0.f;
#pragma unroll
    for (int q = 0; q < 25; q++){ float e = __expf(Ss[(h * 25 + q) * 26 + k] - m); Ss[(h * 25 + q) * 26 + k] = e; s += e; }
    float inv = 1.0f / s;
#pragma unroll
    for (int q = 0; q < 25; q++) Ss[(h * 25 + q) * 26 + k] *= inv;
  }
  __syncthreads();
  if (tid < 128){
    int c = tid, h = c >> 5;
    float acc[25] = {};
    for (int k = 0; k < 25; k++){
      float v = Vs[k * SST + c];
#pragma unroll
      for (int q = 0; q < 25; q++) acc[q] = fmaf(Ss[(h * 25 + q) * 26 + k], v, acc[q]);
    }
#pragma unroll
    for (int q = 0; q < 25; q++)
      O[(size_t)(g * 25 + q) * 128 + c] = Qs[q * SST + c] + acc[q];
  }
}

// ---------------- fully-fused head ----------------
__global__ __launch_bounds__(128) void head_fused(const float* __restrict__ O1,
    const float* __restrict__ S2,
    const float* __restrict__ Wq2, const float* __restrict__ bq2,
    const float* __restrict__ Wv2, const float* __restrict__ bv2,
    const float* __restrict__ Wo2, const float* __restrict__ bo2,
    const float* __restrict__ Wl,  const float* __restrict__ bl,
    const float* __restrict__ Wc1, const float* __restrict__ bc1,
    const float* __restrict__ Wc2, const float* __restrict__ bc2,
    const float* __restrict__ Wc3, const float* __restrict__ bc3,
    float* __restrict__ out)
{
  __shared__ float va[128], vb[128];
  int g = blockIdx.x, c = threadIdx.x;
  float s = 0.f;
  for (int k = 0; k < 25; k++) s += O1[(size_t)(g * 25 + k) * 128 + c];
  va[c] = s;
  __syncthreads();
  float o2 = bq2[c];
  for (int k = 0; k < 128; k++) o2 = fmaf(S2[k], Wq2[k * 128 + c], o2);
  o2 += 25.f * bv2[c];
  for (int k = 0; k < 128; k++) o2 = fmaf(va[k], Wv2[k * 128 + c], o2);
  __syncthreads(); vb[c] = o2; __syncthreads();
  float t = bo2[c];
  for (int k = 0; k < 128; k++) t = fmaf(vb[k], Wo2[k * 128 + c], t);
  float o2f = o2 + fmaxf(t, 0.f);
  va[c] = o2f; __syncthreads();
  float z = bl[c];
  for (int k = 0; k < 128; k++) z = fmaf(va[k], Wl[k * 128 + c], z);
  vb[c] = z; __syncthreads();
  float z1 = bc1[c];
  for (int k = 0; k < 128; k++) z1 = fmaf(vb[k], Wc1[k * 128 + c], z1);
  z1 = fmaxf(z1, 0.f);
  va[c] = z1; __syncthreads();
  if (c < 64){
    float z2 = bc2[c];
    for (int k = 0; k < 128; k++) z2 = fmaf(va[k], Wc2[k * 64 + c], z2);
    vb[c] = fmaxf(z2, 0.f);
  }
  __syncthreads();
  if (c < 10){
    float lg = bc3[c];
    for (int k = 0; k < 64; k++) lg = fmaf(vb[k], Wc3[k * 10 + c], lg);
    out[g * 10 + c] = lg;
  }
}

// ---------------- host ----------------
extern "C" void kernel_launch(void* const* d_in, const int* in_sizes, int n_in,
                              void* d_out, int out_size, void* d_ws, size_t ws_size,
                              hipStream_t stream)
{
  const int*  edge = (const int*)d_in[1];
  const int N = in_sizes[0] / FIN;      // 20000
  const int E = in_sizes[1] / 2;        // 320000
  const int G = N / MAXN;               // 200
  const int* srcp = edge;
  const int* dstp = edge + E;
  float* out = (float*)d_out;           // f32: [logits 200x10 | p1 200x128 | p2 200x128]

  float* w = (float*)d_ws;
  size_t off = 0;
  auto alloc = [&](size_t nfl){ nfl = (nfl + 3) & ~(size_t)3; float* p = w + off; off += nfl; return p; };
  auto allocS = [&](size_t nsh)->short*{ size_t nfl = ((nsh + 1) / 2 + 3) & ~(size_t)3; short* p = (short*)(w + off); off += nfl; return p; };

  float* dflag = alloc(1);
  float* degb  = alloc(N);

  float* biasVS  = alloc(356);          // [bv0 | cvec]
  float* biasQKV = alloc(384);          // [bq1 | bk1 | bv1]
  float* cvec = biasVS + 256;

  const int castT[24] = {4,6,7,8,9,10,11,15,23,24,25,26,29,30,31,32,33,34,35,36,37,38,39,40};
  float* wf[41] = {nullptr};
  for (int i = 0; i < 24; i++) wf[castT[i]] = alloc((size_t)in_sizes[castT[i]]);
  wf[13] = biasVS; wf[17] = biasQKV; wf[19] = biasQKV + 128; wf[21] = biasQKV + 256;

  float* P1 = alloc((size_t)N * 256);   // [Oa | O0]
  float* P2 = alloc((size_t)N * 256);   // QKV
  float* P3 = alloc((size_t)N * 356);   // VdS; later Ob/O1
  float* Adj = alloc((size_t)G * MAXN * MAXN);
  float* Q0  = alloc(25 * 256);
  short* xaggB = allocS((size_t)N * 256);  // bf16 xagg

  short* W1t   = allocS(128 * 136);
  short* W2t   = allocS(128 * 136);
  short* WVSt  = allocS(356 * 264);     // [Wv0t | Ubart]
  short* WQKVt = allocS(384 * 264);     // [Wq1t | Wk1t | Wv1t]
  short* Wo0t  = allocS(256 * 264);
  short* Wo1t  = allocS(128 * 136);
  short* Ubart = WVSt + (size_t)256 * 264;
  if (off * sizeof(float) > ws_size) return;

  float* Oa  = P1;
  float* O0  = P1 + (size_t)G * KS1 * 256;
  float* QKV = P2;
  float* Ob  = P3;
  float* O1  = P3 + (size_t)G * KS1 * 128;

  dim3 blk(256);
  auto gemmb = [&](const void* A, int lda, const short* Bt, int ldbt, const float* bias,
                   const float* resid, int ldr, float* C, int ldc, int M, int Nc, int K, int mode,
                   const float* aflag, int abf){
    dim3 grid(ceil_div(M, 64), ceil_div(Nc, 128));
    if (K == 128)
      gemm_bf16_t<128><<<grid, blk, 0, stream>>>(A, lda, Bt, ldbt, bias, resid, ldr, C, ldc, M, Nc, mode, aflag, abf);
    else
      gemm_bf16_t<256><<<grid, blk, 0, stream>>>(A, lda, Bt, ldbt, bias, resid, ldr, C, ldc, M, Nc, mode, aflag, abf);
  };

  // 1. dtype sniff
  sniff_dtype<<<1, blk, 0, stream>>>((const unsigned short*)d_in[0], dflag);

  // 2. unified prep
  PrepBatch pb; int ne = 0, blks = 0;
  auto addC = [&](const void* s, float* d, int n){
    pb.src[ne]=s; pb.dst[ne]=d; pb.a[ne]=n; pb.b[ne]=0; pb.blk0[ne]=blks;
    blks += ceil_div(ceil_div(n, 4), 256); ne++; };
  auto addW = [&](const void* s, short* d, int K, int Nn){
    pb.src[ne]=s; pb.dst[ne]=d; pb.a[ne]=K; pb.b[ne]=Nn; pb.blk0[ne]=blks;
    blks += ceil_div(K * Nn, 256); ne++; };
  for (int i = 0; i < 24; i++){ int t = castT[i]; addC(d_in[t], wf[t], in_sizes[t]); }
  addC(d_in[13], biasVS, 256);
  addC(d_in[17], biasQKV, 128); addC(d_in[19], biasQKV + 128, 128); addC(d_in[21], biasQKV + 256, 128);
  addW(d_in[3],  W1t, 128, 128);             addW(d_in[5],  W2t, 128, 128);
  addW(d_in[12], WVSt, 256, 256);            addW(d_in[16], WQKVt, 256, 128);
  addW(d_in[18], WQKVt + 128*264, 256, 128); addW(d_in[20], WQKVt + 256*264, 256, 128);
  addW(d_in[14], Wo0t, 256, 256);            addW(d_in[22], Wo1t, 128, 128);
  pb.blk0[ne] = blks; pb.ne = ne;
  prep_all<<<dim3(blks), blk, 0, stream>>>(pb, dflag);

  // 3-5. adjacency
  int totalA = G * MAXN * MAXN;
  zero_init<<<ceil_div(totalA, 256), blk, 0, stream>>>(Adj, degb, totalA, N);
  deg_edges<<<ceil_div(E, 256), blk, 0, stream>>>(dstp, degb, E);
  adj_fin<<<ceil_div(N + E, 256), blk, 0, stream>>>(srcp, dstp, degb, Adj, N, E);

  // 6. whole GCN stage (t1, x1+pool1, xagg1, t2, x2+pool2, xagg2) per graph
  gcn_all<<<dim3(G), blk, 0, stream>>>(d_in[0], dflag, Adj, W1t, wf[4], W2t, wf[6],
                                       xaggB, out + 2000, out + 27600);

  // 7. Q0 + Ubar^T + cvec
  ubar_q0<<<dim3(100), blk, 0, stream>>>(wf[7], wf[8], wf[9], wf[10], wf[11], Q0, Ubart, cvec);

  // 8. [Vd | S2d] = xagg @ [Wv0 | Ubar]^T + [bv0 | cvec]
  gemmb(xaggB, 256, WVSt, 264, biasVS, nullptr, 0, P3, 356, N, 356, 256, 0, nullptr, 1);

  // 9-10. fused q-softmax+AV+residual, then Wo0 (mode2)
  av_pool0<<<dim3(G), blk, 0, stream>>>(P3, Q0, Oa);
  gemmb(Oa, 256, Wo0t, 264, wf[15], Oa, 256, O0, 256, G * KS1, 256, 256, 2, nullptr, 0);

  // 11-13. SAB
  gemmb(O0, 256, WQKVt, 264, biasQKV, nullptr, 0, QKV, 384, G * KS1, 384, 256, 0, nullptr, 0);
  sab_attn<<<dim3(G), blk, 0, stream>>>(QKV, Ob);
  gemmb(Ob, 128, Wo1t, 136, wf[23], Ob, 128, O1, 128, G * KS1, 128, 128, 2, nullptr, 0);

  // 14. fused head -> logits
  head_fused<<<dim3(G), dim3(128), 0, stream>>>(O1, wf[24], wf[25], wf[26], wf[29], wf[30],
      wf[31], wf[32], wf[33], wf[34], wf[35], wf[36], wf[37], wf[38], wf[39], wf[40], out);
}

// Round 11
// 304.728 us; speedup vs baseline: 6.3951x; 1.1160x over previous
//
#include <hip/hip_runtime.h>
#include <hip/hip_bf16.h>
#include <cstdint>
#include <cstddef>

typedef __hip_bfloat16 bf16;
typedef __attribute__((ext_vector_type(8))) short s16x8;
typedef __attribute__((ext_vector_type(4))) float f32x4;

#define MAXN 100
#define HH   4
#define FIN  128
#define KS1  25

static inline int ceil_div(int a, int b){ return (a + b - 1) / b; }

__device__ inline short f2bf(float f){               // RNE float->bf16 bits
  unsigned int u = __float_as_uint(f);
  u = (u + 0x7FFF + ((u >> 16) & 1)) >> 16;
  return (short)u;
}
__device__ inline float loadf(const void* s, int i, bool isbf){
  return isbf ? __bfloat162float(((const bf16*)s)[i]) : ((const float*)s)[i];
}

// ---------------- input dtype sniff ----------------
__global__ __launch_bounds__(256) void sniff_dtype(const unsigned short* __restrict__ u,
                                                   float* __restrict__ flag){
  __shared__ int cnt;
  if (threadIdx.x == 0) cnt = 0;
  __syncthreads();
  unsigned short b = u[2 * threadIdx.x];
  unsigned int w = ((unsigned int)b) << 16;
  float v = __uint_as_float(w);
  float a = fabsf(v);
  if (a >= 6.1e-5f && a <= 16384.f) atomicAdd(&cnt, 1);
  __syncthreads();
  if (threadIdx.x == 0) *flag = (cnt >= 128) ? 1.0f : 0.0f;
}

// ---------------- unified prep: casts + transposes + fills, flat 1-D grid ----------------
// b[t]==0: cast n=a floats; b[t]>0: Wt[n][K+8]=bf16(W[k][n]); b[t]==-1: fill 0; b[t]==-2: fill 1.0f
struct PrepBatch {
  const void* src[40];
  void*       dst[40];
  int         a[40];
  int         b[40];
  int         blk0[41];
  int         ne;
};

__global__ __launch_bounds__(256) void prep_all(PrepBatch pb, const float* __restrict__ flag){
  int blk = blockIdx.x;
  int t = 0;
  while (t + 1 < pb.ne && pb.blk0[t + 1] <= blk) t++;
  int local = blk - pb.blk0[t];
  bool isbf = (*flag != 0.0f);
  const void* s = pb.src[t];
  int bt = pb.b[t];
  if (bt < 0){
    float val = (bt == -2) ? 1.0f : 0.0f;
    int n = pb.a[t];
    float* d = (float*)pb.dst[t];
    int v = local * 256 + threadIdx.x;
    int base = v * 4;
    if (base + 3 < n) ((float4*)d)[v] = make_float4(val, val, val, val);
    else for (int j = base; j < n && j < base + 4; j++) d[j] = val;
  } else if (bt == 0){
    int n = pb.a[t];
    float* d = (float*)pb.dst[t];
    int v = local * 256 + threadIdx.x;
    int base = v * 4;
    if (base + 3 < n){
      float4 f;
      if (isbf){
        ushort4 u = ((const ushort4*)s)[v];
        f.x = __uint_as_float(((unsigned)u.x) << 16);
        f.y = __uint_as_float(((unsigned)u.y) << 16);
        f.z = __uint_as_float(((unsigned)u.z) << 16);
        f.w = __uint_as_float(((unsigned)u.w) << 16);
      } else f = ((const float4*)s)[v];
      ((float4*)d)[v] = f;
    } else {
      for (int j = base; j < n && j < base + 4; j++) d[j] = loadf(s, j, isbf);
    }
  } else {
    int K = pb.a[t], Nn = bt, ldt = K + 8;
    short* d = (short*)pb.dst[t];
    int i = local * 256 + threadIdx.x;
    if (i < K * Nn){
      int n = i / K, k = i - n * K;        // k-fast: coalesced 2B writes
      d[(size_t)n * ldt + k] = f2bf(loadf(s, (size_t)k * Nn + n, isbf));
    }
  }
}

// ---------------- adjacency build ----------------
__global__ __launch_bounds__(256) void deg_edges(const int* __restrict__ dst, float* deg, int e){
  int i = blockIdx.x * 256 + threadIdx.x;
  if (i < e) atomicAdd(&deg[dst[i]], 1.0f);
}
__global__ __launch_bounds__(256) void adj_fin(const int* __restrict__ src, const int* __restrict__ dst,
                                               const float* __restrict__ deg,
                                               float* __restrict__ A, int n, int e){
  int i = blockIdx.x * 256 + threadIdx.x;
  if (i < n){
    float dv = rsqrtf(deg[i]);
    int g = i / MAXN, r = i - g * MAXN;
    atomicAdd(&A[(size_t)g * (MAXN * MAXN) + r * MAXN + r], dv * dv);
  } else if (i < n + e){
    int j = i - n;
    int s = src[j], d = dst[j];
    float nv = rsqrtf(deg[s]) * rsqrtf(deg[d]);
    int g = d / MAXN;
    int dl = d - g * MAXN;
    int sl = s - (s / MAXN) * MAXN;
    atomicAdd(&A[(size_t)g * (MAXN * MAXN) + dl * MAXN + sl], nv);
  }
}

// ---------------- gcn_all: whole GCN stage per graph, all-MFMA (unchanged r10) ----------------
#define GLDK 136
__global__ __launch_bounds__(256) void gcn_all(
    const void* __restrict__ X, const float* __restrict__ xflag,
    const float* __restrict__ Adj,
    const short* __restrict__ W1t, const float* __restrict__ b1,
    const short* __restrict__ W2t, const float* __restrict__ b2,
    short* __restrict__ xaggB,
    float* __restrict__ p1, float* __restrict__ p2)
{
  __shared__ short As[112 * GLDK];
  __shared__ short S1[112 * GLDK];
  __shared__ short S2[128 * GLDK];
  __shared__ short S4[128 * GLDK];
  int g = blockIdx.x;
  int tid = threadIdx.x;
  int wave = tid >> 6, lane = tid & 63;
  int quad = lane >> 4, l16 = lane & 15;
  int gn0 = wave * 16 + l16, gn1 = gn0 + 64;
  bool isbf = (*xflag != 0.0f);

  for (int i = tid; i < 112 * GLDK / 2; i += 256){ ((int*)As)[i] = 0; ((int*)S1)[i] = 0; }
  for (int i = tid; i < 128 * GLDK / 2; i += 256){ ((int*)S2)[i] = 0; ((int*)S4)[i] = 0; }
  __syncthreads();

  const float* Ag = Adj + (size_t)g * (MAXN * MAXN);
  for (int i = tid; i < MAXN * MAXN; i += 256){
    int r = i / MAXN, s = i - r * MAXN;
    As[r * GLDK + s] = f2bf(Ag[i]);
  }
  for (int i = tid; i < MAXN * 16; i += 256){
    int r = i >> 4, k8 = (i & 15) << 3;
    s16x8 v;
    if (isbf){
      v = *reinterpret_cast<const s16x8*>((const short*)X + (size_t)(g * MAXN + r) * 128 + k8);
    } else {
      const float* ap = (const float*)X + (size_t)(g * MAXN + r) * 128 + k8;
      float4 f0 = *reinterpret_cast<const float4*>(ap);
      float4 f1 = *reinterpret_cast<const float4*>(ap + 4);
      v[0] = f2bf(f0.x); v[1] = f2bf(f0.y); v[2] = f2bf(f0.z); v[3] = f2bf(f0.w);
      v[4] = f2bf(f1.x); v[5] = f2bf(f1.y); v[6] = f2bf(f1.z); v[7] = f2bf(f1.w);
    }
    *reinterpret_cast<s16x8*>(&S1[r * GLDK + k8]) = v;
  }
  __syncthreads();

  f32x4 acc[7][2];
  auto zacc = [&](){
#pragma unroll
    for (int rt = 0; rt < 7; rt++){ acc[rt][0] = (f32x4){0.f,0.f,0.f,0.f}; acc[rt][1] = (f32x4){0.f,0.f,0.f,0.f}; }
  };
  auto passL = [&](const short* Abuf, const short* Bbuf){
#pragma unroll
    for (int kt = 0; kt < 4; kt++){
      int kb = kt * 32 + quad * 8;
      s16x8 bf0 = *reinterpret_cast<const s16x8*>(&Bbuf[gn0 * GLDK + kb]);
      s16x8 bf1 = *reinterpret_cast<const s16x8*>(&Bbuf[gn1 * GLDK + kb]);
#pragma unroll
      for (int rt = 0; rt < 7; rt++){
        s16x8 a = *reinterpret_cast<const s16x8*>(&Abuf[(rt * 16 + l16) * GLDK + kb]);
        acc[rt][0] = __builtin_amdgcn_mfma_f32_16x16x32_bf16(a, bf0, acc[rt][0], 0, 0, 0);
        acc[rt][1] = __builtin_amdgcn_mfma_f32_16x16x32_bf16(a, bf1, acc[rt][1], 0, 0, 0);
      }
    }
  };
  auto passG = [&](const short* Abuf, const short* __restrict__ Bt){
#pragma unroll
    for (int kt = 0; kt < 4; kt++){
      int kb = kt * 32 + quad * 8;
      s16x8 bf0 = *reinterpret_cast<const s16x8*>(&Bt[(size_t)gn0 * 136 + kb]);
      s16x8 bf1 = *reinterpret_cast<const s16x8*>(&Bt[(size_t)gn1 * 136 + kb]);
#pragma unroll
      for (int rt = 0; rt < 7; rt++){
        s16x8 a = *reinterpret_cast<const s16x8*>(&Abuf[(rt * 16 + l16) * GLDK + kb]);
        acc[rt][0] = __builtin_amdgcn_mfma_f32_16x16x32_bf16(a, bf0, acc[rt][0], 0, 0, 0);
        acc[rt][1] = __builtin_amdgcn_mfma_f32_16x16x32_bf16(a, bf1, acc[rt][1], 0, 0, 0);
      }
    }
  };
  auto writeB = [&](short* Bbuf){
#pragma unroll
    for (int rt = 0; rt < 7; rt++){
      int row = rt * 16 + quad * 4;
#pragma unroll
      for (int g2 = 0; g2 < 2; g2++){
        int col = g2 ? gn1 : gn0;
        short4 o;
        o.x = f2bf(acc[rt][g2][0]); o.y = f2bf(acc[rt][g2][1]);
        o.z = f2bf(acc[rt][g2][2]); o.w = f2bf(acc[rt][g2][3]);
        *reinterpret_cast<short4*>(&Bbuf[col * GLDK + row]) = o;
      }
    }
  };

  float s10 = 0.f, s11 = 0.f, s20 = 0.f, s21 = 0.f;
  auto hopEpi = [&](const float* bias, short* AoutA, short* BoutB, float& sum0, float& sum1){
    float bv0 = bias[gn0], bv1 = bias[gn1];
#pragma unroll
    for (int rt = 0; rt < 7; rt++){
#pragma unroll
      for (int g2 = 0; g2 < 2; g2++){
        int col = g2 ? gn1 : gn0;
        float bv = g2 ? bv1 : bv0;
        float vals[4];
#pragma unroll
        for (int r = 0; r < 4; r++){
          int row = rt * 16 + quad * 4 + r;
          float v = fmaxf(acc[rt][g2][r] + bv, 0.f);
          vals[r] = v;
          if (row < MAXN){ if (g2) sum1 += v; else sum0 += v; }
        }
        short4 o;
        o.x = f2bf(vals[0]); o.y = f2bf(vals[1]); o.z = f2bf(vals[2]); o.w = f2bf(vals[3]);
        *reinterpret_cast<short4*>(&BoutB[col * GLDK + rt * 16 + quad * 4]) = o;
        if (AoutA){
          AoutA[(rt * 16 + quad * 4 + 0) * GLDK + col] = o.x;
          AoutA[(rt * 16 + quad * 4 + 1) * GLDK + col] = o.y;
          AoutA[(rt * 16 + quad * 4 + 2) * GLDK + col] = o.z;
          AoutA[(rt * 16 + quad * 4 + 3) * GLDK + col] = o.w;
        }
      }
    }
  };
  auto xaggEpi = [&](int colbase){
#pragma unroll
    for (int rt = 0; rt < 7; rt++){
#pragma unroll
      for (int g2 = 0; g2 < 2; g2++){
        int col = (g2 ? gn1 : gn0) + colbase;
#pragma unroll
        for (int r = 0; r < 4; r++){
          int row = rt * 16 + quad * 4 + r;
          if (row < MAXN) xaggB[(size_t)(g * MAXN + row) * 256 + col] = f2bf(acc[rt][g2][r]);
        }
      }
    }
  };

  zacc(); passG(S1, W1t); writeB(S2);
  __syncthreads();
  zacc(); passL(As, S2); hopEpi(b1, S1, S4, s10, s11);
  __syncthreads();
  zacc(); passL(As, S4); xaggEpi(0);
  zacc(); passG(S1, W2t); writeB(S2);
  __syncthreads();
  zacc(); passL(As, S2); hopEpi(b2, nullptr, S4, s20, s21);
  __syncthreads();
  zacc(); passL(As, S4); xaggEpi(128);

  s10 += __shfl_xor(s10, 16); s10 += __shfl_xor(s10, 32);
  s11 += __shfl_xor(s11, 16); s11 += __shfl_xor(s11, 32);
  s20 += __shfl_xor(s20, 16); s20 += __shfl_xor(s20, 32);
  s21 += __shfl_xor(s21, 16); s21 += __shfl_xor(s21, 32);
  if (quad == 0){
    p1[g * 128 + gn0] = s10; p1[g * 128 + gn1] = s11;
    p2[g * 128 + gn0] = s20; p2[g * 128 + gn1] = s21;
  }
}

// ---------------- MFMA bf16 GEMM (VdS only now; K=256, A bf16) ----------------
template<int K>
__global__ __launch_bounds__(256) void gemm_bf16_t(
    const short* __restrict__ A, int lda,
    const short* __restrict__ Bt, int ldbt,
    const float* __restrict__ bias,
    float* __restrict__ C, int ldc,
    int M, int Nn)
{
  constexpr int LDK = K + 8;
  constexpr int KU = K / 8;
  constexpr int KT = K / 32;
  __shared__ short As[64 * LDK];
  int bm = blockIdx.x * 64, bn = blockIdx.y * 128;
  int tid = threadIdx.x;
  int wave = tid >> 6, lane = tid & 63;
  int quad = lane >> 4, l16 = lane & 15;

  int gn0 = bn + wave * 16 + l16;
  int gn1 = gn0 + 64;
  s16x8 B0[KT], B1[KT];
#pragma unroll
  for (int kt = 0; kt < KT; kt++){
    int kb = kt * 32 + quad * 8;
    s16x8 z;
#pragma unroll
    for (int j = 0; j < 8; j++) z[j] = 0;
    B0[kt] = (gn0 < Nn) ? *reinterpret_cast<const s16x8*>(&Bt[(size_t)gn0 * ldbt + kb]) : z;
    B1[kt] = (gn1 < Nn) ? *reinterpret_cast<const s16x8*>(&Bt[(size_t)gn1 * ldbt + kb]) : z;
  }

  for (int u = tid; u < 64 * KU; u += 256){
    int r = u / KU, k8 = (u - r * KU) << 3;
    int gr = bm + r;
    s16x8 v;
    if (gr < M) v = *reinterpret_cast<const s16x8*>(A + (size_t)gr * lda + k8);
    else {
#pragma unroll
      for (int j = 0; j < 8; j++) v[j] = 0;
    }
    *reinterpret_cast<s16x8*>(&As[r * LDK + k8]) = v;
  }
  __syncthreads();

  f32x4 acc[4][2];
#pragma unroll
  for (int rt = 0; rt < 4; rt++)
#pragma unroll
    for (int g2 = 0; g2 < 2; g2++) acc[rt][g2] = (f32x4){0.f,0.f,0.f,0.f};

  const short* arow = &As[l16 * LDK];
#pragma unroll
  for (int kt = 0; kt < KT; kt++){
    int kb = kt * 32 + quad * 8;
#pragma unroll
    for (int rt = 0; rt < 4; rt++){
      s16x8 a = *reinterpret_cast<const s16x8*>(&arow[rt * 16 * LDK + kb]);
      acc[rt][0] = __builtin_amdgcn_mfma_f32_16x16x32_bf16(a, B0[kt], acc[rt][0], 0, 0, 0);
      acc[rt][1] = __builtin_amdgcn_mfma_f32_16x16x32_bf16(a, B1[kt], acc[rt][1], 0, 0, 0);
    }
  }

#pragma unroll
  for (int g2 = 0; g2 < 2; g2++){
    int gc = (g2 == 0) ? gn0 : gn1;
    if (gc >= Nn) continue;
    float bvv = bias ? bias[gc] : 0.f;
#pragma unroll
    for (int rt = 0; rt < 4; rt++){
#pragma unroll
      for (int r = 0; r < 4; r++){
        int gr = bm + rt * 16 + quad * 4 + r;
        if (gr >= M) continue;
        C[(size_t)gr * ldc + gc] = acc[rt][g2][r] + bvv;
      }
    }
  }
}

// ---------------- ubar_q0 ----------------
__global__ __launch_bounds__(256) void ubar_q0(const float* __restrict__ S0,
    const float* __restrict__ Wq0, const float* __restrict__ bq0,
    const float* __restrict__ Wk0, const float* __restrict__ bk0,
    float* __restrict__ Q0, short* __restrict__ Ubart, float* __restrict__ cvec)
{
  __shared__ float q0s[64];
  int j = blockIdx.x, h = j / 25, q = j - h * 25;
  int tid = threadIdx.x;
  if (tid < 64){
    int c = h * 64 + tid;
    float acc = bq0[c];
    for (int e = 0; e < 256; e++) acc = fmaf(S0[q * 256 + e], Wq0[e * 256 + c], acc);
    q0s[tid] = acc;
    Q0[q * 256 + c] = acc;
  }
  __syncthreads();
  float acc = 0.f;
  const float* wp = &Wk0[(size_t)tid * 256 + h * 64];
#pragma unroll
  for (int d = 0; d < 64; d++) acc = fmaf(wp[d], q0s[d], acc);
  Ubart[(size_t)j * 264 + tid] = f2bf(acc * 0.0625f);
  if (tid == 0){
    float cb = 0.f;
    for (int d = 0; d < 64; d++) cb = fmaf(bk0[h * 64 + d], q0s[d], cb);
    cvec[j] = cb * 0.0625f;
  }
}

// ---------------- tail_all: av_pool0 + Wo0 + QKV + SAB + Wo1 + head, one block/graph ----------------
struct TailParams {
  const float* VdS;   const float* Q0;
  const short* Wo0t;  const float* bo0;
  const short* WQKVt; const float* biasQKV;
  const short* Wo1t;  const float* bo1;
  const float *S2, *Wq2, *bq2, *Wv2, *bv2, *Wo2, *bo2, *Wl, *bl, *Wc1, *bc1, *Wc2, *bc2, *Wc3, *bc3;
  float* out;
};

__global__ __launch_bounds__(256) void tail_all(TailParams P)
{
  __shared__ float Ssh[100 * 101];   // scores; later QKV [25 x 388]
  __shared__ float OaF[25 * 260];    // Oa fp32; later Ob fp32
  __shared__ float O0F[25 * 260];    // O0 fp32; later O1 fp32
  __shared__ short Abf[32 * 264];    // bf16 A-staging K=256 (pad rows zero)
  __shared__ short Abf2[32 * 136];   // bf16 A-staging K=128
  __shared__ float Ss2[4 * 25 * 26];
  __shared__ float hva[128], hvb[128];
  int g = blockIdx.x, tid = threadIdx.x;
  int wave = tid >> 6, lane = tid & 63, quad = lane >> 4, l16 = lane & 15;

  for (int i = tid; i < 32 * 264 / 2; i += 256) ((int*)Abf)[i] = 0;
  for (int i = tid; i < 32 * 136 / 2; i += 256) ((int*)Abf2)[i] = 0;

  // 1. stage GMPool_G scores
  const float* vds = P.VdS + (size_t)g * 100 * 356;
  for (int i = tid; i < 100 * 100; i += 256){
    int k = i / 100, j = i - k * 100;
    Ssh[k * 101 + j] = vds[(size_t)k * 356 + 256 + j];
  }
  __syncthreads();
  // 2. softmax over q per (k,h)
  for (int p = tid; p < 400; p += 256){
    int k = p >> 2, h = p & 3;
    float* base = &Ssh[k * 101 + h * 25];
    float m = -1e30f;
#pragma unroll
    for (int q = 0; q < 25; q++) m = fmaxf(m, base[q]);
    float s = 0.f;
#pragma unroll
    for (int q = 0; q < 25; q++){ float e = __expf(base[q] - m); base[q] = e; s += e; }
    float inv = 1.0f / s;
#pragma unroll
    for (int q = 0; q < 25; q++) base[q] *= inv;
  }
  __syncthreads();
  // 3. AV + residual -> Oa (fp32 + bf16 A-staging)
  {
    int c = tid, h = c >> 6;
    float acc[25] = {};
    const float* vp = vds + c;
    for (int k = 0; k < 100; k++){
      float v = vp[(size_t)k * 356];
      const float* a = &Ssh[k * 101 + h * 25];
#pragma unroll
      for (int q = 0; q < 25; q++) acc[q] = fmaf(a[q], v, acc[q]);
    }
#pragma unroll
    for (int q = 0; q < 25; q++){
      float oa = P.Q0[q * 256 + c] + acc[q];
      OaF[q * 260 + c] = oa;
      Abf[q * 264 + c] = f2bf(oa);
    }
  }
  __syncthreads();
  // 4. O0 = Oa + relu(Oa @ Wo0 + bo0)  [K=256, 2 col passes]
  {
    f32x4 accP[2][2][2];
#pragma unroll
    for (int pass = 0; pass < 2; pass++){
      int c0 = pass * 128 + wave * 16 + l16, c1 = c0 + 64;
      s16x8 B0[8], B1[8];
#pragma unroll
      for (int kt = 0; kt < 8; kt++){
        int kb = kt * 32 + quad * 8;
        B0[kt] = *reinterpret_cast<const s16x8*>(&P.Wo0t[(size_t)c0 * 264 + kb]);
        B1[kt] = *reinterpret_cast<const s16x8*>(&P.Wo0t[(size_t)c1 * 264 + kb]);
      }
#pragma unroll
      for (int rt = 0; rt < 2; rt++){ accP[pass][rt][0] = (f32x4){0.f,0.f,0.f,0.f}; accP[pass][rt][1] = (f32x4){0.f,0.f,0.f,0.f}; }
#pragma unroll
      for (int kt = 0; kt < 8; kt++){
        int kb = kt * 32 + quad * 8;
#pragma unroll
        for (int rt = 0; rt < 2; rt++){
          s16x8 a = *reinterpret_cast<const s16x8*>(&Abf[(rt * 16 + l16) * 264 + kb]);
          accP[pass][rt][0] = __builtin_amdgcn_mfma_f32_16x16x32_bf16(a, B0[kt], accP[pass][rt][0], 0, 0, 0);
          accP[pass][rt][1] = __builtin_amdgcn_mfma_f32_16x16x32_bf16(a, B1[kt], accP[pass][rt][1], 0, 0, 0);
        }
      }
    }
    __syncthreads();                 // all Abf(Oa) reads complete
#pragma unroll
    for (int pass = 0; pass < 2; pass++){
#pragma unroll
      for (int cg = 0; cg < 2; cg++){
        int col = pass * 128 + wave * 16 + l16 + cg * 64;
        float bv = P.bo0[col];
#pragma unroll
        for (int rt = 0; rt < 2; rt++){
#pragma unroll
          for (int r = 0; r < 4; r++){
            int row = rt * 16 + quad * 4 + r;
            if (row < 25){
              float t = accP[pass][rt][cg][r] + bv;
              float v = OaF[row * 260 + col] + fmaxf(t, 0.f);
              O0F[row * 260 + col] = v;
              Abf[row * 264 + col] = f2bf(v);
            }
          }
        }
      }
    }
  }
  __syncthreads();
  // 5. QKV = O0 @ WQKVt + biasQKV  [K=256, 3 col passes] -> Ssh[q*388+col] (scores dead)
  {
    f32x4 accP[3][2][2];
#pragma unroll
    for (int pass = 0; pass < 3; pass++){
      int c0 = pass * 128 + wave * 16 + l16, c1 = c0 + 64;
      s16x8 B0[8], B1[8];
#pragma unroll
      for (int kt = 0; kt < 8; kt++){
        int kb = kt * 32 + quad * 8;
        B0[kt] = *reinterpret_cast<const s16x8*>(&P.WQKVt[(size_t)c0 * 264 + kb]);
        B1[kt] = *reinterpret_cast<const s16x8*>(&P.WQKVt[(size_t)c1 * 264 + kb]);
      }
#pragma unroll
      for (int rt = 0; rt < 2; rt++){ accP[pass][rt][0] = (f32x4){0.f,0.f,0.f,0.f}; accP[pass][rt][1] = (f32x4){0.f,0.f,0.f,0.f}; }
#pragma unroll
      for (int kt = 0; kt < 8; kt++){
        int kb = kt * 32 + quad * 8;
#pragma unroll
        for (int rt = 0; rt < 2; rt++){
          s16x8 a = *reinterpret_cast<const s16x8*>(&Abf[(rt * 16 + l16) * 264 + kb]);
          accP[pass][rt][0] = __builtin_amdgcn_mfma_f32_16x16x32_bf16(a, B0[kt], accP[pass][rt][0], 0, 0, 0);
          accP[pass][rt][1] = __builtin_amdgcn_mfma_f32_16x16x32_bf16(a, B1[kt], accP[pass][rt][1], 0, 0, 0);
        }
      }
    }
    __syncthreads();                 // scores fully consumed; safe to overwrite Ssh
#pragma unroll
    for (int pass = 0; pass < 3; pass++){
#pragma unroll
      for (int cg = 0; cg < 2; cg++){
        int col = pass * 128 + wave * 16 + l16 + cg * 64;
        float bv = P.biasQKV[col];
#pragma unroll
        for (int rt = 0; rt < 2; rt++){
#pragma unroll
          for (int r = 0; r < 4; r++){
            int row = rt * 16 + quad * 4 + r;
            if (row < 25) Ssh[row * 388 + col] = accP[pass][rt][cg][r] + bv;
          }
        }
      }
    }
  }
  __syncthreads();
  // 6. SAB scores (dh=32)
  for (int idx = tid; idx < 2500; idx += 256){
    int h = idx / 625;
    int r = idx - h * 625;
    int q = r / 25, k = r - q * 25;
    const float* qp = &Ssh[q * 388 + h * 32];
    const float* kp = &Ssh[k * 388 + 128 + h * 32];
    float acc = 0.f;
#pragma unroll
    for (int d = 0; d < 32; d += 4){
      float4 a4 = *reinterpret_cast<const float4*>(&qp[d]);
      float4 b4 = *reinterpret_cast<const float4*>(&kp[d]);
      acc = fmaf(a4.x, b4.x, acc); acc = fmaf(a4.y, b4.y, acc);
      acc = fmaf(a4.z, b4.z, acc); acc = fmaf(a4.w, b4.w, acc);
    }
    Ss2[(h * 25 + q) * 26 + k] = acc * 0.0883883476f;
  }
  __syncthreads();
  // 7. softmax over q per (h,k)
  if (tid < 100){
    int h = tid / 25, k = tid - h * 25;
    float m = -1e30f;
#pragma unroll
    for (int q = 0; q < 25; q++) m = fmaxf(m, Ss2[(h * 25 + q) * 26 + k]);
    float s = 0.f;
#pragma unroll
    for (int q = 0; q < 25; q++){ float e = __expf(Ss2[(h * 25 + q) * 26 + k] - m); Ss2[(h * 25 + q) * 26 + k] = e; s += e; }
    float inv = 1.0f / s;
#pragma unroll
    for (int q = 0; q < 25; q++) Ss2[(h * 25 + q) * 26 + k] *= inv;
  }
  __syncthreads();
  // 8. Ob = Q1 + AV -> OaF (Oa dead) + Abf2 bf16
  if (tid < 128){
    int c = tid, h = c >> 5;
    float acc[25] = {};
    for (int k = 0; k < 25; k++){
      float v = Ssh[k * 388 + 256 + c];
#pragma unroll
      for (int q = 0; q < 25; q++) acc[q] = fmaf(Ss2[(h * 25 + q) * 26 + k], v, acc[q]);
    }
#pragma unroll
    for (int q = 0; q < 25; q++){
      float ob = Ssh[q * 388 + c] + acc[q];
      OaF[q * 260 + c] = ob;
      Abf2[q * 136 + c] = f2bf(ob);
    }
  }
  __syncthreads();
  // 9. O1 = Ob + relu(Ob @ Wo1 + bo1) [K=128, 1 pass] -> O0F (O0 dead)
  {
    int c0 = wave * 16 + l16, c1 = c0 + 64;
    s16x8 B0[4], B1[4];
#pragma unroll
    for (int kt = 0; kt < 4; kt++){
      int kb = kt * 32 + quad * 8;
      B0[kt] = *reinterpret_cast<const s16x8*>(&P.Wo1t[(size_t)c0 * 136 + kb]);
      B1[kt] = *reinterpret_cast<const s16x8*>(&P.Wo1t[(size_t)c1 * 136 + kb]);
    }
    f32x4 a00 = (f32x4){0.f,0.f,0.f,0.f}, a01 = a00, a10 = a00, a11 = a00;
#pragma unroll
    for (int kt = 0; kt < 4; kt++){
      int kb = kt * 32 + quad * 8;
      s16x8 aA = *reinterpret_cast<const s16x8*>(&Abf2[l16 * 136 + kb]);
      s16x8 aB = *reinterpret_cast<const s16x8*>(&Abf2[(16 + l16) * 136 + kb]);
      a00 = __builtin_amdgcn_mfma_f32_16x16x32_bf16(aA, B0[kt], a00, 0, 0, 0);
      a01 = __builtin_amdgcn_mfma_f32_16x16x32_bf16(aA, B1[kt], a01, 0, 0, 0);
      a10 = __builtin_amdgcn_mfma_f32_16x16x32_bf16(aB, B0[kt], a10, 0, 0, 0);
      a11 = __builtin_amdgcn_mfma_f32_16x16x32_bf16(aB, B1[kt], a11, 0, 0, 0);
    }
#pragma unroll
    for (int cg = 0; cg < 2; cg++){
      int col = cg ? c1 : c0;
      float bv = P.bo1[col];
      f32x4 accs0 = cg ? a01 : a00;
      f32x4 accs1 = cg ? a11 : a10;
#pragma unroll
      for (int r = 0; r < 4; r++){
        int row0 = quad * 4 + r;
        if (row0 < 25){ float t = accs0[r] + bv; O0F[row0 * 260 + col] = OaF[row0 * 260 + col] + fmaxf(t, 0.f); }
        int row1 = 16 + quad * 4 + r;
        if (row1 < 25){ float t = accs1[r] + bv; O0F[row1 * 260 + col] = OaF[row1 * 260 + col] + fmaxf(t, 0.f); }
      }
    }
  }
  __syncthreads();
  // 10. head (O1 in O0F)
  int c = tid;
  if (c < 128){
    float s = 0.f;
    for (int k = 0; k < 25; k++) s += O0F[k * 260 + c];
    hva[c] = s;
  }
  __syncthreads();
  float o2 = 0.f;
  if (c < 128){
    o2 = P.bq2[c];
    for (int k = 0; k < 128; k++) o2 = fmaf(P.S2[k], P.Wq2[k * 128 + c], o2);
    o2 += 25.f * P.bv2[c];
    for (int k = 0; k < 128; k++) o2 = fmaf(hva[k], P.Wv2[k * 128 + c], o2);
  }
  __syncthreads();
  if (c < 128) hvb[c] = o2;
  __syncthreads();
  float o2f = 0.f;
  if (c < 128){
    float t = P.bo2[c];
    for (int k = 0; k < 128; k++) t = fmaf(hvb[k], P.Wo2[k * 128 + c], t);
    o2f = o2 + fmaxf(t, 0.f);
  }
  __syncthreads();
  if (c < 128) hva[c] = o2f;
  __syncthreads();
  float z = 0.f;
  if (c < 128){
    z = P.bl[c];
    for (int k = 0; k < 128; k++) z = fmaf(hva[k], P.Wl[k * 128 + c], z);
  }
  __syncthreads();
  if (c < 128) hvb[c] = z;
  __syncthreads();
  float z1 = 0.f;
  if (c < 128){
    z1 = P.bc1[c];
    for (int k = 0; k < 128; k++) z1 = fmaf(hvb[k], P.Wc1[k * 128 + c], z1);
    z1 = fmaxf(z1, 0.f);
  }
  __syncthreads();
  if (c < 128) hva[c] = z1;
  __syncthreads();
  if (c < 64){
    float z2 = P.bc2[c];
    for (int k = 0; k < 128; k++) z2 = fmaf(hva[k], P.Wc2[k * 64 + c], z2);
    hvb[c] = fmaxf(z2, 0.f);
  }
  __syncthreads();
  if (c < 10){
    float lg = P.bc3[c];
    for (int k = 0; k < 64; k++) lg = fmaf(hvb[k], P.Wc3[k * 10 + c], lg);
    P.out[g * 10 + c] = lg;
  }
}

// ---------------- host ----------------
extern "C" void kernel_launch(void* const* d_in, const int* in_sizes, int n_in,
                              void* d_out, int out_size, void* d_ws, size_t ws_size,
                              hipStream_t stream)
{
  const int*  edge = (const int*)d_in[1];
  const int N = in_sizes[0] / FIN;      // 20000
  const int E = in_sizes[1] / 2;        // 320000
  const int G = N / MAXN;               // 200
  const int* srcp = edge;
  const int* dstp = edge + E;
  float* out = (float*)d_out;           // f32: [logits 200x10 | p1 200x128 | p2 200x128]

  float* w = (float*)d_ws;
  size_t off = 0;
  auto alloc = [&](size_t nfl){ nfl = (nfl + 3) & ~(size_t)3; float* p = w + off; off += nfl; return p; };
  auto allocS = [&](size_t nsh)->short*{ size_t nfl = ((nsh + 1) / 2 + 3) & ~(size_t)3; short* p = (short*)(w + off); off += nfl; return p; };

  float* dflag = alloc(1);
  float* degb  = alloc(N);

  float* biasVS  = alloc(356);          // [bv0 | cvec]
  float* biasQKV = alloc(384);          // [bq1 | bk1 | bv1]
  float* cvec = biasVS + 256;

  const int castT[24] = {4,6,7,8,9,10,11,15,23,24,25,26,29,30,31,32,33,34,35,36,37,38,39,40};
  float* wf[41] = {nullptr};
  for (int i = 0; i < 24; i++) wf[castT[i]] = alloc((size_t)in_sizes[castT[i]]);
  wf[13] = biasVS; wf[17] = biasQKV; wf[19] = biasQKV + 128; wf[21] = biasQKV + 256;

  float* P3 = alloc((size_t)N * 356);   // VdS
  float* Adj = alloc((size_t)G * MAXN * MAXN);
  float* Q0  = alloc(25 * 256);
  short* xaggB = allocS((size_t)N * 256);

  short* W1t   = allocS(128 * 136);
  short* W2t   = allocS(128 * 136);
  short* WVSt  = allocS(356 * 264);     // [Wv0t | Ubart]
  short* WQKVt = allocS(384 * 264);     // [Wq1t | Wk1t | Wv1t]
  short* Wo0t  = allocS(256 * 264);
  short* Wo1t  = allocS(128 * 136);
  short* Ubart = WVSt + (size_t)256 * 264;
  if (off * sizeof(float) > ws_size) return;

  dim3 blk(256);

  // 1. dtype sniff
  sniff_dtype<<<1, blk, 0, stream>>>((const unsigned short*)d_in[0], dflag);

  // 2. unified prep (casts + transposes + fills: Adj=0, deg=1)
  PrepBatch pb; int ne = 0, blks = 0;
  auto addC = [&](const void* s, float* d, int n){
    pb.src[ne]=s; pb.dst[ne]=d; pb.a[ne]=n; pb.b[ne]=0; pb.blk0[ne]=blks;
    blks += ceil_div(ceil_div(n, 4), 256); ne++; };
  auto addW = [&](const void* s, short* d, int K, int Nn){
    pb.src[ne]=s; pb.dst[ne]=d; pb.a[ne]=K; pb.b[ne]=Nn; pb.blk0[ne]=blks;
    blks += ceil_div(K * Nn, 256); ne++; };
  auto addF = [&](float* d, int n, int mode){   // mode -1: zeros, -2: ones
    pb.src[ne]=nullptr; pb.dst[ne]=d; pb.a[ne]=n; pb.b[ne]=mode; pb.blk0[ne]=blks;
    blks += ceil_div(ceil_div(n, 4), 256); ne++; };
  for (int i = 0; i < 24; i++){ int t = castT[i]; addC(d_in[t], wf[t], in_sizes[t]); }
  addC(d_in[13], biasVS, 256);
  addC(d_in[17], biasQKV, 128); addC(d_in[19], biasQKV + 128, 128); addC(d_in[21], biasQKV + 256, 128);
  addW(d_in[3],  W1t, 128, 128);             addW(d_in[5],  W2t, 128, 128);
  addW(d_in[12], WVSt, 256, 256);            addW(d_in[16], WQKVt, 256, 128);
  addW(d_in[18], WQKVt + 128*264, 256, 128); addW(d_in[20], WQKVt + 256*264, 256, 128);
  addW(d_in[14], Wo0t, 256, 256);            addW(d_in[22], Wo1t, 128, 128);
  addF(Adj, G * MAXN * MAXN, -1);
  addF(degb, N, -2);
  pb.blk0[ne] = blks; pb.ne = ne;
  prep_all<<<dim3(blks), blk, 0, stream>>>(pb, dflag);

  // 3-4. adjacency
  deg_edges<<<ceil_div(E, 256), blk, 0, stream>>>(dstp, degb, E);
  adj_fin<<<ceil_div(N + E, 256), blk, 0, stream>>>(srcp, dstp, degb, Adj, N, E);

  // 5. whole GCN stage per graph (pools straight to out)
  gcn_all<<<dim3(G), blk, 0, stream>>>(d_in[0], dflag, Adj, W1t, wf[4], W2t, wf[6],
                                       xaggB, out + 2000, out + 27600);

  // 6. Q0 + Ubar^T + cvec
  ubar_q0<<<dim3(100), blk, 0, stream>>>(wf[7], wf[8], wf[9], wf[10], wf[11], Q0, Ubart, cvec);

  // 7. [Vd | S2d] = xagg @ [Wv0 | Ubar]^T + [bv0 | cvec]
  {
    dim3 grid(ceil_div(N, 64), ceil_div(356, 128));
    gemm_bf16_t<256><<<grid, blk, 0, stream>>>(xaggB, 256, WVSt, 264, biasVS, P3, 356, N, 356);
  }

  // 8. fused tail: softmax+AV+Wo0+QKV+SAB+Wo1+head
  TailParams tp;
  tp.VdS = P3; tp.Q0 = Q0;
  tp.Wo0t = Wo0t; tp.bo0 = wf[15];
  tp.WQKVt = WQKVt; tp.biasQKV = biasQKV;
  tp.Wo1t = Wo1t; tp.bo1 = wf[23];
  tp.S2 = wf[24]; tp.Wq2 = wf[25]; tp.bq2 = wf[26]; tp.Wv2 = wf[29]; tp.bv2 = wf[30];
  tp.Wo2 = wf[31]; tp.bo2 = wf[32]; tp.Wl = wf[33]; tp.bl = wf[34];
  tp.Wc1 = wf[35]; tp.bc1 = wf[36]; tp.Wc2 = wf[37]; tp.bc2 = wf[38];
  tp.Wc3 = wf[39]; tp.bc3 = wf[40];
  tp.out = out;
  tail_all<<<dim3(G), blk, 0, stream>>>(tp);
}